// Round 2
// baseline (5907.722 us; speedup 1.0000x reference)
//
#include <hip/hip_runtime.h>
#include <cmath>

#define HWD 192
#define PIX (HWD*HWD)      // 36864
#define BB  4
#define CCH 128

__device__ __forceinline__ float gelu_f(float x) {
    return 0.5f * x * (1.0f + erff(x * 0.70710678118654752f));
}

// ---------------- LayerNorm over channel axis (per b,h,w position) -------------
__global__ __launch_bounds__(64) void ln_kernel(const float* __restrict__ in,
        const float* __restrict__ w, const float* __restrict__ b,
        float* __restrict__ out)
{
    int t = blockIdx.x * 64 + threadIdx.x;        // BB*PIX/4 threads
    int bi = t / (PIX/4);
    int p  = (t - bi*(PIX/4)) * 4;
    const float* base = in + (size_t)bi * CCH * PIX + p;
    float s0=0,s1=0,s2=0,s3=0,q0=0,q1=0,q2=0,q3=0;
    for (int c=0;c<CCH;++c) {
        const float4 v = *(const float4*)(base + (size_t)c*PIX);
        s0+=v.x; s1+=v.y; s2+=v.z; s3+=v.w;
        q0+=v.x*v.x; q1+=v.y*v.y; q2+=v.z*v.z; q3+=v.w*v.w;
    }
    const float inv = 1.f/128.f;
    float m0=s0*inv, m1=s1*inv, m2=s2*inv, m3=s3*inv;
    float i0 = rsqrtf(q0*inv - m0*m0 + 1e-6f);
    float i1 = rsqrtf(q1*inv - m1*m1 + 1e-6f);
    float i2 = rsqrtf(q2*inv - m2*m2 + 1e-6f);
    float i3 = rsqrtf(q3*inv - m3*m3 + 1e-6f);
    float* ob = out + (size_t)bi * CCH * PIX + p;
    for (int c=0;c<CCH;++c) {
        const float4 v = *(const float4*)(base + (size_t)c*PIX);
        float wc = w[c], bc = b[c];
        float4 r;
        r.x=(v.x-m0)*i0*wc+bc; r.y=(v.y-m1)*i1*wc+bc;
        r.z=(v.z-m2)*i2*wc+bc; r.w=(v.w-m3)*i3*wc+bc;
        *(float4*)(ob + (size_t)c*PIX) = r;
    }
}

// ---------------- 1x1 conv as GEMM: out[b,co,p] = sum_ci W[co,ci]*in[b,ci,p] ----
// tile: 128 co x 128 px, thread = 8co x 8px, K-chunk 16
template<bool DOGELU, bool DORES>
__global__ __launch_bounds__(256) void conv1x1_kernel(
    const float* __restrict__ in, const float* __restrict__ w,
    const float* __restrict__ bias, const float* __restrict__ res,
    float* __restrict__ out, int Cin, int Cout)
{
    __shared__ float ws_[16][128];
    __shared__ float is_[16][128];
    const int px0 = blockIdx.x * 128;
    const int co0 = blockIdx.y * 128;
    const int bi  = blockIdx.z;
    const int tid = threadIdx.x;
    const int tc = tid >> 4, tp = tid & 15;
    float acc[8][8];
    #pragma unroll
    for (int i=0;i<8;++i)
        #pragma unroll
        for (int j=0;j<8;++j) acc[i][j]=0.f;
    const float* inb = in + (size_t)bi * Cin * PIX + px0;
    for (int k0 = 0; k0 < Cin; k0 += 16) {
        #pragma unroll
        for (int rep=0; rep<2; ++rep) {
            int f = tid + rep*256;
            int r = f >> 5, c4 = (f & 31) * 4;
            *(float4*)&is_[r][c4] = *(const float4*)(inb + (size_t)(k0 + r) * PIX + c4);
        }
        #pragma unroll
        for (int rep=0; rep<2; ++rep) {
            int f = tid + rep*256;
            int ci_ = f >> 2, j4 = (f & 3) * 4;
            const float4 wv = *(const float4*)(w + (size_t)(co0 + ci_) * Cin + k0 + j4);
            ws_[j4+0][ci_] = wv.x; ws_[j4+1][ci_] = wv.y;
            ws_[j4+2][ci_] = wv.z; ws_[j4+3][ci_] = wv.w;
        }
        __syncthreads();
        #pragma unroll
        for (int k=0;k<16;++k) {
            float a[8], bb[8];
            *(float4*)&a[0] = *(float4*)&ws_[k][tc*8];
            *(float4*)&a[4] = *(float4*)&ws_[k][tc*8+4];
            *(float4*)&bb[0] = *(float4*)&is_[k][tp*8];
            *(float4*)&bb[4] = *(float4*)&is_[k][tp*8+4];
            #pragma unroll
            for (int i=0;i<8;++i)
                #pragma unroll
                for (int j=0;j<8;++j)
                    acc[i][j] += a[i]*bb[j];
        }
        __syncthreads();
    }
    #pragma unroll
    for (int i=0;i<8;++i) {
        int co = co0 + tc*8 + i;
        float bs = bias[co];
        size_t obase = ((size_t)bi*Cout + co)*PIX + px0 + tp*8;
        float r[8];
        #pragma unroll
        for (int j=0;j<8;++j) {
            float v = acc[i][j] + bs;
            if (DOGELU) v = gelu_f(v);
            r[j] = v;
        }
        if (DORES) {
            const float4 e0 = *(const float4*)(res + obase);
            const float4 e1 = *(const float4*)(res + obase + 4);
            r[0]+=e0.x; r[1]+=e0.y; r[2]+=e0.z; r[3]+=e0.w;
            r[4]+=e1.x; r[5]+=e1.y; r[6]+=e1.z; r[7]+=e1.w;
        }
        *(float4*)(out + obase)     = make_float4(r[0],r[1],r[2],r[3]);
        *(float4*)(out + obase + 4) = make_float4(r[4],r[5],r[6],r[7]);
    }
}

// ---------------- depthwise 3x3 pad1 + bias, out = gelu(conv)+in (per-batch) ----
// in/out: (256, PIX) for one batch element
__global__ __launch_bounds__(256) void dw3x3_kernel(const float* __restrict__ in,
    const float* __restrict__ w, const float* __restrict__ b,
    float* __restrict__ out)
{
    int t = blockIdx.x*256 + threadIdx.x;     // 256*PIX/4 threads
    int c = t / (PIX/4);
    int p4 = (t - c*(PIX/4)) * 4;
    int y = p4 / HWD, x0 = p4 - y*HWD;
    const float* ib = in + (size_t)c * PIX;
    float wk[9];
    #pragma unroll
    for (int e=0;e<9;++e) wk[e] = w[c*9+e];
    float bc = b[c];
    float a0=bc,a1=bc,a2=bc,a3=bc;
    #pragma unroll
    for (int ky=0;ky<3;++ky) {
        int yy = y + ky - 1;
        if ((unsigned)yy < (unsigned)HWD) {
            const float* row = ib + (size_t)yy*HWD;
            float v[6];
            #pragma unroll
            for (int d=0;d<6;++d) {
                int xx = x0 + d - 1;
                v[d] = ((unsigned)xx < (unsigned)HWD) ? row[xx] : 0.f;
            }
            a0 += v[0]*wk[ky*3+0] + v[1]*wk[ky*3+1] + v[2]*wk[ky*3+2];
            a1 += v[1]*wk[ky*3+0] + v[2]*wk[ky*3+1] + v[3]*wk[ky*3+2];
            a2 += v[2]*wk[ky*3+0] + v[3]*wk[ky*3+1] + v[4]*wk[ky*3+2];
            a3 += v[3]*wk[ky*3+0] + v[4]*wk[ky*3+1] + v[5]*wk[ky*3+2];
        }
    }
    const float4 cen = *(const float4*)(ib + (size_t)y*HWD + x0);
    float4 r;
    r.x = gelu_f(a0)+cen.x; r.y = gelu_f(a1)+cen.y;
    r.z = gelu_f(a2)+cen.z; r.w = gelu_f(a3)+cen.w;
    *(float4*)(out + (size_t)c*PIX + p4) = r;
}

// ---------------- window attention (per-batch; qkv = (384,PIX), o = (128,PIX)) -
__global__ __launch_bounds__(256) void attn_kernel(const float* __restrict__ qkv,
    const float* __restrict__ table, float* __restrict__ o)
{
    __shared__ float K[256][32];
    __shared__ float V[256][32];
    const int win = blockIdx.x, head = blockIdx.y;
    const int wy = win/12, wx = win - wy*12;
    const int t = threadIdx.x;
    const int iy = t >> 4, ix = t & 15;
    const int gy = wy*16 + iy, gx = wx*16 + ix;
    const size_t sp = (size_t)gy*HWD + gx;
    const float* qb = qkv + ((size_t)head*32) * PIX + sp;
    const float* kb = qkv + ((size_t)(128 + head*32)) * PIX + sp;
    const float* vb = qkv + ((size_t)(256 + head*32)) * PIX + sp;
    float q[32];
    #pragma unroll
    for (int cc=0;cc<32;++cc) {
        q[cc]     = qb[(size_t)cc*PIX];
        K[t][cc]  = kb[(size_t)cc*PIX];
        V[t][cc]  = vb[(size_t)cc*PIX];
    }
    __syncthreads();
    const float scale = 0.17677669529663687f;   // 32^-0.5
    const float* tb = table + head*961;
    float m = -1e30f, l = 0.f;
    float oacc[32];
    #pragma unroll
    for (int cc=0;cc<32;++cc) oacc[cc]=0.f;
    for (int kt=0; kt<256; ++kt) {
        float s = 0.f;
        const float* kr = &K[kt][0];
        #pragma unroll
        for (int cc=0;cc<32;cc+=4) {
            const float4 kv = *(const float4*)(kr + cc);
            s += q[cc]*kv.x + q[cc+1]*kv.y + q[cc+2]*kv.z + q[cc+3]*kv.w;
        }
        int kh = kt >> 4, kw = kt & 15;
        s = s*scale + tb[(kh - iy + 15)*31 + (kw - ix + 15)];
        float mn = fmaxf(m, s);
        float corr = __expf(m - mn);
        float p = __expf(s - mn);
        l = l*corr + p;
        const float* vr = &V[kt][0];
        #pragma unroll
        for (int cc=0;cc<32;cc+=4) {
            const float4 vv = *(const float4*)(vr + cc);
            oacc[cc]   = oacc[cc]  *corr + p*vv.x;
            oacc[cc+1] = oacc[cc+1]*corr + p*vv.y;
            oacc[cc+2] = oacc[cc+2]*corr + p*vv.z;
            oacc[cc+3] = oacc[cc+3]*corr + p*vv.w;
        }
        m = mn;
    }
    float invl = 1.f / l;
    float* ob = o + ((size_t)head*32) * PIX + sp;
    #pragma unroll
    for (int cc=0;cc<32;++cc) ob[(size_t)cc*PIX] = oacc[cc]*invl;
}

// ---------------- mean over spatial for channels 0..31 (full batch) ------------
__global__ __launch_bounds__(256) void meanpool_kernel(const float* __restrict__ in,
    float* __restrict__ v)
{
    int bc = blockIdx.x;               // BB*32
    int bi = bc >> 5, c = bc & 31;
    const float* base = in + ((size_t)bi*CCH + c) * PIX;
    float s = 0.f;
    for (int i = threadIdx.x; i < PIX/4; i += 256) {
        const float4 t4 = ((const float4*)base)[i];
        s += t4.x+t4.y+t4.z+t4.w;
    }
    #pragma unroll
    for (int off=32; off>0; off>>=1) s += __shfl_down(s, off, 64);
    __shared__ float red[4];
    if ((threadIdx.x & 63) == 0) red[threadIdx.x >> 6] = s;
    __syncthreads();
    if (threadIdx.x == 0) v[bc] = (red[0]+red[1]+red[2]+red[3]) * (1.f/PIX);
}

// ---------------- tiny MLP producing dynamic 3x3 kernels -----------------------
__global__ __launch_bounds__(256) void mlp_kernel(const float* __restrict__ v,
    const float* __restrict__ pw1, const float* __restrict__ pb1,
    const float* __restrict__ pw2, const float* __restrict__ pb2,
    float* __restrict__ dk)
{
    __shared__ float h[64];
    int tid = threadIdx.x;
    if (tid < 64) {
        int bi = tid >> 4, m = tid & 15;
        float s = pb1[m];
        for (int c=0;c<32;++c) s += v[bi*32+c]*pw1[m*32+c];
        h[tid] = gelu_f(s);
    }
    __syncthreads();
    for (int idx = tid; idx < BB*288; idx += 256) {
        int bi = idx / 288, j = idx - bi*288;
        float s = pb2[j];
        for (int m=0;m<16;++m) s += h[bi*16+m]*pw2[j*16+m];
        dk[idx] = s;
    }
}

// ---------------- weight transpose (CO,CI,T) -> (CI,T,CO) ----------------------
__global__ __launch_bounds__(256) void wtrans_kernel(const float* __restrict__ w,
    float* __restrict__ wt, int CO, int CI, int T)
{
    int idx = blockIdx.x*256 + threadIdx.x;
    if (idx >= CO*CI*T) return;
    int co = idx / (CI*T);
    int r = idx - co*CI*T;
    int ci = r / T;
    int tp = r - ci*T;
    wt[((size_t)ci*T + tp)*CO + co] = w[idx];
}

// ---------------- 13x13 dense conv 32->32 pad6 + fused dynamic dw3x3 -----------
__global__ __launch_bounds__(256) void conv13_kernel(const float* __restrict__ in,
    const float* __restrict__ wt,   // [ci][169][32]
    const float* __restrict__ dk,   // [B*32][9]
    float* __restrict__ out)        // (B,32,PIX)
{
    const int bi = blockIdx.y;
    const int tile = blockIdx.x;            // 144
    const int ty0 = (tile/12)*16, tx0 = (tile - (tile/12)*12)*16;
    const int ty = threadIdx.x >> 4, tx = threadIdx.x & 15;
    __shared__ float patch[28*28];
    __shared__ float wsm[169*32];
    float acc[32];
    #pragma unroll
    for (int i=0;i<32;++i) acc[i]=0.f;
    const float* inb = in + (size_t)bi * CCH * PIX;
    #pragma unroll 1
    for (int ci=0; ci<32; ++ci) {
        __syncthreads();
        for (int idx=threadIdx.x; idx<784; idx+=256) {
            int py = idx/28, px = idx - py*28;
            int gy = ty0 + py - 6, gx = tx0 + px - 6;
            patch[idx] = ((unsigned)gy < (unsigned)HWD && (unsigned)gx < (unsigned)HWD)
                         ? inb[(size_t)ci*PIX + (size_t)gy*HWD + gx] : 0.f;
        }
        // stage weights for this ci: 169*32 = 5408 floats = 1352 float4
        const float4* wsrc = (const float4*)(wt + (size_t)ci*169*32);
        for (int idx=threadIdx.x; idx<1352; idx+=256)
            ((float4*)wsm)[idx] = wsrc[idx];
        __syncthreads();
        #pragma unroll 1
        for (int dy=0; dy<13; ++dy) {
            const float* prow = &patch[(ty+dy)*28 + tx];
            const float* wrow = &wsm[dy*13*32];
            #pragma unroll
            for (int dx=0; dx<13; ++dx) {
                float pv = prow[dx];
                const float* wr = wrow + dx*32;
                #pragma unroll
                for (int c4=0;c4<8;++c4) {
                    const float4 wv = *(const float4*)(wr + c4*4);
                    acc[c4*4+0] += pv*wv.x;
                    acc[c4*4+1] += pv*wv.y;
                    acc[c4*4+2] += pv*wv.z;
                    acc[c4*4+3] += pv*wv.w;
                }
            }
        }
        // fused dynamic depthwise 3x3 (channel ci only)
        const float* dkk = dk + (bi*32 + ci)*9;
        float dsum = 0.f;
        #pragma unroll
        for (int e=0;e<9;++e) {
            int ey = e/3, ex = e - ey*3;
            dsum += patch[(ty+5+ey)*28 + (tx+5+ex)] * dkk[e];
        }
        #pragma unroll
        for (int co=0;co<32;++co) acc[co] += (co==ci) ? dsum : 0.f;
    }
    const int oy = ty0+ty, ox = tx0+tx;
    #pragma unroll
    for (int co=0;co<32;++co)
        out[((size_t)bi*32 + co)*PIX + (size_t)oy*HWD + ox] = acc[co];
}

// ---------------- copy (B,32,PIX) into channels 0..31 of (B,128,PIX) -----------
__global__ __launch_bounds__(256) void copyslice_kernel(const float* __restrict__ src,
    float* __restrict__ dst)
{
    int idx = blockIdx.x*256 + threadIdx.x;      // BB*32*PIX/4
    int bc = idx / (PIX/4);
    int p4 = (idx - bc*(PIX/4)) * 4;
    int bi = bc >> 5, c = bc & 31;
    *(float4*)(dst + ((size_t)bi*CCH + c)*PIX + p4) =
        *(const float4*)(src + (size_t)bc*PIX + p4);
}

// ---------------- final dense 3x3 conv 128->128 pad1 + bias + skip -------------
__global__ __launch_bounds__(256) void conv3x3_kernel(const float* __restrict__ in,
    const float* __restrict__ wt,    // [ci][9][128]
    const float* __restrict__ bias, const float* __restrict__ skip,
    float* __restrict__ out)
{
    const int bi = blockIdx.z;
    const int co0 = blockIdx.y * 32;
    const int tile = blockIdx.x;
    const int ty0 = (tile/12)*16, tx0 = (tile - (tile/12)*12)*16;
    const int ty = threadIdx.x >> 4, tx = threadIdx.x & 15;
    __shared__ float patch[18*18];
    float acc[32];
    #pragma unroll
    for (int i=0;i<32;++i) acc[i]=0.f;
    const float* inb = in + (size_t)bi * CCH * PIX;
    #pragma unroll 1
    for (int ci=0; ci<CCH; ++ci) {
        __syncthreads();
        for (int idx=threadIdx.x; idx<324; idx+=256) {
            int py = idx/18, px = idx - py*18;
            int gy = ty0 + py - 1, gx = tx0 + px - 1;
            patch[idx] = ((unsigned)gy < (unsigned)HWD && (unsigned)gx < (unsigned)HWD)
                         ? inb[(size_t)ci*PIX + (size_t)gy*HWD + gx] : 0.f;
        }
        __syncthreads();
        const float* wci = wt + (size_t)ci*9*CCH + co0;
        #pragma unroll
        for (int t=0;t<9;++t) {
            float pv = patch[(ty + t/3)*18 + tx + (t - (t/3)*3)];
            const float* wr = wci + t*CCH;
            #pragma unroll
            for (int co=0;co<32;++co) acc[co] += pv*wr[co];
        }
    }
    const int oy = ty0+ty, ox = tx0+tx;
    #pragma unroll
    for (int co=0;co<32;++co) {
        size_t o = ((size_t)bi*CCH + co0 + co)*PIX + (size_t)oy*HWD + ox;
        out[o] = acc[co] + bias[co0+co] + skip[o];
    }
}

extern "C" void kernel_launch(void* const* d_in, const int* in_sizes, int n_in,
                              void* d_out, int out_size, void* d_ws, size_t ws_size,
                              hipStream_t stream) {
    (void)in_sizes; (void)n_in; (void)out_size;
    const float* x_in      = (const float*)d_in[0];
    const float* plk       = (const float*)d_in[1];
    const float* ln_proj_w = (const float*)d_in[2];
    const float* ln_proj_b = (const float*)d_in[3];
    const float* proj_w1   = (const float*)d_in[4];
    const float* proj_b1   = (const float*)d_in[5];
    const float* proj_dw   = (const float*)d_in[6];
    const float* proj_dwb  = (const float*)d_in[7];
    const float* proj_w2   = (const float*)d_in[8];
    const float* proj_b2   = (const float*)d_in[9];
    const float* ln_attn_w = (const float*)d_in[10];
    const float* ln_attn_b = (const float*)d_in[11];
    const float* qkv_w     = (const float*)d_in[12];
    const float* qkv_b     = (const float*)d_in[13];
    const float* attn_ow   = (const float*)d_in[14];
    const float* attn_ob   = (const float*)d_in[15];
    const float* rpe       = (const float*)d_in[16];
    const float* ffn_w1    = (const float*)d_in[17];
    const float* ffn_b1    = (const float*)d_in[18];
    const float* ffn_dw    = (const float*)d_in[19];
    const float* ffn_dwb   = (const float*)d_in[20];
    const float* ffn_w2    = (const float*)d_in[21];
    const float* ffn_b2    = (const float*)d_in[22];
    const float* pk_w1     = (const float*)d_in[23];
    const float* pk_b1     = (const float*)d_in[24];
    const float* pk_w2     = (const float*)d_in[25];
    const float* pk_b2     = (const float*)d_in[26];
    const float* aggr_w    = (const float*)d_in[27];
    const float* aggr_b    = (const float*)d_in[28];
    const float* ln_out_w  = (const float*)d_in[29];
    const float* ln_out_b  = (const float*)d_in[30];
    const float* co_w      = (const float*)d_in[31];
    const float* co_b      = (const float*)d_in[32];
    float* out = (float*)d_out;

    const size_t N1b = (size_t)CCH * PIX;      // 4,718,592 (one batch, 128ch)
    const size_t NEb = (size_t)256 * PIX;      // 9,437,184 (one batch, 256ch)
    const size_t RAsz = (size_t)BB * N1b;      // 18,874,368
    const size_t EQsz = 2 * NEb;               // 18,874,368 (>= 3*N1b and >= BB*32*PIX)
    const size_t need_floats = 2*RAsz + EQsz + 32*169*32 + 128*9*128 + 256 + BB*288;
    if (ws_size < need_floats * sizeof(float)) return;   // diagnostic guard

    float* ws  = (float*)d_ws;
    float* RA  = ws;
    float* RB  = RA + RAsz;
    float* EQ  = RB + RAsz;                    // aliased: E1/E2 | per-batch QKV | C13
    float* E1  = EQ;
    float* E2  = EQ + NEb;
    float* C13 = EQ;                           // BB*32*PIX = 4,718,592 fits
    float* WT13 = EQ + EQsz;                   // 32*169*32
    float* WT3  = WT13 + (size_t)32*169*32;    // 128*9*128
    float* VB   = WT3 + (size_t)128*9*128;     // 256
    float* DK   = VB + 256;                    // BB*288

    dim3 blk(256);

    // weight transposes
    wtrans_kernel<<<(32*32*169+255)/256, blk, 0, stream>>>(plk, WT13, 32, 32, 169);
    wtrans_kernel<<<(128*128*9+255)/256, blk, 0, stream>>>(co_w, WT3, 128, 128, 9);

    // x = conv_ffn(LN(x), proj)   [E buffers are per-batch -> loop b]
    ln_kernel<<<576, 64, 0, stream>>>(x_in, ln_proj_w, ln_proj_b, RA);
    for (int b=0;b<BB;++b) {
        conv1x1_kernel<true,false><<<dim3(288,2,1), blk, 0, stream>>>(RA + b*N1b, proj_w1, proj_b1, nullptr, E1, 128, 256);
        dw3x3_kernel<<<9216, blk, 0, stream>>>(E1, proj_dw, proj_dwb, E2);
        conv1x1_kernel<false,false><<<dim3(288,1,1), blk, 0, stream>>>(E2, proj_w2, proj_b2, nullptr, RB + b*N1b, 256, 128);
    }

    // x = x + window_attention(LN(x))
    ln_kernel<<<576, 64, 0, stream>>>(RB, ln_attn_w, ln_attn_b, RA);
    for (int b=0;b<BB;++b) {
        conv1x1_kernel<false,false><<<dim3(288,3,1), blk, 0, stream>>>(RA + b*N1b, qkv_w, qkv_b, nullptr, EQ, 128, 384);
        attn_kernel<<<dim3(144,4,1), blk, 0, stream>>>(EQ, rpe, RA + b*N1b);
    }
    conv1x1_kernel<false,true><<<dim3(288,1,BB), blk, 0, stream>>>(RA, attn_ow, attn_ob, RB, RB, 128, 128);

    // x lives in RB across the loop
    for (int i=0;i<2;++i) {
        const float* fw1 = ffn_w1 + (size_t)i*256*128;
        const float* fb1 = ffn_b1 + (size_t)i*256;
        const float* fdw = ffn_dw + (size_t)i*256*9;
        const float* fdb = ffn_dwb + (size_t)i*256;
        const float* fw2 = ffn_w2 + (size_t)i*128*256;
        const float* fb2 = ffn_b2 + (size_t)i*128;
        const float* w1i = pk_w1 + (size_t)i*16*32;
        const float* b1i = pk_b1 + (size_t)i*16;
        const float* w2i = pk_w2 + (size_t)i*288*16;
        const float* b2i = pk_b2 + (size_t)i*288;
        const float* awi = aggr_w + (size_t)i*128*128;
        const float* abi = aggr_b + (size_t)i*128;

        for (int b=0;b<BB;++b) {
            conv1x1_kernel<true,false><<<dim3(288,2,1), blk, 0, stream>>>(RB + b*N1b, fw1, fb1, nullptr, E1, 128, 256);
            dw3x3_kernel<<<9216, blk, 0, stream>>>(E1, fdw, fdb, E2);
            conv1x1_kernel<false,false><<<dim3(288,1,1), blk, 0, stream>>>(E2, fw2, fb2, nullptr, RA + b*N1b, 256, 128);
        }
        meanpool_kernel<<<BB*32, blk, 0, stream>>>(RA, VB);
        mlp_kernel<<<1, blk, 0, stream>>>(VB, w1i, b1i, w2i, b2i, DK);
        conv13_kernel<<<dim3(144,BB), blk, 0, stream>>>(RA, WT13, DK, C13);
        copyslice_kernel<<<(BB*32*(PIX/4))/256, blk, 0, stream>>>(C13, RA);
        conv1x1_kernel<false,true><<<dim3(288,1,BB), blk, 0, stream>>>(RA, awi, abi, RB, RB, 128, 128);
    }

    // out = conv3x3(LN(x)) + bias + skip
    ln_kernel<<<576, 64, 0, stream>>>(RB, ln_out_w, ln_out_b, RA);
    conv3x3_kernel<<<dim3(144,4,BB), blk, 0, stream>>>(RA, WT3, co_b, x_in, out);
}

// Round 3
// 4722.502 us; speedup vs baseline: 1.2510x; 1.2510x over previous
//
#include <hip/hip_runtime.h>
#include <cmath>

#define HWD 192
#define PIX (HWD*HWD)      // 36864
#define BB  4
#define CCH 128

__device__ __forceinline__ float gelu_f(float x) {
    return 0.5f * x * (1.0f + erff(x * 0.70710678118654752f));
}

// ---------------- LayerNorm over channel axis (per b,h,w position) -------------
__global__ __launch_bounds__(64) void ln_kernel(const float* __restrict__ in,
        const float* __restrict__ w, const float* __restrict__ b,
        float* __restrict__ out)
{
    int t = blockIdx.x * 64 + threadIdx.x;        // BB*PIX/4 threads
    int bi = t / (PIX/4);
    int p  = (t - bi*(PIX/4)) * 4;
    const float* base = in + (size_t)bi * CCH * PIX + p;
    float s0=0,s1=0,s2=0,s3=0,q0=0,q1=0,q2=0,q3=0;
    for (int c=0;c<CCH;++c) {
        const float4 v = *(const float4*)(base + (size_t)c*PIX);
        s0+=v.x; s1+=v.y; s2+=v.z; s3+=v.w;
        q0+=v.x*v.x; q1+=v.y*v.y; q2+=v.z*v.z; q3+=v.w*v.w;
    }
    const float inv = 1.f/128.f;
    float m0=s0*inv, m1=s1*inv, m2=s2*inv, m3=s3*inv;
    float i0 = rsqrtf(q0*inv - m0*m0 + 1e-6f);
    float i1 = rsqrtf(q1*inv - m1*m1 + 1e-6f);
    float i2 = rsqrtf(q2*inv - m2*m2 + 1e-6f);
    float i3 = rsqrtf(q3*inv - m3*m3 + 1e-6f);
    float* ob = out + (size_t)bi * CCH * PIX + p;
    for (int c=0;c<CCH;++c) {
        const float4 v = *(const float4*)(base + (size_t)c*PIX);
        float wc = w[c], bc = b[c];
        float4 r;
        r.x=(v.x-m0)*i0*wc+bc; r.y=(v.y-m1)*i1*wc+bc;
        r.z=(v.z-m2)*i2*wc+bc; r.w=(v.w-m3)*i3*wc+bc;
        *(float4*)(ob + (size_t)c*PIX) = r;
    }
}

// ---------------- 1x1 conv as GEMM: out[b,co,p] = sum_ci W[co,ci]*in[b,ci,p] ----
template<bool DOGELU, bool DORES>
__global__ __launch_bounds__(256) void conv1x1_kernel(
    const float* __restrict__ in, const float* __restrict__ w,
    const float* __restrict__ bias, const float* __restrict__ res,
    float* __restrict__ out, int Cin, int Cout)
{
    __shared__ float ws_[16][128];
    __shared__ float is_[16][128];
    const int px0 = blockIdx.x * 128;
    const int co0 = blockIdx.y * 128;
    const int bi  = blockIdx.z;
    const int tid = threadIdx.x;
    const int tc = tid >> 4, tp = tid & 15;
    float acc[8][8];
    #pragma unroll
    for (int i=0;i<8;++i)
        #pragma unroll
        for (int j=0;j<8;++j) acc[i][j]=0.f;
    const float* inb = in + (size_t)bi * Cin * PIX + px0;
    for (int k0 = 0; k0 < Cin; k0 += 16) {
        #pragma unroll
        for (int rep=0; rep<2; ++rep) {
            int f = tid + rep*256;
            int r = f >> 5, c4 = (f & 31) * 4;
            *(float4*)&is_[r][c4] = *(const float4*)(inb + (size_t)(k0 + r) * PIX + c4);
        }
        #pragma unroll
        for (int rep=0; rep<2; ++rep) {
            int f = tid + rep*256;
            int ci_ = f >> 2, j4 = (f & 3) * 4;
            const float4 wv = *(const float4*)(w + (size_t)(co0 + ci_) * Cin + k0 + j4);
            ws_[j4+0][ci_] = wv.x; ws_[j4+1][ci_] = wv.y;
            ws_[j4+2][ci_] = wv.z; ws_[j4+3][ci_] = wv.w;
        }
        __syncthreads();
        #pragma unroll
        for (int k=0;k<16;++k) {
            float a[8], bb[8];
            *(float4*)&a[0] = *(float4*)&ws_[k][tc*8];
            *(float4*)&a[4] = *(float4*)&ws_[k][tc*8+4];
            *(float4*)&bb[0] = *(float4*)&is_[k][tp*8];
            *(float4*)&bb[4] = *(float4*)&is_[k][tp*8+4];
            #pragma unroll
            for (int i=0;i<8;++i)
                #pragma unroll
                for (int j=0;j<8;++j)
                    acc[i][j] += a[i]*bb[j];
        }
        __syncthreads();
    }
    #pragma unroll
    for (int i=0;i<8;++i) {
        int co = co0 + tc*8 + i;
        float bs = bias[co];
        size_t obase = ((size_t)bi*Cout + co)*PIX + px0 + tp*8;
        float r[8];
        #pragma unroll
        for (int j=0;j<8;++j) {
            float v = acc[i][j] + bs;
            if (DOGELU) v = gelu_f(v);
            r[j] = v;
        }
        if (DORES) {
            const float4 e0 = *(const float4*)(res + obase);
            const float4 e1 = *(const float4*)(res + obase + 4);
            r[0]+=e0.x; r[1]+=e0.y; r[2]+=e0.z; r[3]+=e0.w;
            r[4]+=e1.x; r[5]+=e1.y; r[6]+=e1.z; r[7]+=e1.w;
        }
        *(float4*)(out + obase)     = make_float4(r[0],r[1],r[2],r[3]);
        *(float4*)(out + obase + 4) = make_float4(r[4],r[5],r[6],r[7]);
    }
}

// ---------------- depthwise 3x3 pad1 + bias, out = gelu(conv)+in (per-batch) ----
__global__ __launch_bounds__(256) void dw3x3_kernel(const float* __restrict__ in,
    const float* __restrict__ w, const float* __restrict__ b,
    float* __restrict__ out)
{
    int t = blockIdx.x*256 + threadIdx.x;     // 256*PIX/4 threads
    int c = t / (PIX/4);
    int p4 = (t - c*(PIX/4)) * 4;
    int y = p4 / HWD, x0 = p4 - y*HWD;
    const float* ib = in + (size_t)c * PIX;
    float wk[9];
    #pragma unroll
    for (int e=0;e<9;++e) wk[e] = w[c*9+e];
    float bc = b[c];
    float a0=bc,a1=bc,a2=bc,a3=bc;
    #pragma unroll
    for (int ky=0;ky<3;++ky) {
        int yy = y + ky - 1;
        if ((unsigned)yy < (unsigned)HWD) {
            const float* row = ib + (size_t)yy*HWD;
            float v[6];
            #pragma unroll
            for (int d=0;d<6;++d) {
                int xx = x0 + d - 1;
                v[d] = ((unsigned)xx < (unsigned)HWD) ? row[xx] : 0.f;
            }
            a0 += v[0]*wk[ky*3+0] + v[1]*wk[ky*3+1] + v[2]*wk[ky*3+2];
            a1 += v[1]*wk[ky*3+0] + v[2]*wk[ky*3+1] + v[3]*wk[ky*3+2];
            a2 += v[2]*wk[ky*3+0] + v[3]*wk[ky*3+1] + v[4]*wk[ky*3+2];
            a3 += v[3]*wk[ky*3+0] + v[4]*wk[ky*3+1] + v[5]*wk[ky*3+2];
        }
    }
    const float4 cen = *(const float4*)(ib + (size_t)y*HWD + x0);
    float4 r;
    r.x = gelu_f(a0)+cen.x; r.y = gelu_f(a1)+cen.y;
    r.z = gelu_f(a2)+cen.z; r.w = gelu_f(a3)+cen.w;
    *(float4*)(out + (size_t)c*PIX + p4) = r;
}

// ---------------- window attention (per-batch; qkv = (384,PIX), o = (128,PIX)) -
__global__ __launch_bounds__(256) void attn_kernel(const float* __restrict__ qkv,
    const float* __restrict__ table, float* __restrict__ o)
{
    __shared__ float K[256][32];
    __shared__ float V[256][32];
    const int win = blockIdx.x, head = blockIdx.y;
    const int wy = win/12, wx = win - wy*12;
    const int t = threadIdx.x;
    const int iy = t >> 4, ix = t & 15;
    const int gy = wy*16 + iy, gx = wx*16 + ix;
    const size_t sp = (size_t)gy*HWD + gx;
    const float* qb = qkv + ((size_t)head*32) * PIX + sp;
    const float* kb = qkv + ((size_t)(128 + head*32)) * PIX + sp;
    const float* vb = qkv + ((size_t)(256 + head*32)) * PIX + sp;
    float q[32];
    #pragma unroll
    for (int cc=0;cc<32;++cc) {
        q[cc]     = qb[(size_t)cc*PIX];
        K[t][cc]  = kb[(size_t)cc*PIX];
        V[t][cc]  = vb[(size_t)cc*PIX];
    }
    __syncthreads();
    const float scale = 0.17677669529663687f;   // 32^-0.5
    const float* tb = table + head*961;
    float m = -1e30f, l = 0.f;
    float oacc[32];
    #pragma unroll
    for (int cc=0;cc<32;++cc) oacc[cc]=0.f;
    for (int kt=0; kt<256; ++kt) {
        float s = 0.f;
        const float* kr = &K[kt][0];
        #pragma unroll
        for (int cc=0;cc<32;cc+=4) {
            const float4 kv = *(const float4*)(kr + cc);
            s += q[cc]*kv.x + q[cc+1]*kv.y + q[cc+2]*kv.z + q[cc+3]*kv.w;
        }
        int kh = kt >> 4, kw = kt & 15;
        s = s*scale + tb[(kh - iy + 15)*31 + (kw - ix + 15)];
        float mn = fmaxf(m, s);
        float corr = __expf(m - mn);
        float p = __expf(s - mn);
        l = l*corr + p;
        const float* vr = &V[kt][0];
        #pragma unroll
        for (int cc=0;cc<32;cc+=4) {
            const float4 vv = *(const float4*)(vr + cc);
            oacc[cc]   = oacc[cc]  *corr + p*vv.x;
            oacc[cc+1] = oacc[cc+1]*corr + p*vv.y;
            oacc[cc+2] = oacc[cc+2]*corr + p*vv.z;
            oacc[cc+3] = oacc[cc+3]*corr + p*vv.w;
        }
        m = mn;
    }
    float invl = 1.f / l;
    float* ob = o + ((size_t)head*32) * PIX + sp;
    #pragma unroll
    for (int cc=0;cc<32;++cc) ob[(size_t)cc*PIX] = oacc[cc]*invl;
}

// ---------------- mean over spatial for channels 0..31 (full batch) ------------
__global__ __launch_bounds__(256) void meanpool_kernel(const float* __restrict__ in,
    float* __restrict__ v)
{
    int bc = blockIdx.x;               // BB*32
    int bi = bc >> 5, c = bc & 31;
    const float* base = in + ((size_t)bi*CCH + c) * PIX;
    float s = 0.f;
    for (int i = threadIdx.x; i < PIX/4; i += 256) {
        const float4 t4 = ((const float4*)base)[i];
        s += t4.x+t4.y+t4.z+t4.w;
    }
    #pragma unroll
    for (int off=32; off>0; off>>=1) s += __shfl_down(s, off, 64);
    __shared__ float red[4];
    if ((threadIdx.x & 63) == 0) red[threadIdx.x >> 6] = s;
    __syncthreads();
    if (threadIdx.x == 0) v[bc] = (red[0]+red[1]+red[2]+red[3]) * (1.f/PIX);
}

// ---------------- tiny MLP producing dynamic 3x3 kernels -----------------------
__global__ __launch_bounds__(256) void mlp_kernel(const float* __restrict__ v,
    const float* __restrict__ pw1, const float* __restrict__ pb1,
    const float* __restrict__ pw2, const float* __restrict__ pb2,
    float* __restrict__ dk)
{
    __shared__ float h[64];
    int tid = threadIdx.x;
    if (tid < 64) {
        int bi = tid >> 4, m = tid & 15;
        float s = pb1[m];
        for (int c=0;c<32;++c) s += v[bi*32+c]*pw1[m*32+c];
        h[tid] = gelu_f(s);
    }
    __syncthreads();
    for (int idx = tid; idx < BB*288; idx += 256) {
        int bi = idx / 288, j = idx - bi*288;
        float s = pb2[j];
        for (int m=0;m<16;++m) s += h[bi*16+m]*pw2[j*16+m];
        dk[idx] = s;
    }
}

// ---------------- weight transpose (CO,CI,T) -> (CI,T,CO) ----------------------
__global__ __launch_bounds__(256) void wtrans_kernel(const float* __restrict__ w,
    float* __restrict__ wt, int CO, int CI, int T)
{
    int idx = blockIdx.x*256 + threadIdx.x;
    if (idx >= CO*CI*T) return;
    int co = idx / (CI*T);
    int r = idx - co*CI*T;
    int ci = r / T;
    int tp = r - ci*T;
    wt[((size_t)ci*T + tp)*CO + co] = w[idx];
}

// ---------------- 13x13 dense conv 32->32 pad6 + fused dynamic dw3x3 -----------
// ci-split into 4 groups of 8; weights read wave-uniform (scalar broadcast);
// partial sums to partial[grp][bi][co][PIX]
__global__ __launch_bounds__(256) void conv13p_kernel(const float* __restrict__ in,
    const float* __restrict__ wt,   // [ci][169][32]
    const float* __restrict__ dk,   // [B*32][9]
    float* __restrict__ partial)    // [4][B][32][PIX]
{
    const int bi  = blockIdx.z;
    const int grp = blockIdx.y;             // 0..3
    const int tile = blockIdx.x;            // 144
    const int ty0 = (tile/12)*16, tx0 = (tile - (tile/12)*12)*16;
    const int ty = threadIdx.x >> 4, tx = threadIdx.x & 15;
    __shared__ float patch[28*28];
    float acc[32];
    #pragma unroll
    for (int i=0;i<32;++i) acc[i]=0.f;
    const float* inb = in + (size_t)bi * CCH * PIX;
    #pragma unroll 1
    for (int c8=0; c8<8; ++c8) {
        const int ci = grp*8 + c8;
        __syncthreads();
        for (int idx=threadIdx.x; idx<784; idx+=256) {
            int py = idx/28, px = idx - py*28;
            int gy = ty0 + py - 6, gx = tx0 + px - 6;
            patch[idx] = ((unsigned)gy < (unsigned)HWD && (unsigned)gx < (unsigned)HWD)
                         ? inb[(size_t)ci*PIX + (size_t)gy*HWD + gx] : 0.f;
        }
        __syncthreads();
        const float* wci = wt + (size_t)ci*169*32;
        #pragma unroll 1
        for (int dy=0; dy<13; ++dy) {
            const float* prow = &patch[(ty+dy)*28 + tx];
            const float* wrow = wci + dy*13*32;     // wave-uniform -> scalar loads
            #pragma unroll
            for (int dx=0; dx<13; ++dx) {
                float pv = prow[dx];
                const float* wr = wrow + dx*32;
                #pragma unroll
                for (int co=0;co<32;++co) acc[co] += pv*wr[co];
            }
        }
        // fused dynamic depthwise 3x3 (channel ci only)
        const float* dkk = dk + (bi*32 + ci)*9;
        float dsum = 0.f;
        #pragma unroll
        for (int e=0;e<9;++e) {
            int ey = e/3, ex = e - ey*3;
            dsum += patch[(ty+5+ey)*28 + (tx+5+ex)] * dkk[e];
        }
        #pragma unroll
        for (int co=0;co<32;++co) acc[co] += (co==ci) ? dsum : 0.f;
    }
    const int oy = ty0+ty, ox = tx0+tx;
    float* ob = partial + (((size_t)grp*BB + bi)*32)*PIX + (size_t)oy*HWD + ox;
    #pragma unroll
    for (int co=0;co<32;++co) ob[(size_t)co*PIX] = acc[co];
}

// ---------------- reduce 4 partials into channels 0..31 of (B,128,PIX) ---------
__global__ __launch_bounds__(256) void reduce13_kernel(const float* __restrict__ partial,
    float* __restrict__ dst)
{
    int idx = blockIdx.x*256 + threadIdx.x;      // BB*32*PIX/4
    int bc = idx / (PIX/4);
    int p4 = (idx - bc*(PIX/4)) * 4;
    int bi = bc >> 5, c = bc & 31;
    const size_t stride = (size_t)BB*32*PIX;
    const float* p0 = partial + ((size_t)bi*32 + c)*PIX + p4;
    float4 a = *(const float4*)(p0);
    const float4 b1 = *(const float4*)(p0 + stride);
    const float4 b2 = *(const float4*)(p0 + 2*stride);
    const float4 b3 = *(const float4*)(p0 + 3*stride);
    a.x += b1.x+b2.x+b3.x; a.y += b1.y+b2.y+b3.y;
    a.z += b1.z+b2.z+b3.z; a.w += b1.w+b2.w+b3.w;
    *(float4*)(dst + ((size_t)bi*CCH + c)*PIX + p4) = a;
}

// ---------------- final dense 3x3 conv 128->128 pad1 + bias + skip -------------
__global__ __launch_bounds__(256) void conv3x3_kernel(const float* __restrict__ in,
    const float* __restrict__ wt,    // [ci][9][128]
    const float* __restrict__ bias, const float* __restrict__ skip,
    float* __restrict__ out)
{
    const int bi = blockIdx.z;
    const int co0 = blockIdx.y * 32;
    const int tile = blockIdx.x;
    const int ty0 = (tile/12)*16, tx0 = (tile - (tile/12)*12)*16;
    const int ty = threadIdx.x >> 4, tx = threadIdx.x & 15;
    __shared__ float patch[18*18];
    float acc[32];
    #pragma unroll
    for (int i=0;i<32;++i) acc[i]=0.f;
    const float* inb = in + (size_t)bi * CCH * PIX;
    #pragma unroll 1
    for (int ci=0; ci<CCH; ++ci) {
        __syncthreads();
        for (int idx=threadIdx.x; idx<324; idx+=256) {
            int py = idx/18, px = idx - py*18;
            int gy = ty0 + py - 1, gx = tx0 + px - 1;
            patch[idx] = ((unsigned)gy < (unsigned)HWD && (unsigned)gx < (unsigned)HWD)
                         ? inb[(size_t)ci*PIX + (size_t)gy*HWD + gx] : 0.f;
        }
        __syncthreads();
        const float* wci = wt + (size_t)ci*9*CCH + co0;
        #pragma unroll
        for (int t=0;t<9;++t) {
            float pv = patch[(ty + t/3)*18 + tx + (t - (t/3)*3)];
            const float* wr = wci + t*CCH;
            #pragma unroll
            for (int co=0;co<32;++co) acc[co] += pv*wr[co];
        }
    }
    const int oy = ty0+ty, ox = tx0+tx;
    #pragma unroll
    for (int co=0;co<32;++co) {
        size_t o = ((size_t)bi*CCH + co0 + co)*PIX + (size_t)oy*HWD + ox;
        out[o] = acc[co] + bias[co0+co] + skip[o];
    }
}

extern "C" void kernel_launch(void* const* d_in, const int* in_sizes, int n_in,
                              void* d_out, int out_size, void* d_ws, size_t ws_size,
                              hipStream_t stream) {
    (void)in_sizes; (void)n_in; (void)out_size;
    const float* x_in      = (const float*)d_in[0];
    const float* plk       = (const float*)d_in[1];
    const float* ln_proj_w = (const float*)d_in[2];
    const float* ln_proj_b = (const float*)d_in[3];
    const float* proj_w1   = (const float*)d_in[4];
    const float* proj_b1   = (const float*)d_in[5];
    const float* proj_dw   = (const float*)d_in[6];
    const float* proj_dwb  = (const float*)d_in[7];
    const float* proj_w2   = (const float*)d_in[8];
    const float* proj_b2   = (const float*)d_in[9];
    const float* ln_attn_w = (const float*)d_in[10];
    const float* ln_attn_b = (const float*)d_in[11];
    const float* qkv_w     = (const float*)d_in[12];
    const float* qkv_b     = (const float*)d_in[13];
    const float* attn_ow   = (const float*)d_in[14];
    const float* attn_ob   = (const float*)d_in[15];
    const float* rpe       = (const float*)d_in[16];
    const float* ffn_w1    = (const float*)d_in[17];
    const float* ffn_b1    = (const float*)d_in[18];
    const float* ffn_dw    = (const float*)d_in[19];
    const float* ffn_dwb   = (const float*)d_in[20];
    const float* ffn_w2    = (const float*)d_in[21];
    const float* ffn_b2    = (const float*)d_in[22];
    const float* pk_w1     = (const float*)d_in[23];
    const float* pk_b1     = (const float*)d_in[24];
    const float* pk_w2     = (const float*)d_in[25];
    const float* pk_b2     = (const float*)d_in[26];
    const float* aggr_w    = (const float*)d_in[27];
    const float* aggr_b    = (const float*)d_in[28];
    const float* ln_out_w  = (const float*)d_in[29];
    const float* ln_out_b  = (const float*)d_in[30];
    const float* co_w      = (const float*)d_in[31];
    const float* co_b      = (const float*)d_in[32];
    float* out = (float*)d_out;

    const size_t N1b = (size_t)CCH * PIX;      // 4,718,592 (one batch, 128ch)
    const size_t NEb = (size_t)256 * PIX;      // 9,437,184 (one batch, 256ch)
    const size_t RAsz = (size_t)BB * N1b;      // 18,874,368
    const size_t EQsz = 2 * NEb;               // 18,874,368 (== 4*BB*32*PIX partials)
    const size_t need_floats = 2*RAsz + EQsz + 32*169*32 + 128*9*128 + 256 + BB*288;
    if (ws_size < need_floats * sizeof(float)) return;   // diagnostic guard

    float* ws  = (float*)d_ws;
    float* RA  = ws;
    float* RB  = RA + RAsz;
    float* EQ  = RB + RAsz;                    // aliased: E1/E2 | per-batch QKV | partials
    float* E1  = EQ;
    float* E2  = EQ + NEb;
    float* C13p = EQ;                          // 4*BB*32*PIX = 18,874,368 fits exactly
    float* WT13 = EQ + EQsz;                   // 32*169*32
    float* WT3  = WT13 + (size_t)32*169*32;    // 128*9*128
    float* VB   = WT3 + (size_t)128*9*128;     // 256
    float* DK   = VB + 256;                    // BB*288

    dim3 blk(256);

    // weight transposes
    wtrans_kernel<<<(32*32*169+255)/256, blk, 0, stream>>>(plk, WT13, 32, 32, 169);
    wtrans_kernel<<<(128*128*9+255)/256, blk, 0, stream>>>(co_w, WT3, 128, 128, 9);

    // x = conv_ffn(LN(x), proj)   [E buffers are per-batch -> loop b]
    ln_kernel<<<576, 64, 0, stream>>>(x_in, ln_proj_w, ln_proj_b, RA);
    for (int b=0;b<BB;++b) {
        conv1x1_kernel<true,false><<<dim3(288,2,1), blk, 0, stream>>>(RA + b*N1b, proj_w1, proj_b1, nullptr, E1, 128, 256);
        dw3x3_kernel<<<9216, blk, 0, stream>>>(E1, proj_dw, proj_dwb, E2);
        conv1x1_kernel<false,false><<<dim3(288,1,1), blk, 0, stream>>>(E2, proj_w2, proj_b2, nullptr, RB + b*N1b, 256, 128);
    }

    // x = x + window_attention(LN(x))
    ln_kernel<<<576, 64, 0, stream>>>(RB, ln_attn_w, ln_attn_b, RA);
    for (int b=0;b<BB;++b) {
        conv1x1_kernel<false,false><<<dim3(288,3,1), blk, 0, stream>>>(RA + b*N1b, qkv_w, qkv_b, nullptr, EQ, 128, 384);
        attn_kernel<<<dim3(144,4,1), blk, 0, stream>>>(EQ, rpe, RA + b*N1b);
    }
    conv1x1_kernel<false,true><<<dim3(288,1,BB), blk, 0, stream>>>(RA, attn_ow, attn_ob, RB, RB, 128, 128);

    // x lives in RB across the loop
    for (int i=0;i<2;++i) {
        const float* fw1 = ffn_w1 + (size_t)i*256*128;
        const float* fb1 = ffn_b1 + (size_t)i*256;
        const float* fdw = ffn_dw + (size_t)i*256*9;
        const float* fdb = ffn_dwb + (size_t)i*256;
        const float* fw2 = ffn_w2 + (size_t)i*128*256;
        const float* fb2 = ffn_b2 + (size_t)i*128;
        const float* w1i = pk_w1 + (size_t)i*16*32;
        const float* b1i = pk_b1 + (size_t)i*16;
        const float* w2i = pk_w2 + (size_t)i*288*16;
        const float* b2i = pk_b2 + (size_t)i*288;
        const float* awi = aggr_w + (size_t)i*128*128;
        const float* abi = aggr_b + (size_t)i*128;

        for (int b=0;b<BB;++b) {
            conv1x1_kernel<true,false><<<dim3(288,2,1), blk, 0, stream>>>(RB + b*N1b, fw1, fb1, nullptr, E1, 128, 256);
            dw3x3_kernel<<<9216, blk, 0, stream>>>(E1, fdw, fdb, E2);
            conv1x1_kernel<false,false><<<dim3(288,1,1), blk, 0, stream>>>(E2, fw2, fb2, nullptr, RA + b*N1b, 256, 128);
        }
        meanpool_kernel<<<BB*32, blk, 0, stream>>>(RA, VB);
        mlp_kernel<<<1, blk, 0, stream>>>(VB, w1i, b1i, w2i, b2i, DK);
        conv13p_kernel<<<dim3(144,4,BB), blk, 0, stream>>>(RA, WT13, DK, C13p);
        reduce13_kernel<<<(BB*32*(PIX/4))/256, blk, 0, stream>>>(C13p, RA);
        conv1x1_kernel<false,true><<<dim3(288,1,BB), blk, 0, stream>>>(RA, awi, abi, RB, RB, 128, 128);
    }

    // out = conv3x3(LN(x)) + bias + skip
    ln_kernel<<<576, 64, 0, stream>>>(RB, ln_out_w, ln_out_b, RA);
    conv3x3_kernel<<<dim3(144,4,BB), blk, 0, stream>>>(RA, WT3, co_b, x_in, out);
}

// Round 4
// 3344.892 us; speedup vs baseline: 1.7662x; 1.4119x over previous
//
#include <hip/hip_runtime.h>
#include <cmath>

#define HWD 192
#define PIX (HWD*HWD)      // 36864
#define BB  4
#define CCH 128

using short8 = __attribute__((ext_vector_type(8))) short;
using f32x4  = __attribute__((ext_vector_type(4))) float;

__device__ __forceinline__ float gelu_f(float x) {
    return 0.5f * x * (1.0f + erff(x * 0.70710678118654752f));
}
__device__ __forceinline__ unsigned short f2bf(float f) {
    unsigned int u = __float_as_uint(f);
    u += 0x7fff + ((u >> 16) & 1);          // round-to-nearest-even
    return (unsigned short)(u >> 16);
}

// ---------------- LayerNorm over channel axis (per b,h,w position) -------------
__global__ __launch_bounds__(64) void ln_kernel(const float* __restrict__ in,
        const float* __restrict__ w, const float* __restrict__ b,
        float* __restrict__ out)
{
    int t = blockIdx.x * 64 + threadIdx.x;        // BB*PIX/4 threads
    int bi = t / (PIX/4);
    int p  = (t - bi*(PIX/4)) * 4;
    const float* base = in + (size_t)bi * CCH * PIX + p;
    float s0=0,s1=0,s2=0,s3=0,q0=0,q1=0,q2=0,q3=0;
    for (int c=0;c<CCH;++c) {
        const float4 v = *(const float4*)(base + (size_t)c*PIX);
        s0+=v.x; s1+=v.y; s2+=v.z; s3+=v.w;
        q0+=v.x*v.x; q1+=v.y*v.y; q2+=v.z*v.z; q3+=v.w*v.w;
    }
    const float inv = 1.f/128.f;
    float m0=s0*inv, m1=s1*inv, m2=s2*inv, m3=s3*inv;
    float i0 = rsqrtf(q0*inv - m0*m0 + 1e-6f);
    float i1 = rsqrtf(q1*inv - m1*m1 + 1e-6f);
    float i2 = rsqrtf(q2*inv - m2*m2 + 1e-6f);
    float i3 = rsqrtf(q3*inv - m3*m3 + 1e-6f);
    float* ob = out + (size_t)bi * CCH * PIX + p;
    for (int c=0;c<CCH;++c) {
        const float4 v = *(const float4*)(base + (size_t)c*PIX);
        float wc = w[c], bc = b[c];
        float4 r;
        r.x=(v.x-m0)*i0*wc+bc; r.y=(v.y-m1)*i1*wc+bc;
        r.z=(v.z-m2)*i2*wc+bc; r.w=(v.w-m3)*i3*wc+bc;
        *(float4*)(ob + (size_t)c*PIX) = r;
    }
}

// ---------------- 1x1 conv via bf16 MFMA -------------------------------------
// block: 128co x 128px, 4 waves 2x2. X staged transposed [px][ci] bf16 in LDS.
// Cout inferred = gridDim.y*128; batch via blockIdx.z.
template<bool DOGELU, bool DORES>
__global__ __launch_bounds__(256) void conv1x1_mfma_kernel(
    const float* __restrict__ in,            // (z, Cin, PIX)
    const unsigned short* __restrict__ wq,   // (Cout, Cin) bf16
    const float* __restrict__ bias,
    const float* __restrict__ res,           // (z, Cout, PIX) or null
    float* __restrict__ out,                 // (z, Cout, PIX)
    int Cin)
{
    constexpr int CIP = 72;
    __shared__ unsigned short XL[128*CIP];
    const int Cout = gridDim.y * 128;
    const int px0 = blockIdx.x * 128;
    const int co0 = blockIdx.y * 128;
    const size_t bi = blockIdx.z;
    in  += bi * (size_t)Cin * PIX;
    out += bi * (size_t)Cout * PIX;
    if (DORES) res += bi * (size_t)Cout * PIX;
    const int tid = threadIdx.x;
    const int lane = tid & 63, wid = tid >> 6;
    const int wco = (wid >> 1) * 64;
    const int wpx = (wid & 1) * 64;
    const int l15 = lane & 15, l4 = lane >> 4;

    f32x4 acc[4][4];
    #pragma unroll
    for (int i=0;i<4;++i)
        #pragma unroll
        for (int j=0;j<4;++j) acc[i][j] = (f32x4){0.f,0.f,0.f,0.f};

    for (int k0 = 0; k0 < Cin; k0 += 64) {
        __syncthreads();
        // stage 128px x 64ci, transposed, fp32->bf16
        #pragma unroll
        for (int it = 0; it < 8; ++it) {
            int f = tid + it*256;            // 0..2047
            int px = f & 127;
            int ci = (f >> 7) * 4;           // 0..60
            const float* gp = in + (size_t)(k0+ci)*PIX + px0 + px;
            float v0 = gp[0];
            float v1 = gp[PIX];
            float v2 = gp[2*PIX];
            float v3 = gp[3*PIX];
            uint2 pk;
            pk.x = (unsigned)f2bf(v0) | ((unsigned)f2bf(v1) << 16);
            pk.y = (unsigned)f2bf(v2) | ((unsigned)f2bf(v3) << 16);
            *(uint2*)&XL[px*CIP + ci] = pk;
        }
        __syncthreads();
        #pragma unroll
        for (int ks = 0; ks < 2; ++ks) {
            short8 a[4];
            #pragma unroll
            for (int mt=0; mt<4; ++mt) {
                int co = co0 + wco + mt*16 + l15;
                a[mt] = *(const short8*)(wq + (size_t)co*Cin + k0 + ks*32 + l4*8);
            }
            #pragma unroll
            for (int nt=0; nt<4; ++nt) {
                const short8 b = *(const short8*)&XL[(wpx + nt*16 + l15)*CIP + ks*32 + l4*8];
                #pragma unroll
                for (int mt=0; mt<4; ++mt)
                    acc[mt][nt] = __builtin_amdgcn_mfma_f32_16x16x32_bf16(a[mt], b, acc[mt][nt], 0, 0, 0);
            }
        }
    }
    #pragma unroll
    for (int mt=0; mt<4; ++mt) {
        #pragma unroll
        for (int r=0; r<4; ++r) {
            int co = co0 + wco + mt*16 + l4*4 + r;
            float bs = bias[co];
            #pragma unroll
            for (int nt=0; nt<4; ++nt) {
                int px = px0 + wpx + nt*16 + l15;
                float v = acc[mt][nt][r] + bs;
                if (DOGELU) v = gelu_f(v);
                size_t o = (size_t)co*PIX + px;
                if (DORES) v += res[o];
                out[o] = v;
            }
        }
    }
}

// ---------------- 3x3 dense conv 128->128 via bf16 MFMA + bias + skip ----------
// block: 128co x (2 rows x 64 x). X staged with halo [4 rows][66 x][32 ci] bf16.
__global__ __launch_bounds__(256) void conv3x3_mfma_kernel(
    const float* __restrict__ in,            // (B,128,PIX)
    const unsigned short* __restrict__ wq,   // (128,9,128) bf16 [co][tap][ci]
    const float* __restrict__ bias, const float* __restrict__ skip,
    float* __restrict__ out)
{
    constexpr int CIP = 40;
    __shared__ unsigned short XL[4*66*CIP];
    const int x0 = blockIdx.x * 64;          // 0..2
    const int y0 = blockIdx.y * 2;           // 0..95
    const int bi = blockIdx.z;
    const int tid = threadIdx.x;
    const int lane = tid & 63, wid = tid >> 6;
    const int wco = (wid >> 1) * 64;
    const int wrow = wid & 1;
    const int l15 = lane & 15, l4 = lane >> 4;
    const float* inb = in + (size_t)bi * CCH * PIX;

    f32x4 acc[4][4];
    #pragma unroll
    for (int i=0;i<4;++i)
        #pragma unroll
        for (int j=0;j<4;++j) acc[i][j] = (f32x4){0.f,0.f,0.f,0.f};

    for (int ci0 = 0; ci0 < 128; ci0 += 32) {
        __syncthreads();
        // stage 4 rows x 66 x x 32 ci (zero-pad OOB)
        for (int it = 0; it < 33; ++it) {
            int idx = tid + it*256;          // 0..8447
            int ci = idx / 264;
            int rem = idx - ci*264;
            int row = rem / 66;
            int x = rem - row*66;
            int gy = y0 - 1 + row, gx = x0 - 1 + x;
            float v = ((unsigned)gy < (unsigned)HWD && (unsigned)gx < (unsigned)HWD)
                      ? inb[(size_t)(ci0+ci)*PIX + (size_t)gy*HWD + gx] : 0.f;
            XL[(row*66 + x)*CIP + ci] = f2bf(v);
        }
        __syncthreads();
        #pragma unroll
        for (int dy=0; dy<3; ++dy) {
            #pragma unroll
            for (int dx=0; dx<3; ++dx) {
                short8 a[4];
                #pragma unroll
                for (int mt=0; mt<4; ++mt) {
                    int co = wco + mt*16 + l15;
                    a[mt] = *(const short8*)(wq + ((size_t)co*9 + dy*3+dx)*128 + ci0 + l4*8);
                }
                const int rl = wrow + dy;    // 0..3
                #pragma unroll
                for (int nt=0; nt<4; ++nt) {
                    const int xl = nt*16 + l15 + dx;   // 0..65
                    const short8 b = *(const short8*)&XL[(rl*66 + xl)*CIP + l4*8];
                    #pragma unroll
                    for (int mt=0; mt<4; ++mt)
                        acc[mt][nt] = __builtin_amdgcn_mfma_f32_16x16x32_bf16(a[mt], b, acc[mt][nt], 0, 0, 0);
                }
            }
        }
    }
    const int gy = y0 + wrow;
    #pragma unroll
    for (int mt=0; mt<4; ++mt) {
        #pragma unroll
        for (int r=0; r<4; ++r) {
            int co = wco + mt*16 + l4*4 + r;
            float bs = bias[co];
            #pragma unroll
            for (int nt=0; nt<4; ++nt) {
                int gx = x0 + nt*16 + l15;
                size_t o = ((size_t)bi*CCH + co)*PIX + (size_t)gy*HWD + gx;
                out[o] = acc[mt][nt][r] + bs + skip[o];
            }
        }
    }
}

// ---------------- depthwise 3x3 pad1 + bias, out = gelu(conv)+in (per-batch) ----
__global__ __launch_bounds__(256) void dw3x3_kernel(const float* __restrict__ in,
    const float* __restrict__ w, const float* __restrict__ b,
    float* __restrict__ out)
{
    int t = blockIdx.x*256 + threadIdx.x;     // 256*PIX/4 threads
    int c = t / (PIX/4);
    int p4 = (t - c*(PIX/4)) * 4;
    int y = p4 / HWD, x0 = p4 - y*HWD;
    const float* ib = in + (size_t)c * PIX;
    float wk[9];
    #pragma unroll
    for (int e=0;e<9;++e) wk[e] = w[c*9+e];
    float bc = b[c];
    float a0=bc,a1=bc,a2=bc,a3=bc;
    #pragma unroll
    for (int ky=0;ky<3;++ky) {
        int yy = y + ky - 1;
        if ((unsigned)yy < (unsigned)HWD) {
            const float* row = ib + (size_t)yy*HWD;
            float v[6];
            #pragma unroll
            for (int d=0;d<6;++d) {
                int xx = x0 + d - 1;
                v[d] = ((unsigned)xx < (unsigned)HWD) ? row[xx] : 0.f;
            }
            a0 += v[0]*wk[ky*3+0] + v[1]*wk[ky*3+1] + v[2]*wk[ky*3+2];
            a1 += v[1]*wk[ky*3+0] + v[2]*wk[ky*3+1] + v[3]*wk[ky*3+2];
            a2 += v[2]*wk[ky*3+0] + v[3]*wk[ky*3+1] + v[4]*wk[ky*3+2];
            a3 += v[3]*wk[ky*3+0] + v[4]*wk[ky*3+1] + v[5]*wk[ky*3+2];
        }
    }
    const float4 cen = *(const float4*)(ib + (size_t)y*HWD + x0);
    float4 r;
    r.x = gelu_f(a0)+cen.x; r.y = gelu_f(a1)+cen.y;
    r.z = gelu_f(a2)+cen.z; r.w = gelu_f(a3)+cen.w;
    *(float4*)(out + (size_t)c*PIX + p4) = r;
}

// ---------------- window attention (per-batch; qkv = (384,PIX), o = (128,PIX)) -
__global__ __launch_bounds__(256) void attn_kernel(const float* __restrict__ qkv,
    const float* __restrict__ table, float* __restrict__ o)
{
    __shared__ float K[256][32];
    __shared__ float V[256][32];
    const int win = blockIdx.x, head = blockIdx.y;
    const int wy = win/12, wx = win - wy*12;
    const int t = threadIdx.x;
    const int iy = t >> 4, ix = t & 15;
    const int gy = wy*16 + iy, gx = wx*16 + ix;
    const size_t sp = (size_t)gy*HWD + gx;
    const float* qb = qkv + ((size_t)head*32) * PIX + sp;
    const float* kb = qkv + ((size_t)(128 + head*32)) * PIX + sp;
    const float* vb = qkv + ((size_t)(256 + head*32)) * PIX + sp;
    float q[32];
    #pragma unroll
    for (int cc=0;cc<32;++cc) {
        q[cc]     = qb[(size_t)cc*PIX];
        K[t][cc]  = kb[(size_t)cc*PIX];
        V[t][cc]  = vb[(size_t)cc*PIX];
    }
    __syncthreads();
    const float scale = 0.17677669529663687f;   // 32^-0.5
    const float* tb = table + head*961;
    float m = -1e30f, l = 0.f;
    float oacc[32];
    #pragma unroll
    for (int cc=0;cc<32;++cc) oacc[cc]=0.f;
    for (int kt=0; kt<256; ++kt) {
        float s = 0.f;
        const float* kr = &K[kt][0];
        #pragma unroll
        for (int cc=0;cc<32;cc+=4) {
            const float4 kv = *(const float4*)(kr + cc);
            s += q[cc]*kv.x + q[cc+1]*kv.y + q[cc+2]*kv.z + q[cc+3]*kv.w;
        }
        int kh = kt >> 4, kw = kt & 15;
        s = s*scale + tb[(kh - iy + 15)*31 + (kw - ix + 15)];
        float mn = fmaxf(m, s);
        float corr = __expf(m - mn);
        float p = __expf(s - mn);
        l = l*corr + p;
        const float* vr = &V[kt][0];
        #pragma unroll
        for (int cc=0;cc<32;cc+=4) {
            const float4 vv = *(const float4*)(vr + cc);
            oacc[cc]   = oacc[cc]  *corr + p*vv.x;
            oacc[cc+1] = oacc[cc+1]*corr + p*vv.y;
            oacc[cc+2] = oacc[cc+2]*corr + p*vv.z;
            oacc[cc+3] = oacc[cc+3]*corr + p*vv.w;
        }
        m = mn;
    }
    float invl = 1.f / l;
    float* ob = o + ((size_t)head*32) * PIX + sp;
    #pragma unroll
    for (int cc=0;cc<32;++cc) ob[(size_t)cc*PIX] = oacc[cc]*invl;
}

// ---------------- mean over spatial for channels 0..31 (full batch) ------------
__global__ __launch_bounds__(256) void meanpool_kernel(const float* __restrict__ in,
    float* __restrict__ v)
{
    int bc = blockIdx.x;               // BB*32
    int bi = bc >> 5, c = bc & 31;
    const float* base = in + ((size_t)bi*CCH + c) * PIX;
    float s = 0.f;
    for (int i = threadIdx.x; i < PIX/4; i += 256) {
        const float4 t4 = ((const float4*)base)[i];
        s += t4.x+t4.y+t4.z+t4.w;
    }
    #pragma unroll
    for (int off=32; off>0; off>>=1) s += __shfl_down(s, off, 64);
    __shared__ float red[4];
    if ((threadIdx.x & 63) == 0) red[threadIdx.x >> 6] = s;
    __syncthreads();
    if (threadIdx.x == 0) v[bc] = (red[0]+red[1]+red[2]+red[3]) * (1.f/PIX);
}

// ---------------- tiny MLP producing dynamic 3x3 kernels -----------------------
__global__ __launch_bounds__(256) void mlp_kernel(const float* __restrict__ v,
    const float* __restrict__ pw1, const float* __restrict__ pb1,
    const float* __restrict__ pw2, const float* __restrict__ pb2,
    float* __restrict__ dk)
{
    __shared__ float h[64];
    int tid = threadIdx.x;
    if (tid < 64) {
        int bi = tid >> 4, m = tid & 15;
        float s = pb1[m];
        for (int c=0;c<32;++c) s += v[bi*32+c]*pw1[m*32+c];
        h[tid] = gelu_f(s);
    }
    __syncthreads();
    for (int idx = tid; idx < BB*288; idx += 256) {
        int bi = idx / 288, j = idx - bi*288;
        float s = pb2[j];
        for (int m=0;m<16;++m) s += h[bi*16+m]*pw2[j*16+m];
        dk[idx] = s;
    }
}

// ---------------- weight transpose (CO,CI,T) -> (CI,T,CO) ----------------------
__global__ __launch_bounds__(256) void wtrans_kernel(const float* __restrict__ w,
    float* __restrict__ wt, int CO, int CI, int T)
{
    int idx = blockIdx.x*256 + threadIdx.x;
    if (idx >= CO*CI*T) return;
    int co = idx / (CI*T);
    int r = idx - co*CI*T;
    int ci = r / T;
    int tp = r - ci*T;
    wt[((size_t)ci*T + tp)*CO + co] = w[idx];
}

// ---------------- fp32 -> bf16 cast (same layout) ------------------------------
__global__ __launch_bounds__(256) void wcast_kernel(const float* __restrict__ w,
    unsigned short* __restrict__ wq, int n)
{
    int idx = blockIdx.x*256 + threadIdx.x;
    if (idx < n) wq[idx] = f2bf(w[idx]);
}

// ---------------- co_w (128,128,3,3) -> bf16 [co][tap][ci] ---------------------
__global__ __launch_bounds__(256) void w3cast_kernel(const float* __restrict__ w,
    unsigned short* __restrict__ wq)
{
    int idx = blockIdx.x*256 + threadIdx.x;     // 128*128*9
    if (idx >= 128*128*9) return;
    int co = idx / (128*9);
    int rem = idx - co*128*9;
    int ci = rem / 9;
    int tap = rem - ci*9;
    wq[((size_t)co*9 + tap)*128 + ci] = f2bf(w[idx]);
}

// ---------------- 13x13 dense conv 32->32 pad6 + fused dynamic dw3x3 -----------
__global__ __launch_bounds__(256) void conv13p_kernel(const float* __restrict__ in,
    const float* __restrict__ wt,   // [ci][169][32]
    const float* __restrict__ dk,   // [B*32][9]
    float* __restrict__ partial)    // [4][B][32][PIX]
{
    const int bi  = blockIdx.z;
    const int grp = blockIdx.y;             // 0..3
    const int tile = blockIdx.x;            // 144
    const int ty0 = (tile/12)*16, tx0 = (tile - (tile/12)*12)*16;
    const int ty = threadIdx.x >> 4, tx = threadIdx.x & 15;
    __shared__ float patch[28*28];
    float acc[32];
    #pragma unroll
    for (int i=0;i<32;++i) acc[i]=0.f;
    const float* inb = in + (size_t)bi * CCH * PIX;
    #pragma unroll 1
    for (int c8=0; c8<8; ++c8) {
        const int ci = grp*8 + c8;
        __syncthreads();
        for (int idx=threadIdx.x; idx<784; idx+=256) {
            int py = idx/28, px = idx - py*28;
            int gy = ty0 + py - 6, gx = tx0 + px - 6;
            patch[idx] = ((unsigned)gy < (unsigned)HWD && (unsigned)gx < (unsigned)HWD)
                         ? inb[(size_t)ci*PIX + (size_t)gy*HWD + gx] : 0.f;
        }
        __syncthreads();
        const float* wci = wt + (size_t)ci*169*32;
        #pragma unroll 1
        for (int dy=0; dy<13; ++dy) {
            const float* prow = &patch[(ty+dy)*28 + tx];
            const float* wrow = wci + dy*13*32;     // wave-uniform -> scalar loads
            #pragma unroll
            for (int dx=0; dx<13; ++dx) {
                float pv = prow[dx];
                const float* wr = wrow + dx*32;
                #pragma unroll
                for (int co=0;co<32;++co) acc[co] += pv*wr[co];
            }
        }
        const float* dkk = dk + (bi*32 + ci)*9;
        float dsum = 0.f;
        #pragma unroll
        for (int e=0;e<9;++e) {
            int ey = e/3, ex = e - ey*3;
            dsum += patch[(ty+5+ey)*28 + (tx+5+ex)] * dkk[e];
        }
        #pragma unroll
        for (int co=0;co<32;++co) acc[co] += (co==ci) ? dsum : 0.f;
    }
    const int oy = ty0+ty, ox = tx0+tx;
    float* ob = partial + (((size_t)grp*BB + bi)*32)*PIX + (size_t)oy*HWD + ox;
    #pragma unroll
    for (int co=0;co<32;++co) ob[(size_t)co*PIX] = acc[co];
}

// ---------------- reduce 4 partials into channels 0..31 of (B,128,PIX) ---------
__global__ __launch_bounds__(256) void reduce13_kernel(const float* __restrict__ partial,
    float* __restrict__ dst)
{
    int idx = blockIdx.x*256 + threadIdx.x;      // BB*32*PIX/4
    int bc = idx / (PIX/4);
    int p4 = (idx - bc*(PIX/4)) * 4;
    int bi = bc >> 5, c = bc & 31;
    const size_t stride = (size_t)BB*32*PIX;
    const float* p0 = partial + ((size_t)bi*32 + c)*PIX + p4;
    float4 a = *(const float4*)(p0);
    const float4 b1 = *(const float4*)(p0 + stride);
    const float4 b2 = *(const float4*)(p0 + 2*stride);
    const float4 b3 = *(const float4*)(p0 + 3*stride);
    a.x += b1.x+b2.x+b3.x; a.y += b1.y+b2.y+b3.y;
    a.z += b1.z+b2.z+b3.z; a.w += b1.w+b2.w+b3.w;
    *(float4*)(dst + ((size_t)bi*CCH + c)*PIX + p4) = a;
}

extern "C" void kernel_launch(void* const* d_in, const int* in_sizes, int n_in,
                              void* d_out, int out_size, void* d_ws, size_t ws_size,
                              hipStream_t stream) {
    (void)in_sizes; (void)n_in; (void)out_size;
    const float* x_in      = (const float*)d_in[0];
    const float* plk       = (const float*)d_in[1];
    const float* ln_proj_w = (const float*)d_in[2];
    const float* ln_proj_b = (const float*)d_in[3];
    const float* proj_w1   = (const float*)d_in[4];
    const float* proj_b1   = (const float*)d_in[5];
    const float* proj_dw   = (const float*)d_in[6];
    const float* proj_dwb  = (const float*)d_in[7];
    const float* proj_w2   = (const float*)d_in[8];
    const float* proj_b2   = (const float*)d_in[9];
    const float* ln_attn_w = (const float*)d_in[10];
    const float* ln_attn_b = (const float*)d_in[11];
    const float* qkv_w     = (const float*)d_in[12];
    const float* qkv_b     = (const float*)d_in[13];
    const float* attn_ow   = (const float*)d_in[14];
    const float* attn_ob   = (const float*)d_in[15];
    const float* rpe       = (const float*)d_in[16];
    const float* ffn_w1    = (const float*)d_in[17];
    const float* ffn_b1    = (const float*)d_in[18];
    const float* ffn_dw    = (const float*)d_in[19];
    const float* ffn_dwb   = (const float*)d_in[20];
    const float* ffn_w2    = (const float*)d_in[21];
    const float* ffn_b2    = (const float*)d_in[22];
    const float* pk_w1     = (const float*)d_in[23];
    const float* pk_b1     = (const float*)d_in[24];
    const float* pk_w2     = (const float*)d_in[25];
    const float* pk_b2     = (const float*)d_in[26];
    const float* aggr_w    = (const float*)d_in[27];
    const float* aggr_b    = (const float*)d_in[28];
    const float* ln_out_w  = (const float*)d_in[29];
    const float* ln_out_b  = (const float*)d_in[30];
    const float* co_w      = (const float*)d_in[31];
    const float* co_b      = (const float*)d_in[32];
    float* out = (float*)d_out;

    const size_t N1b = (size_t)CCH * PIX;      // 4,718,592 (one batch, 128ch)
    const size_t NEb = (size_t)256 * PIX;      // 9,437,184 (one batch, 256ch)
    const size_t RAsz = (size_t)BB * N1b;      // 18,874,368
    const size_t EQsz = 2 * NEb;               // 18,874,368 (== 4*BB*32*PIX partials)
    const size_t QTOT = 442368;                // total bf16 weight elems (ushort)
    const size_t need_floats = 2*RAsz + EQsz + (size_t)32*169*32 + 256 + 1152 + QTOT/2 + 16;
    if (ws_size < need_floats * sizeof(float)) return;   // diagnostic guard

    float* ws  = (float*)d_ws;
    float* RA  = ws;
    float* RB  = RA + RAsz;
    float* EQ  = RB + RAsz;                    // aliased: E1/E2 | per-batch QKV | partials
    float* E1  = EQ;
    float* E2  = EQ + NEb;
    float* C13p = EQ;                          // 4*BB*32*PIX = 18,874,368 fits exactly
    float* WT13 = EQ + EQsz;                   // 32*169*32 = 173,056
    float* VB   = WT13 + (size_t)32*169*32;    // 256
    float* DK   = VB + 256;                    // 1152
    unsigned short* Q0  = (unsigned short*)(DK + 1152);
    unsigned short* qPW1 = Q0;                 // 256*128
    unsigned short* qPW2 = qPW1 + 32768;       // 128*256
    unsigned short* qQKV = qPW2 + 32768;       // 384*128
    unsigned short* qAT  = qQKV + 49152;       // 128*128
    unsigned short* qF1  = qAT  + 16384;       // 2*256*128
    unsigned short* qF2  = qF1  + 65536;       // 2*128*256
    unsigned short* qAG  = qF2  + 65536;       // 2*128*128
    unsigned short* qW3  = qAG  + 32768;       // 128*9*128

    dim3 blk(256);

    // ---- weight prep ----
    wtrans_kernel<<<(32*32*169+255)/256, blk, 0, stream>>>(plk, WT13, 32, 32, 169);
    wcast_kernel<<<128, blk, 0, stream>>>(proj_w1, qPW1, 32768);
    wcast_kernel<<<128, blk, 0, stream>>>(proj_w2, qPW2, 32768);
    wcast_kernel<<<192, blk, 0, stream>>>(qkv_w, qQKV, 49152);
    wcast_kernel<<<64,  blk, 0, stream>>>(attn_ow, qAT, 16384);
    wcast_kernel<<<256, blk, 0, stream>>>(ffn_w1, qF1, 65536);
    wcast_kernel<<<256, blk, 0, stream>>>(ffn_w2, qF2, 65536);
    wcast_kernel<<<128, blk, 0, stream>>>(aggr_w, qAG, 32768);
    w3cast_kernel<<<576, blk, 0, stream>>>(co_w, qW3);

    // x = conv_ffn(LN(x), proj)   [E buffers are per-batch -> loop b]
    ln_kernel<<<576, 64, 0, stream>>>(x_in, ln_proj_w, ln_proj_b, RA);
    for (int b=0;b<BB;++b) {
        conv1x1_mfma_kernel<true,false><<<dim3(288,2,1), blk, 0, stream>>>(RA + b*N1b, qPW1, proj_b1, nullptr, E1, 128);
        dw3x3_kernel<<<9216, blk, 0, stream>>>(E1, proj_dw, proj_dwb, E2);
        conv1x1_mfma_kernel<false,false><<<dim3(288,1,1), blk, 0, stream>>>(E2, qPW2, proj_b2, nullptr, RB + b*N1b, 256);
    }

    // x = x + window_attention(LN(x))
    ln_kernel<<<576, 64, 0, stream>>>(RB, ln_attn_w, ln_attn_b, RA);
    for (int b=0;b<BB;++b) {
        conv1x1_mfma_kernel<false,false><<<dim3(288,3,1), blk, 0, stream>>>(RA + b*N1b, qQKV, qkv_b, nullptr, EQ, 128);
        attn_kernel<<<dim3(144,4,1), blk, 0, stream>>>(EQ, rpe, RA + b*N1b);
    }
    conv1x1_mfma_kernel<false,true><<<dim3(288,1,BB), blk, 0, stream>>>(RA, qAT, attn_ob, RB, RB, 128);

    // x lives in RB across the loop
    for (int i=0;i<2;++i) {
        const float* fb1 = ffn_b1 + (size_t)i*256;
        const float* fdw = ffn_dw + (size_t)i*256*9;
        const float* fdb = ffn_dwb + (size_t)i*256;
        const float* fb2 = ffn_b2 + (size_t)i*128;
        const float* w1i = pk_w1 + (size_t)i*16*32;
        const float* b1i = pk_b1 + (size_t)i*16;
        const float* w2i = pk_w2 + (size_t)i*288*16;
        const float* b2i = pk_b2 + (size_t)i*288;
        const float* abi = aggr_b + (size_t)i*128;

        for (int b=0;b<BB;++b) {
            conv1x1_mfma_kernel<true,false><<<dim3(288,2,1), blk, 0, stream>>>(RB + b*N1b, qF1 + (size_t)i*32768, fb1, nullptr, E1, 128);
            dw3x3_kernel<<<9216, blk, 0, stream>>>(E1, fdw, fdb, E2);
            conv1x1_mfma_kernel<false,false><<<dim3(288,1,1), blk, 0, stream>>>(E2, qF2 + (size_t)i*32768, fb2, nullptr, RA + b*N1b, 256);
        }
        meanpool_kernel<<<BB*32, blk, 0, stream>>>(RA, VB);
        mlp_kernel<<<1, blk, 0, stream>>>(VB, w1i, b1i, w2i, b2i, DK);
        conv13p_kernel<<<dim3(144,4,BB), blk, 0, stream>>>(RA, WT13, DK, C13p);
        reduce13_kernel<<<(BB*32*(PIX/4))/256, blk, 0, stream>>>(C13p, RA);
        conv1x1_mfma_kernel<false,true><<<dim3(288,1,BB), blk, 0, stream>>>(RA, qAG + (size_t)i*16384, abi, RB, RB, 128);
    }

    // out = conv3x3(LN(x)) + bias + skip
    ln_kernel<<<576, 64, 0, stream>>>(RB, ln_out_w, ln_out_b, RA);
    conv3x3_mfma_kernel<<<dim3(3,96,BB), blk, 0, stream>>>(RA, qW3, co_b, x_in, out);
}

// Round 5
// 2853.158 us; speedup vs baseline: 2.0706x; 1.1723x over previous
//
#include <hip/hip_runtime.h>
#include <cmath>

#define HWD 192
#define PIX (HWD*HWD)      // 36864
#define BB  4
#define CCH 128

using short8 = __attribute__((ext_vector_type(8))) short;
using f32x4  = __attribute__((ext_vector_type(4))) float;

__device__ __forceinline__ float gelu_f(float x) {
    return 0.5f * x * (1.0f + erff(x * 0.70710678118654752f));
}
__device__ __forceinline__ unsigned short f2bf(float f) {
    unsigned int u = __float_as_uint(f);
    u += 0x7fff + ((u >> 16) & 1);          // round-to-nearest-even
    return (unsigned short)(u >> 16);
}
__device__ __forceinline__ float bf2f(unsigned short s) {
    return __uint_as_float((unsigned int)s << 16);
}

// ---------------- LayerNorm over channel axis (per b,h,w position) -------------
__global__ __launch_bounds__(64) void ln_kernel(const float* __restrict__ in,
        const float* __restrict__ w, const float* __restrict__ b,
        float* __restrict__ out)
{
    int t = blockIdx.x * 64 + threadIdx.x;        // BB*PIX/4 threads
    int bi = t / (PIX/4);
    int p  = (t - bi*(PIX/4)) * 4;
    const float* base = in + (size_t)bi * CCH * PIX + p;
    float s0=0,s1=0,s2=0,s3=0,q0=0,q1=0,q2=0,q3=0;
    for (int c=0;c<CCH;++c) {
        const float4 v = *(const float4*)(base + (size_t)c*PIX);
        s0+=v.x; s1+=v.y; s2+=v.z; s3+=v.w;
        q0+=v.x*v.x; q1+=v.y*v.y; q2+=v.z*v.z; q3+=v.w*v.w;
    }
    const float inv = 1.f/128.f;
    float m0=s0*inv, m1=s1*inv, m2=s2*inv, m3=s3*inv;
    float i0 = rsqrtf(q0*inv - m0*m0 + 1e-6f);
    float i1 = rsqrtf(q1*inv - m1*m1 + 1e-6f);
    float i2 = rsqrtf(q2*inv - m2*m2 + 1e-6f);
    float i3 = rsqrtf(q3*inv - m3*m3 + 1e-6f);
    float* ob = out + (size_t)bi * CCH * PIX + p;
    for (int c=0;c<CCH;++c) {
        const float4 v = *(const float4*)(base + (size_t)c*PIX);
        float wc = w[c], bc = b[c];
        float4 r;
        r.x=(v.x-m0)*i0*wc+bc; r.y=(v.y-m1)*i1*wc+bc;
        r.z=(v.z-m2)*i2*wc+bc; r.w=(v.w-m3)*i3*wc+bc;
        *(float4*)(ob + (size_t)c*PIX) = r;
    }
}

// ---------------- 1x1 conv via bf16 MFMA -------------------------------------
template<bool DOGELU, bool DORES>
__global__ __launch_bounds__(256) void conv1x1_mfma_kernel(
    const float* __restrict__ in,            // (z, Cin, PIX)
    const unsigned short* __restrict__ wq,   // (Cout, Cin) bf16
    const float* __restrict__ bias,
    const float* __restrict__ res,           // (z, Cout, PIX) or null
    float* __restrict__ out,                 // (z, Cout, PIX)
    int Cin)
{
    constexpr int CIP = 72;
    __shared__ unsigned short XL[128*CIP];
    const int Cout = gridDim.y * 128;
    const int px0 = blockIdx.x * 128;
    const int co0 = blockIdx.y * 128;
    const size_t bi = blockIdx.z;
    in  += bi * (size_t)Cin * PIX;
    out += bi * (size_t)Cout * PIX;
    if (DORES) res += bi * (size_t)Cout * PIX;
    const int tid = threadIdx.x;
    const int lane = tid & 63, wid = tid >> 6;
    const int wco = (wid >> 1) * 64;
    const int wpx = (wid & 1) * 64;
    const int l15 = lane & 15, l4 = lane >> 4;

    f32x4 acc[4][4];
    #pragma unroll
    for (int i=0;i<4;++i)
        #pragma unroll
        for (int j=0;j<4;++j) acc[i][j] = (f32x4){0.f,0.f,0.f,0.f};

    for (int k0 = 0; k0 < Cin; k0 += 64) {
        __syncthreads();
        #pragma unroll
        for (int it = 0; it < 8; ++it) {
            int f = tid + it*256;            // 0..2047
            int px = f & 127;
            int ci = (f >> 7) * 4;           // 0..60
            const float* gp = in + (size_t)(k0+ci)*PIX + px0 + px;
            float v0 = gp[0];
            float v1 = gp[PIX];
            float v2 = gp[2*PIX];
            float v3 = gp[3*PIX];
            uint2 pk;
            pk.x = (unsigned)f2bf(v0) | ((unsigned)f2bf(v1) << 16);
            pk.y = (unsigned)f2bf(v2) | ((unsigned)f2bf(v3) << 16);
            *(uint2*)&XL[px*CIP + ci] = pk;
        }
        __syncthreads();
        #pragma unroll
        for (int ks = 0; ks < 2; ++ks) {
            short8 a[4];
            #pragma unroll
            for (int mt=0; mt<4; ++mt) {
                int co = co0 + wco + mt*16 + l15;
                a[mt] = *(const short8*)(wq + (size_t)co*Cin + k0 + ks*32 + l4*8);
            }
            #pragma unroll
            for (int nt=0; nt<4; ++nt) {
                const short8 b = *(const short8*)&XL[(wpx + nt*16 + l15)*CIP + ks*32 + l4*8];
                #pragma unroll
                for (int mt=0; mt<4; ++mt)
                    acc[mt][nt] = __builtin_amdgcn_mfma_f32_16x16x32_bf16(a[mt], b, acc[mt][nt], 0, 0, 0);
            }
        }
    }
    #pragma unroll
    for (int mt=0; mt<4; ++mt) {
        #pragma unroll
        for (int r=0; r<4; ++r) {
            int co = co0 + wco + mt*16 + l4*4 + r;
            float bs = bias[co];
            #pragma unroll
            for (int nt=0; nt<4; ++nt) {
                int px = px0 + wpx + nt*16 + l15;
                float v = acc[mt][nt][r] + bs;
                if (DOGELU) v = gelu_f(v);
                size_t o = (size_t)co*PIX + px;
                if (DORES) v += res[o];
                out[o] = v;
            }
        }
    }
}

// ---------------- 3x3 dense conv 128->128 via bf16 MFMA + bias + skip ----------
__global__ __launch_bounds__(256) void conv3x3_mfma_kernel(
    const float* __restrict__ in,            // (B,128,PIX)
    const unsigned short* __restrict__ wq,   // (128,9,128) bf16 [co][tap][ci]
    const float* __restrict__ bias, const float* __restrict__ skip,
    float* __restrict__ out)
{
    constexpr int CIP = 40;
    __shared__ unsigned short XL[4*66*CIP];
    const int x0 = blockIdx.x * 64;          // 0..2
    const int y0 = blockIdx.y * 2;           // 0..95
    const int bi = blockIdx.z;
    const int tid = threadIdx.x;
    const int lane = tid & 63, wid = tid >> 6;
    const int wco = (wid >> 1) * 64;
    const int wrow = wid & 1;
    const int l15 = lane & 15, l4 = lane >> 4;
    const float* inb = in + (size_t)bi * CCH * PIX;

    f32x4 acc[4][4];
    #pragma unroll
    for (int i=0;i<4;++i)
        #pragma unroll
        for (int j=0;j<4;++j) acc[i][j] = (f32x4){0.f,0.f,0.f,0.f};

    for (int ci0 = 0; ci0 < 128; ci0 += 32) {
        __syncthreads();
        for (int it = 0; it < 33; ++it) {
            int idx = tid + it*256;          // 0..8447
            int ci = idx / 264;
            int rem = idx - ci*264;
            int row = rem / 66;
            int x = rem - row*66;
            int gy = y0 - 1 + row, gx = x0 - 1 + x;
            float v = ((unsigned)gy < (unsigned)HWD && (unsigned)gx < (unsigned)HWD)
                      ? inb[(size_t)(ci0+ci)*PIX + (size_t)gy*HWD + gx] : 0.f;
            XL[(row*66 + x)*CIP + ci] = f2bf(v);
        }
        __syncthreads();
        #pragma unroll
        for (int dy=0; dy<3; ++dy) {
            #pragma unroll
            for (int dx=0; dx<3; ++dx) {
                short8 a[4];
                #pragma unroll
                for (int mt=0; mt<4; ++mt) {
                    int co = wco + mt*16 + l15;
                    a[mt] = *(const short8*)(wq + ((size_t)co*9 + dy*3+dx)*128 + ci0 + l4*8);
                }
                const int rl = wrow + dy;    // 0..3
                #pragma unroll
                for (int nt=0; nt<4; ++nt) {
                    const int xl = nt*16 + l15 + dx;   // 0..65
                    const short8 b = *(const short8*)&XL[(rl*66 + xl)*CIP + l4*8];
                    #pragma unroll
                    for (int mt=0; mt<4; ++mt)
                        acc[mt][nt] = __builtin_amdgcn_mfma_f32_16x16x32_bf16(a[mt], b, acc[mt][nt], 0, 0, 0);
                }
            }
        }
    }
    const int gy = y0 + wrow;
    #pragma unroll
    for (int mt=0; mt<4; ++mt) {
        #pragma unroll
        for (int r=0; r<4; ++r) {
            int co = wco + mt*16 + l4*4 + r;
            float bs = bias[co];
            #pragma unroll
            for (int nt=0; nt<4; ++nt) {
                int gx = x0 + nt*16 + l15;
                size_t o = ((size_t)bi*CCH + co)*PIX + (size_t)gy*HWD + gx;
                out[o] = acc[mt][nt][r] + bs + skip[o];
            }
        }
    }
}

// ---------------- 13x13 dense conv 32->32 pad6 via bf16 MFMA + fused dyn dw3x3 -
// block: 4 waves; wave w = output row y0+w, 16 px, 32 co. LDS patch staged once.
__global__ __launch_bounds__(256) void conv13_mfma_kernel(
    const float* __restrict__ in,            // (B,128,PIX) reads ch 0..31
    const unsigned short* __restrict__ wq,   // [169][32co][32ci] bf16
    const float* __restrict__ dk,            // [B*32][9]
    float* __restrict__ out)                 // (B,32,PIX)
{
    constexpr int CIP = 40;
    __shared__ unsigned short XL[16*28*CIP];
    const int x0 = blockIdx.x * 16;          // 0..11
    const int y0 = blockIdx.y * 4;           // 0..47
    const int bi = blockIdx.z;
    const int tid = threadIdx.x;
    const int lane = tid & 63, wr = tid >> 6;
    const int l15 = lane & 15, l4 = lane >> 4;
    const float* inb = in + (size_t)bi * CCH * PIX;

    // stage 16 rows x 28 x x 32 ci (zero-pad OOB)
    #pragma unroll 1
    for (int it = 0; it < 56; ++it) {
        int idx = tid + it*256;              // 0..14335
        int ci = idx / 448;
        int p  = idx - ci*448;
        int row = p / 28;
        int x   = p - row*28;
        int gy = y0 - 6 + row, gx = x0 - 6 + x;
        float v = ((unsigned)gy < (unsigned)HWD && (unsigned)gx < (unsigned)HWD)
                  ? inb[(size_t)ci*PIX + (size_t)gy*HWD + gx] : 0.f;
        XL[(row*28 + x)*CIP + ci] = f2bf(v);
    }
    __syncthreads();

    f32x4 acc0 = (f32x4){0.f,0.f,0.f,0.f};
    f32x4 acc1 = (f32x4){0.f,0.f,0.f,0.f};
    #pragma unroll 1
    for (int dy=0; dy<13; ++dy) {
        const unsigned short* wrow = wq + (size_t)dy*13*1024;
        const int rbase = (wr + dy)*28;
        #pragma unroll
        for (int dx=0; dx<13; ++dx) {
            const short8 a0 = *(const short8*)(wrow + dx*1024 + l15*32 + l4*8);
            const short8 a1 = *(const short8*)(wrow + dx*1024 + (16+l15)*32 + l4*8);
            const short8 b  = *(const short8*)&XL[(rbase + l15 + dx)*CIP + l4*8];
            acc0 = __builtin_amdgcn_mfma_f32_16x16x32_bf16(a0, b, acc0, 0, 0, 0);
            acc1 = __builtin_amdgcn_mfma_f32_16x16x32_bf16(a1, b, acc1, 0, 0, 0);
        }
    }
    // epilogue: += dynamic depthwise 3x3 at channel co, then store
    const int gy = y0 + wr;
    #pragma unroll
    for (int mt=0; mt<2; ++mt) {
        #pragma unroll
        for (int r=0; r<4; ++r) {
            const int co = mt*16 + l4*4 + r;
            const float* dkk = dk + (bi*32 + co)*9;
            float dsum = 0.f;
            #pragma unroll
            for (int e=0; e<9; ++e) {
                int ey = e/3, ex = e - ey*3;
                dsum += bf2f(XL[((wr+5+ey)*28 + l15+5+ex)*CIP + co]) * dkk[e];
            }
            float v = (mt==0 ? acc0[r] : acc1[r]) + dsum;
            out[((size_t)bi*32 + co)*PIX + (size_t)gy*HWD + x0 + l15] = v;
        }
    }
}

// ---------------- depthwise 3x3 pad1 + bias, out = gelu(conv)+in (per-batch) ----
__global__ __launch_bounds__(256) void dw3x3_kernel(const float* __restrict__ in,
    const float* __restrict__ w, const float* __restrict__ b,
    float* __restrict__ out)
{
    int t = blockIdx.x*256 + threadIdx.x;     // 256*PIX/4 threads
    int c = t / (PIX/4);
    int p4 = (t - c*(PIX/4)) * 4;
    int y = p4 / HWD, x0 = p4 - y*HWD;
    const float* ib = in + (size_t)c * PIX;
    float wk[9];
    #pragma unroll
    for (int e=0;e<9;++e) wk[e] = w[c*9+e];
    float bc = b[c];
    float a0=bc,a1=bc,a2=bc,a3=bc;
    #pragma unroll
    for (int ky=0;ky<3;++ky) {
        int yy = y + ky - 1;
        if ((unsigned)yy < (unsigned)HWD) {
            const float* row = ib + (size_t)yy*HWD;
            float v[6];
            #pragma unroll
            for (int d=0;d<6;++d) {
                int xx = x0 + d - 1;
                v[d] = ((unsigned)xx < (unsigned)HWD) ? row[xx] : 0.f;
            }
            a0 += v[0]*wk[ky*3+0] + v[1]*wk[ky*3+1] + v[2]*wk[ky*3+2];
            a1 += v[1]*wk[ky*3+0] + v[2]*wk[ky*3+1] + v[3]*wk[ky*3+2];
            a2 += v[2]*wk[ky*3+0] + v[3]*wk[ky*3+1] + v[4]*wk[ky*3+2];
            a3 += v[3]*wk[ky*3+0] + v[4]*wk[ky*3+1] + v[5]*wk[ky*3+2];
        }
    }
    const float4 cen = *(const float4*)(ib + (size_t)y*HWD + x0);
    float4 r;
    r.x = gelu_f(a0)+cen.x; r.y = gelu_f(a1)+cen.y;
    r.z = gelu_f(a2)+cen.z; r.w = gelu_f(a3)+cen.w;
    *(float4*)(out + (size_t)c*PIX + p4) = r;
}

// ---------------- window attention (per-batch; qkv = (384,PIX), o = (128,PIX)) -
__global__ __launch_bounds__(256) void attn_kernel(const float* __restrict__ qkv,
    const float* __restrict__ table, float* __restrict__ o)
{
    __shared__ float K[256][32];
    __shared__ float V[256][32];
    const int win = blockIdx.x, head = blockIdx.y;
    const int wy = win/12, wx = win - wy*12;
    const int t = threadIdx.x;
    const int iy = t >> 4, ix = t & 15;
    const int gy = wy*16 + iy, gx = wx*16 + ix;
    const size_t sp = (size_t)gy*HWD + gx;
    const float* qb = qkv + ((size_t)head*32) * PIX + sp;
    const float* kb = qkv + ((size_t)(128 + head*32)) * PIX + sp;
    const float* vb = qkv + ((size_t)(256 + head*32)) * PIX + sp;
    float q[32];
    #pragma unroll
    for (int cc=0;cc<32;++cc) {
        q[cc]     = qb[(size_t)cc*PIX];
        K[t][cc]  = kb[(size_t)cc*PIX];
        V[t][cc]  = vb[(size_t)cc*PIX];
    }
    __syncthreads();
    const float scale = 0.17677669529663687f;   // 32^-0.5
    const float* tb = table + head*961;
    float m = -1e30f, l = 0.f;
    float oacc[32];
    #pragma unroll
    for (int cc=0;cc<32;++cc) oacc[cc]=0.f;
    for (int kt=0; kt<256; ++kt) {
        float s = 0.f;
        const float* kr = &K[kt][0];
        #pragma unroll
        for (int cc=0;cc<32;cc+=4) {
            const float4 kv = *(const float4*)(kr + cc);
            s += q[cc]*kv.x + q[cc+1]*kv.y + q[cc+2]*kv.z + q[cc+3]*kv.w;
        }
        int kh = kt >> 4, kw = kt & 15;
        s = s*scale + tb[(kh - iy + 15)*31 + (kw - ix + 15)];
        float mn = fmaxf(m, s);
        float corr = __expf(m - mn);
        float p = __expf(s - mn);
        l = l*corr + p;
        const float* vr = &V[kt][0];
        #pragma unroll
        for (int cc=0;cc<32;cc+=4) {
            const float4 vv = *(const float4*)(vr + cc);
            oacc[cc]   = oacc[cc]  *corr + p*vv.x;
            oacc[cc+1] = oacc[cc+1]*corr + p*vv.y;
            oacc[cc+2] = oacc[cc+2]*corr + p*vv.z;
            oacc[cc+3] = oacc[cc+3]*corr + p*vv.w;
        }
        m = mn;
    }
    float invl = 1.f / l;
    float* ob = o + ((size_t)head*32) * PIX + sp;
    #pragma unroll
    for (int cc=0;cc<32;++cc) ob[(size_t)cc*PIX] = oacc[cc]*invl;
}

// ---------------- mean over spatial for channels 0..31 (full batch) ------------
__global__ __launch_bounds__(256) void meanpool_kernel(const float* __restrict__ in,
    float* __restrict__ v)
{
    int bc = blockIdx.x;               // BB*32
    int bi = bc >> 5, c = bc & 31;
    const float* base = in + ((size_t)bi*CCH + c) * PIX;
    float s = 0.f;
    for (int i = threadIdx.x; i < PIX/4; i += 256) {
        const float4 t4 = ((const float4*)base)[i];
        s += t4.x+t4.y+t4.z+t4.w;
    }
    #pragma unroll
    for (int off=32; off>0; off>>=1) s += __shfl_down(s, off, 64);
    __shared__ float red[4];
    if ((threadIdx.x & 63) == 0) red[threadIdx.x >> 6] = s;
    __syncthreads();
    if (threadIdx.x == 0) v[bc] = (red[0]+red[1]+red[2]+red[3]) * (1.f/PIX);
}

// ---------------- tiny MLP producing dynamic 3x3 kernels -----------------------
__global__ __launch_bounds__(256) void mlp_kernel(const float* __restrict__ v,
    const float* __restrict__ pw1, const float* __restrict__ pb1,
    const float* __restrict__ pw2, const float* __restrict__ pb2,
    float* __restrict__ dk)
{
    __shared__ float h[64];
    int tid = threadIdx.x;
    if (tid < 64) {
        int bi = tid >> 4, m = tid & 15;
        float s = pb1[m];
        for (int c=0;c<32;++c) s += v[bi*32+c]*pw1[m*32+c];
        h[tid] = gelu_f(s);
    }
    __syncthreads();
    for (int idx = tid; idx < BB*288; idx += 256) {
        int bi = idx / 288, j = idx - bi*288;
        float s = pb2[j];
        for (int m=0;m<16;++m) s += h[bi*16+m]*pw2[j*16+m];
        dk[idx] = s;
    }
}

// ---------------- fp32 -> bf16 cast (same layout) ------------------------------
__global__ __launch_bounds__(256) void wcast_kernel(const float* __restrict__ w,
    unsigned short* __restrict__ wq, int n)
{
    int idx = blockIdx.x*256 + threadIdx.x;
    if (idx < n) wq[idx] = f2bf(w[idx]);
}

// ---------------- co_w (128,128,3,3) -> bf16 [co][tap][ci] ---------------------
__global__ __launch_bounds__(256) void w3cast_kernel(const float* __restrict__ w,
    unsigned short* __restrict__ wq)
{
    int idx = blockIdx.x*256 + threadIdx.x;     // 128*128*9
    if (idx >= 128*128*9) return;
    int co = idx / (128*9);
    int rem = idx - co*128*9;
    int ci = rem / 9;
    int tap = rem - ci*9;
    wq[((size_t)co*9 + tap)*128 + ci] = f2bf(w[idx]);
}

// ---------------- plk (32,32,13,13) -> bf16 [tap][co][ci] ----------------------
__global__ __launch_bounds__(256) void w13cast_kernel(const float* __restrict__ w,
    unsigned short* __restrict__ wq)
{
    int idx = blockIdx.x*256 + threadIdx.x;     // 32*32*169
    if (idx >= 32*32*169) return;
    int co = idx / (32*169);
    int rem = idx - co*32*169;
    int ci = rem / 169;
    int tap = rem - ci*169;
    wq[((size_t)tap*32 + co)*32 + ci] = f2bf(w[idx]);
}

// ---------------- copy (B,32,PIX) into channels 0..31 of (B,128,PIX) -----------
__global__ __launch_bounds__(256) void copyslice_kernel(const float* __restrict__ src,
    float* __restrict__ dst)
{
    int idx = blockIdx.x*256 + threadIdx.x;      // BB*32*PIX/4
    int bc = idx / (PIX/4);
    int p4 = (idx - bc*(PIX/4)) * 4;
    int bi = bc >> 5, c = bc & 31;
    *(float4*)(dst + ((size_t)bi*CCH + c)*PIX + p4) =
        *(const float4*)(src + (size_t)bc*PIX + p4);
}

extern "C" void kernel_launch(void* const* d_in, const int* in_sizes, int n_in,
                              void* d_out, int out_size, void* d_ws, size_t ws_size,
                              hipStream_t stream) {
    (void)in_sizes; (void)n_in; (void)out_size;
    const float* x_in      = (const float*)d_in[0];
    const float* plk       = (const float*)d_in[1];
    const float* ln_proj_w = (const float*)d_in[2];
    const float* ln_proj_b = (const float*)d_in[3];
    const float* proj_w1   = (const float*)d_in[4];
    const float* proj_b1   = (const float*)d_in[5];
    const float* proj_dw   = (const float*)d_in[6];
    const float* proj_dwb  = (const float*)d_in[7];
    const float* proj_w2   = (const float*)d_in[8];
    const float* proj_b2   = (const float*)d_in[9];
    const float* ln_attn_w = (const float*)d_in[10];
    const float* ln_attn_b = (const float*)d_in[11];
    const float* qkv_w     = (const float*)d_in[12];
    const float* qkv_b     = (const float*)d_in[13];
    const float* attn_ow   = (const float*)d_in[14];
    const float* attn_ob   = (const float*)d_in[15];
    const float* rpe       = (const float*)d_in[16];
    const float* ffn_w1    = (const float*)d_in[17];
    const float* ffn_b1    = (const float*)d_in[18];
    const float* ffn_dw    = (const float*)d_in[19];
    const float* ffn_dwb   = (const float*)d_in[20];
    const float* ffn_w2    = (const float*)d_in[21];
    const float* ffn_b2    = (const float*)d_in[22];
    const float* pk_w1     = (const float*)d_in[23];
    const float* pk_b1     = (const float*)d_in[24];
    const float* pk_w2     = (const float*)d_in[25];
    const float* pk_b2     = (const float*)d_in[26];
    const float* aggr_w    = (const float*)d_in[27];
    const float* aggr_b    = (const float*)d_in[28];
    const float* ln_out_w  = (const float*)d_in[29];
    const float* ln_out_b  = (const float*)d_in[30];
    const float* co_w      = (const float*)d_in[31];
    const float* co_b      = (const float*)d_in[32];
    float* out = (float*)d_out;

    const size_t N1b = (size_t)CCH * PIX;      // 4,718,592 (one batch, 128ch)
    const size_t NEb = (size_t)256 * PIX;      // 9,437,184 (one batch, 256ch)
    const size_t RAsz = (size_t)BB * N1b;      // 18,874,368
    const size_t EQsz = 2 * NEb;               // 18,874,368
    const size_t QTOT = 615424;                // total bf16 weight elems (ushort)
    const size_t need_floats = 2*RAsz + EQsz + 256 + 1152 + QTOT/2 + 16;
    if (ws_size < need_floats * sizeof(float)) return;   // diagnostic guard

    float* ws  = (float*)d_ws;
    float* RA  = ws;
    float* RB  = RA + RAsz;
    float* EQ  = RB + RAsz;                    // aliased: E1/E2 | per-batch QKV | C13
    float* E1  = EQ;
    float* E2  = EQ + NEb;
    float* C13 = EQ;                           // BB*32*PIX = 4,718,592 fits
    float* VB   = EQ + EQsz;                   // 256
    float* DK   = VB + 256;                    // 1152
    unsigned short* Q0  = (unsigned short*)(DK + 1152);
    unsigned short* qPW1 = Q0;                 // 256*128
    unsigned short* qPW2 = qPW1 + 32768;       // 128*256
    unsigned short* qQKV = qPW2 + 32768;       // 384*128
    unsigned short* qAT  = qQKV + 49152;       // 128*128
    unsigned short* qF1  = qAT  + 16384;       // 2*256*128
    unsigned short* qF2  = qF1  + 65536;       // 2*128*256
    unsigned short* qAG  = qF2  + 65536;       // 2*128*128
    unsigned short* qW3  = qAG  + 32768;       // 128*9*128
    unsigned short* qW13 = qW3  + 147456;      // 169*32*32

    dim3 blk(256);

    // ---- weight prep ----
    wcast_kernel<<<128, blk, 0, stream>>>(proj_w1, qPW1, 32768);
    wcast_kernel<<<128, blk, 0, stream>>>(proj_w2, qPW2, 32768);
    wcast_kernel<<<192, blk, 0, stream>>>(qkv_w, qQKV, 49152);
    wcast_kernel<<<64,  blk, 0, stream>>>(attn_ow, qAT, 16384);
    wcast_kernel<<<256, blk, 0, stream>>>(ffn_w1, qF1, 65536);
    wcast_kernel<<<256, blk, 0, stream>>>(ffn_w2, qF2, 65536);
    wcast_kernel<<<128, blk, 0, stream>>>(aggr_w, qAG, 32768);
    w3cast_kernel<<<576, blk, 0, stream>>>(co_w, qW3);
    w13cast_kernel<<<676, blk, 0, stream>>>(plk, qW13);

    // x = conv_ffn(LN(x), proj)   [E buffers are per-batch -> loop b]
    ln_kernel<<<576, 64, 0, stream>>>(x_in, ln_proj_w, ln_proj_b, RA);
    for (int b=0;b<BB;++b) {
        conv1x1_mfma_kernel<true,false><<<dim3(288,2,1), blk, 0, stream>>>(RA + b*N1b, qPW1, proj_b1, nullptr, E1, 128);
        dw3x3_kernel<<<9216, blk, 0, stream>>>(E1, proj_dw, proj_dwb, E2);
        conv1x1_mfma_kernel<false,false><<<dim3(288,1,1), blk, 0, stream>>>(E2, qPW2, proj_b2, nullptr, RB + b*N1b, 256);
    }

    // x = x + window_attention(LN(x))
    ln_kernel<<<576, 64, 0, stream>>>(RB, ln_attn_w, ln_attn_b, RA);
    for (int b=0;b<BB;++b) {
        conv1x1_mfma_kernel<false,false><<<dim3(288,3,1), blk, 0, stream>>>(RA + b*N1b, qQKV, qkv_b, nullptr, EQ, 128);
        attn_kernel<<<dim3(144,4,1), blk, 0, stream>>>(EQ, rpe, RA + b*N1b);
    }
    conv1x1_mfma_kernel<false,true><<<dim3(288,1,BB), blk, 0, stream>>>(RA, qAT, attn_ob, RB, RB, 128);

    // x lives in RB across the loop
    for (int i=0;i<2;++i) {
        const float* fb1 = ffn_b1 + (size_t)i*256;
        const float* fdw = ffn_dw + (size_t)i*256*9;
        const float* fdb = ffn_dwb + (size_t)i*256;
        const float* fb2 = ffn_b2 + (size_t)i*128;
        const float* w1i = pk_w1 + (size_t)i*16*32;
        const float* b1i = pk_b1 + (size_t)i*16;
        const float* w2i = pk_w2 + (size_t)i*288*16;
        const float* b2i = pk_b2 + (size_t)i*288;
        const float* abi = aggr_b + (size_t)i*128;

        for (int b=0;b<BB;++b) {
            conv1x1_mfma_kernel<true,false><<<dim3(288,2,1), blk, 0, stream>>>(RB + b*N1b, qF1 + (size_t)i*32768, fb1, nullptr, E1, 128);
            dw3x3_kernel<<<9216, blk, 0, stream>>>(E1, fdw, fdb, E2);
            conv1x1_mfma_kernel<false,false><<<dim3(288,1,1), blk, 0, stream>>>(E2, qF2 + (size_t)i*32768, fb2, nullptr, RA + b*N1b, 256);
        }
        meanpool_kernel<<<BB*32, blk, 0, stream>>>(RA, VB);
        mlp_kernel<<<1, blk, 0, stream>>>(VB, w1i, b1i, w2i, b2i, DK);
        conv13_mfma_kernel<<<dim3(12,48,BB), blk, 0, stream>>>(RA, qW13, DK, C13);
        copyslice_kernel<<<(BB*32*(PIX/4))/256, blk, 0, stream>>>(C13, RA);
        conv1x1_mfma_kernel<false,true><<<dim3(288,1,BB), blk, 0, stream>>>(RA, qAG + (size_t)i*16384, abi, RB, RB, 128);
    }

    // out = conv3x3(LN(x)) + bias + skip
    ln_kernel<<<576, 64, 0, stream>>>(RB, ln_out_w, ln_out_b, RA);
    conv3x3_mfma_kernel<<<dim3(3,96,BB), blk, 0, stream>>>(RA, qW3, co_b, x_in, out);
}

// Round 7
// 2131.444 us; speedup vs baseline: 2.7717x; 1.3386x over previous
//
#include <hip/hip_runtime.h>
#include <cmath>

#define HWD 192
#define PIX (HWD*HWD)      // 36864
#define BB  4
#define CCH 128

using short8 = __attribute__((ext_vector_type(8))) short;
using f32x4  = __attribute__((ext_vector_type(4))) float;

__device__ __forceinline__ float gelu_f(float x) {
    return 0.5f * x * (1.0f + erff(x * 0.70710678118654752f));
}
__device__ __forceinline__ unsigned short f2bf(float f) {
    unsigned int u = __float_as_uint(f);
    u += 0x7fff + ((u >> 16) & 1);          // round-to-nearest-even
    return (unsigned short)(u >> 16);
}
__device__ __forceinline__ float bf2f(unsigned short s) {
    return __uint_as_float((unsigned int)s << 16);
}
__device__ __forceinline__ unsigned short to_bf(float v) { return f2bf(v); }
__device__ __forceinline__ unsigned short to_bf(unsigned short v) { return v; }

// ---------------- LayerNorm: fp32 in, bf16 out; 1 px/thread --------------------
__global__ __launch_bounds__(256) void ln_kernel(const float* __restrict__ in,
        const float* __restrict__ w, const float* __restrict__ b,
        unsigned short* __restrict__ out)
{
    int t = blockIdx.x * 256 + threadIdx.x;       // BB*PIX threads
    int bi = t / PIX;
    int p  = t - bi*PIX;
    const float* base = in + (size_t)bi * CCH * PIX + p;
    float v[CCH];
    float s = 0.f;
    #pragma unroll
    for (int c=0;c<CCH;++c) { v[c] = base[(size_t)c*PIX]; s += v[c]; }
    float m = s * (1.f/128.f);
    float q = 0.f;
    #pragma unroll
    for (int c=0;c<CCH;++c) { float d = v[c]-m; q += d*d; }
    float iv = rsqrtf(q*(1.f/128.f) + 1e-6f);
    unsigned short* ob = out + (size_t)bi * CCH * PIX + p;
    #pragma unroll
    for (int c=0;c<CCH;++c)
        ob[(size_t)c*PIX] = f2bf((v[c]-m)*iv*w[c] + b[c]);
}

// ---------------- 1x1 conv via bf16 MFMA ---------------------------------------
// TIN: float or ushort input. OBF: bf16 output. RES: add fp32 residual (OBF=0).
template<typename TIN, bool DOGELU, bool DORES, bool OBF>
__global__ __launch_bounds__(256) void conv1x1_mfma_kernel(
    const TIN* __restrict__ in,              // (z, Cin, PIX)
    const unsigned short* __restrict__ wq,   // (Cout, Cin) bf16
    const float* __restrict__ bias,
    const float* __restrict__ res,           // (z, Cout, PIX) fp32 or null
    void* __restrict__ outv,                 // (z, Cout, PIX)
    int Cin)
{
    constexpr int CIP = 72;
    __shared__ unsigned short XL[128*CIP];
    const int Cout = gridDim.y * 128;
    const int px0 = blockIdx.x * 128;
    const int co0 = blockIdx.y * 128;
    const size_t bi = blockIdx.z;
    in  += bi * (size_t)Cin * PIX;
    if (DORES) res += bi * (size_t)Cout * PIX;
    float* outf = (float*)outv + bi * (size_t)Cout * PIX;
    unsigned short* outb = (unsigned short*)outv + bi * (size_t)Cout * PIX;
    const int tid = threadIdx.x;
    const int lane = tid & 63, wid = tid >> 6;
    const int wco = (wid >> 1) * 64;
    const int wpx = (wid & 1) * 64;
    const int l15 = lane & 15, l4 = lane >> 4;

    f32x4 acc[4][4];
    #pragma unroll
    for (int i=0;i<4;++i)
        #pragma unroll
        for (int j=0;j<4;++j) acc[i][j] = (f32x4){0.f,0.f,0.f,0.f};

    for (int k0 = 0; k0 < Cin; k0 += 64) {
        __syncthreads();
        #pragma unroll
        for (int it = 0; it < 8; ++it) {
            int f = tid + it*256;            // 0..2047
            int px = f & 127;
            int ci = (f >> 7) * 4;           // 0..60
            const TIN* gp = in + (size_t)(k0+ci)*PIX + px0 + px;
            unsigned short b0 = to_bf(gp[0]);
            unsigned short b1 = to_bf(gp[PIX]);
            unsigned short b2 = to_bf(gp[2*PIX]);
            unsigned short b3 = to_bf(gp[3*PIX]);
            uint2 pk;
            pk.x = (unsigned)b0 | ((unsigned)b1 << 16);
            pk.y = (unsigned)b2 | ((unsigned)b3 << 16);
            *(uint2*)&XL[px*CIP + ci] = pk;
        }
        __syncthreads();
        #pragma unroll
        for (int ks = 0; ks < 2; ++ks) {
            short8 a[4];
            #pragma unroll
            for (int mt=0; mt<4; ++mt) {
                int co = co0 + wco + mt*16 + l15;
                a[mt] = *(const short8*)(wq + (size_t)co*Cin + k0 + ks*32 + l4*8);
            }
            #pragma unroll
            for (int nt=0; nt<4; ++nt) {
                const short8 b = *(const short8*)&XL[(wpx + nt*16 + l15)*CIP + ks*32 + l4*8];
                #pragma unroll
                for (int mt=0; mt<4; ++mt)
                    acc[mt][nt] = __builtin_amdgcn_mfma_f32_16x16x32_bf16(a[mt], b, acc[mt][nt], 0, 0, 0);
            }
        }
    }
    #pragma unroll
    for (int mt=0; mt<4; ++mt) {
        #pragma unroll
        for (int r=0; r<4; ++r) {
            int co = co0 + wco + mt*16 + l4*4 + r;
            float bs = bias[co];
            #pragma unroll
            for (int nt=0; nt<4; ++nt) {
                int px = px0 + wpx + nt*16 + l15;
                float v = acc[mt][nt][r] + bs;
                if (DOGELU) v = gelu_f(v);
                size_t o = (size_t)co*PIX + px;
                if (DORES) v += res[o];
                if (OBF) outb[o] = f2bf(v);
                else     outf[o] = v;
            }
        }
    }
}

// ---------------- 3x3 dense conv 128->128 via bf16 MFMA + bias + skip ----------
__global__ __launch_bounds__(256) void conv3x3_mfma_kernel(
    const unsigned short* __restrict__ in,   // (B,128,PIX) bf16
    const unsigned short* __restrict__ wq,   // (128,9,128) bf16 [co][tap][ci]
    const float* __restrict__ bias, const float* __restrict__ skip,
    float* __restrict__ out)
{
    constexpr int CIP = 40;
    __shared__ unsigned short XL[4*66*CIP];
    const int x0 = blockIdx.x * 64;          // 0..2
    const int y0 = blockIdx.y * 2;           // 0..95
    const int bi = blockIdx.z;
    const int tid = threadIdx.x;
    const int lane = tid & 63, wid = tid >> 6;
    const int wco = (wid >> 1) * 64;
    const int wrow = wid & 1;
    const int l15 = lane & 15, l4 = lane >> 4;
    const unsigned short* inb = in + (size_t)bi * CCH * PIX;

    f32x4 acc[4][4];
    #pragma unroll
    for (int i=0;i<4;++i)
        #pragma unroll
        for (int j=0;j<4;++j) acc[i][j] = (f32x4){0.f,0.f,0.f,0.f};

    for (int ci0 = 0; ci0 < 128; ci0 += 32) {
        __syncthreads();
        for (int it = 0; it < 33; ++it) {
            int idx = tid + it*256;          // 0..8447
            int ci = idx / 264;
            int rem = idx - ci*264;
            int row = rem / 66;
            int x = rem - row*66;
            int gy = y0 - 1 + row, gx = x0 - 1 + x;
            unsigned short v = ((unsigned)gy < (unsigned)HWD && (unsigned)gx < (unsigned)HWD)
                      ? inb[(size_t)(ci0+ci)*PIX + (size_t)gy*HWD + gx] : (unsigned short)0;
            XL[(row*66 + x)*CIP + ci] = v;
        }
        __syncthreads();
        #pragma unroll
        for (int dy=0; dy<3; ++dy) {
            #pragma unroll
            for (int dx=0; dx<3; ++dx) {
                short8 a[4];
                #pragma unroll
                for (int mt=0; mt<4; ++mt) {
                    int co = wco + mt*16 + l15;
                    a[mt] = *(const short8*)(wq + ((size_t)co*9 + dy*3+dx)*128 + ci0 + l4*8);
                }
                const int rl = wrow + dy;    // 0..3
                #pragma unroll
                for (int nt=0; nt<4; ++nt) {
                    const int xl = nt*16 + l15 + dx;   // 0..65
                    const short8 b = *(const short8*)&XL[(rl*66 + xl)*CIP + l4*8];
                    #pragma unroll
                    for (int mt=0; mt<4; ++mt)
                        acc[mt][nt] = __builtin_amdgcn_mfma_f32_16x16x32_bf16(a[mt], b, acc[mt][nt], 0, 0, 0);
                }
            }
        }
    }
    const int gy = y0 + wrow;
    #pragma unroll
    for (int mt=0; mt<4; ++mt) {
        #pragma unroll
        for (int r=0; r<4; ++r) {
            int co = wco + mt*16 + l4*4 + r;
            float bs = bias[co];
            #pragma unroll
            for (int nt=0; nt<4; ++nt) {
                int gx = x0 + nt*16 + l15;
                size_t o = ((size_t)bi*CCH + co)*PIX + (size_t)gy*HWD + gx;
                out[o] = acc[mt][nt][r] + bs + skip[o];
            }
        }
    }
}

// ---------------- 13x13 dense conv 32->32 pad6 via bf16 MFMA + fused dyn dw3x3 -
// block: 4 waves; wave wr = output row y0+wr, 64 px, 32 co. XOR-swizzled patch.
// swizzle: (P&3)<<3 -- stays inside the 5-bit ci space, 8-granular (b128-safe).
__global__ __launch_bounds__(256) void conv13_mfma_kernel(
    const unsigned short* __restrict__ Y,    // (B,128,PIX) bf16, reads ch 0..31
    const unsigned short* __restrict__ wq,   // [169][32co][32ci] bf16
    const float* __restrict__ dk,            // [B*32][9]
    unsigned short* __restrict__ outC)       // (B,32,PIX) bf16
{
    __shared__ unsigned short XL[16*76*32];  // 77824 B, swizzled
    const int x0 = blockIdx.x * 64;          // 0..2
    const int y0 = blockIdx.y * 4;           // 0..47
    const int bi = blockIdx.z;
    const int tid = threadIdx.x;
    const int lane = tid & 63, wr = tid >> 6;
    const int l15 = lane & 15, l4 = lane >> 4;
    const unsigned short* inb = Y + (size_t)bi * CCH * PIX;

    // stage 16 rows x 76 px x 32 ci; ushort idx = P*32 + (ci ^ ((P&3)<<3))
    #pragma unroll 1
    for (int it = 0; it < 152; ++it) {
        int idx = tid + it*256;              // 0..38911
        int ci = idx / 1216;
        int rem = idx - ci*1216;
        int row = rem / 76;
        int x   = rem - row*76;
        int gy = y0 - 6 + row, gx = x0 - 6 + x;
        unsigned short v = ((unsigned)gy < (unsigned)HWD && (unsigned)gx < (unsigned)HWD)
                  ? inb[(size_t)ci*PIX + (size_t)gy*HWD + gx] : (unsigned short)0;
        int P = row*76 + x;
        XL[P*32 + (ci ^ ((P&3)<<3))] = v;
    }
    __syncthreads();

    f32x4 acc[2][4];
    #pragma unroll
    for (int i=0;i<2;++i)
        #pragma unroll
        for (int j=0;j<4;++j) acc[i][j] = (f32x4){0.f,0.f,0.f,0.f};

    #pragma unroll 1
    for (int dy=0; dy<13; ++dy) {
        const unsigned short* wrow = wq + (size_t)dy*13*1024;
        #pragma unroll
        for (int dx=0; dx<13; ++dx) {
            const short8 a0 = *(const short8*)(wrow + dx*1024 + l15*32 + l4*8);
            const short8 a1 = *(const short8*)(wrow + dx*1024 + (16+l15)*32 + l4*8);
            #pragma unroll
            for (int nt=0; nt<4; ++nt) {
                const int P = (wr + dy)*76 + nt*16 + l15 + dx;
                const short8 b = *(const short8*)&XL[P*32 + ((l4*8) ^ ((P&3)<<3))];
                acc[0][nt] = __builtin_amdgcn_mfma_f32_16x16x32_bf16(a0, b, acc[0][nt], 0, 0, 0);
                acc[1][nt] = __builtin_amdgcn_mfma_f32_16x16x32_bf16(a1, b, acc[1][nt], 0, 0, 0);
            }
        }
    }
    // epilogue: += dynamic depthwise 3x3 at channel co, store bf16
    const int gy = y0 + wr;
    #pragma unroll
    for (int mt=0; mt<2; ++mt) {
        #pragma unroll
        for (int r=0; r<4; ++r) {
            const int co = mt*16 + l4*4 + r;
            const float* dkk = dk + (bi*32 + co)*9;
            float k0=dkk[0],k1=dkk[1],k2=dkk[2],k3=dkk[3],k4=dkk[4],
                  k5=dkk[5],k6=dkk[6],k7=dkk[7],k8=dkk[8];
            #pragma unroll
            for (int nt=0; nt<4; ++nt) {
                const int px = nt*16 + l15;
                float dsum = 0.f;
                #pragma unroll
                for (int e=0; e<9; ++e) {
                    int ey = e/3, ex = e - ey*3;
                    int P = (wr+5+ey)*76 + px+5+ex;
                    float pv = bf2f(XL[P*32 + (co ^ ((P&3)<<3))]);
                    float kk = (e==0?k0:e==1?k1:e==2?k2:e==3?k3:e==4?k4:e==5?k5:e==6?k6:e==7?k7:k8);
                    dsum += pv * kk;
                }
                float v = acc[mt][nt][r] + dsum;
                outC[((size_t)bi*32 + co)*PIX + (size_t)gy*HWD + x0 + px] = f2bf(v);
            }
        }
    }
}

// ---------------- depthwise 3x3 pad1 + bias, bf16 in/out (gelu(conv)+in) -------
__global__ __launch_bounds__(256) void dw3x3_bf_kernel(const unsigned short* __restrict__ in,
    const float* __restrict__ w, const float* __restrict__ b,
    unsigned short* __restrict__ out)
{
    int t = blockIdx.x*256 + threadIdx.x;     // nb*256*PIX/4 threads
    int pc = t / (PIX/4);
    int p4 = (t - pc*(PIX/4)) * 4;
    int c = pc & 255;
    int y = p4 / HWD, x0 = p4 - y*HWD;
    const unsigned short* ib = in + (size_t)pc * PIX;
    float wk[9];
    #pragma unroll
    for (int e=0;e<9;++e) wk[e] = w[c*9+e];
    float bc = b[c];
    float a0=bc,a1=bc,a2=bc,a3=bc;
    #pragma unroll
    for (int ky=0;ky<3;++ky) {
        int yy = y + ky - 1;
        if ((unsigned)yy < (unsigned)HWD) {
            const unsigned short* row = ib + (size_t)yy*HWD;
            float v[6];
            #pragma unroll
            for (int d=0;d<6;++d) {
                int xx = x0 + d - 1;
                v[d] = ((unsigned)xx < (unsigned)HWD) ? bf2f(row[xx]) : 0.f;
            }
            a0 += v[0]*wk[ky*3+0] + v[1]*wk[ky*3+1] + v[2]*wk[ky*3+2];
            a1 += v[1]*wk[ky*3+0] + v[2]*wk[ky*3+1] + v[3]*wk[ky*3+2];
            a2 += v[2]*wk[ky*3+0] + v[3]*wk[ky*3+1] + v[4]*wk[ky*3+2];
            a3 += v[3]*wk[ky*3+0] + v[4]*wk[ky*3+1] + v[5]*wk[ky*3+2];
        }
    }
    const unsigned short* cen = ib + (size_t)y*HWD + x0;
    unsigned short r0 = f2bf(gelu_f(a0) + bf2f(cen[0]));
    unsigned short r1 = f2bf(gelu_f(a1) + bf2f(cen[1]));
    unsigned short r2 = f2bf(gelu_f(a2) + bf2f(cen[2]));
    unsigned short r3 = f2bf(gelu_f(a3) + bf2f(cen[3]));
    uint2 pk;
    pk.x = (unsigned)r0 | ((unsigned)r1 << 16);
    pk.y = (unsigned)r2 | ((unsigned)r3 << 16);
    *(uint2*)(out + (size_t)pc*PIX + p4) = pk;
}

// ---------------- window attention (bf16 qkv in, bf16 out) ---------------------
__global__ __launch_bounds__(256) void attn_kernel(const unsigned short* __restrict__ qkv,
    const float* __restrict__ table, unsigned short* __restrict__ o)
{
    __shared__ float K[256][32];
    __shared__ float V[256][32];
    const int win = blockIdx.x, head = blockIdx.y, z = blockIdx.z;
    qkv += (size_t)z * 384 * PIX;
    o   += (size_t)z * CCH * PIX;
    const int wy = win/12, wx = win - wy*12;
    const int t = threadIdx.x;
    const int iy = t >> 4, ix = t & 15;
    const int gy = wy*16 + iy, gx = wx*16 + ix;
    const size_t sp = (size_t)gy*HWD + gx;
    const unsigned short* qb = qkv + ((size_t)head*32) * PIX + sp;
    const unsigned short* kb = qkv + ((size_t)(128 + head*32)) * PIX + sp;
    const unsigned short* vb = qkv + ((size_t)(256 + head*32)) * PIX + sp;
    float q[32];
    #pragma unroll
    for (int cc=0;cc<32;++cc) {
        q[cc]     = bf2f(qb[(size_t)cc*PIX]);
        K[t][cc]  = bf2f(kb[(size_t)cc*PIX]);
        V[t][cc]  = bf2f(vb[(size_t)cc*PIX]);
    }
    __syncthreads();
    const float scale = 0.17677669529663687f;   // 32^-0.5
    const float* tb = table + head*961;
    float m = -1e30f, l = 0.f;
    float oacc[32];
    #pragma unroll
    for (int cc=0;cc<32;++cc) oacc[cc]=0.f;
    for (int kt=0; kt<256; ++kt) {
        float s = 0.f;
        const float* kr = &K[kt][0];
        #pragma unroll
        for (int cc=0;cc<32;cc+=4) {
            const float4 kv = *(const float4*)(kr + cc);
            s += q[cc]*kv.x + q[cc+1]*kv.y + q[cc+2]*kv.z + q[cc+3]*kv.w;
        }
        int kh = kt >> 4, kw = kt & 15;
        s = s*scale + tb[(kh - iy + 15)*31 + (kw - ix + 15)];
        float mn = fmaxf(m, s);
        float corr = __expf(m - mn);
        float p = __expf(s - mn);
        l = l*corr + p;
        const float* vr = &V[kt][0];
        #pragma unroll
        for (int cc=0;cc<32;cc+=4) {
            const float4 vv = *(const float4*)(vr + cc);
            oacc[cc]   = oacc[cc]  *corr + p*vv.x;
            oacc[cc+1] = oacc[cc+1]*corr + p*vv.y;
            oacc[cc+2] = oacc[cc+2]*corr + p*vv.z;
            oacc[cc+3] = oacc[cc+3]*corr + p*vv.w;
        }
        m = mn;
    }
    float invl = 1.f / l;
    unsigned short* ob = o + ((size_t)head*32) * PIX + sp;
    #pragma unroll
    for (int cc=0;cc<32;++cc) ob[(size_t)cc*PIX] = f2bf(oacc[cc]*invl);
}

// ---------------- mean over spatial for channels 0..31 (bf16 in) ---------------
__global__ __launch_bounds__(256) void meanpool_kernel(const unsigned short* __restrict__ in,
    float* __restrict__ v)
{
    int bc = blockIdx.x;               // BB*32
    int bi = bc >> 5, c = bc & 31;
    const unsigned short* base = in + ((size_t)bi*CCH + c) * PIX;
    float s = 0.f;
    for (int i = threadIdx.x; i < PIX/4; i += 256) {
        const uint2 t4 = ((const uint2*)base)[i];
        s += bf2f((unsigned short)(t4.x & 0xffff)) + bf2f((unsigned short)(t4.x >> 16))
           + bf2f((unsigned short)(t4.y & 0xffff)) + bf2f((unsigned short)(t4.y >> 16));
    }
    #pragma unroll
    for (int off=32; off>0; off>>=1) s += __shfl_down(s, off, 64);
    __shared__ float red[4];
    if ((threadIdx.x & 63) == 0) red[threadIdx.x >> 6] = s;
    __syncthreads();
    if (threadIdx.x == 0) v[bc] = (red[0]+red[1]+red[2]+red[3]) * (1.f/PIX);
}

// ---------------- tiny MLP producing dynamic 3x3 kernels -----------------------
__global__ __launch_bounds__(256) void mlp_kernel(const float* __restrict__ v,
    const float* __restrict__ pw1, const float* __restrict__ pb1,
    const float* __restrict__ pw2, const float* __restrict__ pb2,
    float* __restrict__ dk)
{
    __shared__ float h[64];
    int tid = threadIdx.x;
    if (tid < 64) {
        int bi = tid >> 4, m = tid & 15;
        float s = pb1[m];
        for (int c=0;c<32;++c) s += v[bi*32+c]*pw1[m*32+c];
        h[tid] = gelu_f(s);
    }
    __syncthreads();
    for (int idx = tid; idx < BB*288; idx += 256) {
        int bi = idx / 288, j = idx - bi*288;
        float s = pb2[j];
        for (int m=0;m<16;++m) s += h[bi*16+m]*pw2[j*16+m];
        dk[idx] = s;
    }
}

// ---------------- fp32 -> bf16 cast (same layout) ------------------------------
__global__ __launch_bounds__(256) void wcast_kernel(const float* __restrict__ w,
    unsigned short* __restrict__ wq, int n)
{
    int idx = blockIdx.x*256 + threadIdx.x;
    if (idx < n) wq[idx] = f2bf(w[idx]);
}

// ---------------- co_w (128,128,3,3) -> bf16 [co][tap][ci] ---------------------
__global__ __launch_bounds__(256) void w3cast_kernel(const float* __restrict__ w,
    unsigned short* __restrict__ wq)
{
    int idx = blockIdx.x*256 + threadIdx.x;     // 128*128*9
    if (idx >= 128*128*9) return;
    int co = idx / (128*9);
    int rem = idx - co*128*9;
    int ci = rem / 9;
    int tap = rem - ci*9;
    wq[((size_t)co*9 + tap)*128 + ci] = f2bf(w[idx]);
}

// ---------------- plk (32,32,13,13) -> bf16 [tap][co][ci] ----------------------
__global__ __launch_bounds__(256) void w13cast_kernel(const float* __restrict__ w,
    unsigned short* __restrict__ wq)
{
    int idx = blockIdx.x*256 + threadIdx.x;     // 32*32*169
    if (idx >= 32*32*169) return;
    int co = idx / (32*169);
    int rem = idx - co*32*169;
    int ci = rem / 169;
    int tap = rem - ci*169;
    wq[((size_t)tap*32 + co)*32 + ci] = f2bf(w[idx]);
}

// ---------------- copy (B,32,PIX) bf16 into ch 0..31 of (B,128,PIX) bf16 -------
__global__ __launch_bounds__(256) void copyslice_kernel(const unsigned short* __restrict__ src,
    unsigned short* __restrict__ dst)
{
    int idx = blockIdx.x*256 + threadIdx.x;      // BB*32*PIX/8
    int bc = idx / (PIX/8);
    int p8 = (idx - bc*(PIX/8)) * 8;
    int bi = bc >> 5, c = bc & 31;
    *(uint4*)(dst + ((size_t)bi*CCH + c)*PIX + p8) =
        *(const uint4*)(src + (size_t)bc*PIX + p8);
}

extern "C" void kernel_launch(void* const* d_in, const int* in_sizes, int n_in,
                              void* d_out, int out_size, void* d_ws, size_t ws_size,
                              hipStream_t stream) {
    (void)in_sizes; (void)n_in; (void)out_size;
    const float* x_in      = (const float*)d_in[0];
    const float* plk       = (const float*)d_in[1];
    const float* ln_proj_w = (const float*)d_in[2];
    const float* ln_proj_b = (const float*)d_in[3];
    const float* proj_w1   = (const float*)d_in[4];
    const float* proj_b1   = (const float*)d_in[5];
    const float* proj_dw   = (const float*)d_in[6];
    const float* proj_dwb  = (const float*)d_in[7];
    const float* proj_w2   = (const float*)d_in[8];
    const float* proj_b2   = (const float*)d_in[9];
    const float* ln_attn_w = (const float*)d_in[10];
    const float* ln_attn_b = (const float*)d_in[11];
    const float* qkv_w     = (const float*)d_in[12];
    const float* qkv_b     = (const float*)d_in[13];
    const float* attn_ow   = (const float*)d_in[14];
    const float* attn_ob   = (const float*)d_in[15];
    const float* rpe       = (const float*)d_in[16];
    const float* ffn_w1    = (const float*)d_in[17];
    const float* ffn_b1    = (const float*)d_in[18];
    const float* ffn_dw    = (const float*)d_in[19];
    const float* ffn_dwb   = (const float*)d_in[20];
    const float* ffn_w2    = (const float*)d_in[21];
    const float* ffn_b2    = (const float*)d_in[22];
    const float* pk_w1     = (const float*)d_in[23];
    const float* pk_b1     = (const float*)d_in[24];
    const float* pk_w2     = (const float*)d_in[25];
    const float* pk_b2     = (const float*)d_in[26];
    const float* aggr_w    = (const float*)d_in[27];
    const float* aggr_b    = (const float*)d_in[28];
    const float* ln_out_w  = (const float*)d_in[29];
    const float* ln_out_b  = (const float*)d_in[30];
    const float* co_w      = (const float*)d_in[31];
    const float* co_b      = (const float*)d_in[32];
    float* out = (float*)d_out;

    const size_t N1b = (size_t)CCH * PIX;          // 4,718,592 elems (one batch)
    const size_t RBsz = (size_t)BB * N1b;          // 18,874,368 fl
    const size_t LNYw = RBsz / 2;                  // bf16 buffer in float-words
    const size_t POOLw = RBsz;                     // 37.7M ushorts in float-words
    const size_t need_floats = RBsz + LNYw + POOLw + 1408 + 307712 + 64;
    if (ws_size < need_floats * sizeof(float)) return;   // diagnostic guard

    float* ws  = (float*)d_ws;
    float* RB  = ws;                               // fp32 residual x
    unsigned short* LNY  = (unsigned short*)(RB + RBsz);   // bf16 (B,128,PIX): LN out / attn out / y
    unsigned short* POOL = (unsigned short*)(RB + RBsz + LNYw); // bf16 pool: E1+E2 half / qkv half / C13
    float* VB  = (float*)(RB + RBsz + LNYw + POOLw);   // 256
    float* DK  = VB + 256;                             // 1152
    unsigned short* Q0  = (unsigned short*)(DK + 1152);
    unsigned short* qPW1 = Q0;                 // 256*128
    unsigned short* qPW2 = qPW1 + 32768;       // 128*256
    unsigned short* qQKV = qPW2 + 32768;       // 384*128
    unsigned short* qAT  = qQKV + 49152;       // 128*128
    unsigned short* qF1  = qAT  + 16384;       // 2*256*128
    unsigned short* qF2  = qF1  + 65536;       // 2*128*256
    unsigned short* qAG  = qF2  + 65536;       // 2*128*128
    unsigned short* qW3  = qAG  + 32768;       // 128*9*128
    unsigned short* qW13 = qW3  + 147456;      // 169*32*32

    unsigned short* E1 = POOL;                 // 2 batches * 256 * PIX
    unsigned short* E2 = POOL + (size_t)2*256*PIX;
    unsigned short* QKV = POOL;                // 2 batches * 384 * PIX
    unsigned short* C13 = POOL;                // 4 batches * 32 * PIX

    dim3 blk(256);

    // ---- weight prep ----
    wcast_kernel<<<128, blk, 0, stream>>>(proj_w1, qPW1, 32768);
    wcast_kernel<<<128, blk, 0, stream>>>(proj_w2, qPW2, 32768);
    wcast_kernel<<<192, blk, 0, stream>>>(qkv_w, qQKV, 49152);
    wcast_kernel<<<64,  blk, 0, stream>>>(attn_ow, qAT, 16384);
    wcast_kernel<<<256, blk, 0, stream>>>(ffn_w1, qF1, 65536);
    wcast_kernel<<<256, blk, 0, stream>>>(ffn_w2, qF2, 65536);
    wcast_kernel<<<128, blk, 0, stream>>>(aggr_w, qAG, 32768);
    w3cast_kernel<<<576, blk, 0, stream>>>(co_w, qW3);
    w13cast_kernel<<<676, blk, 0, stream>>>(plk, qW13);

    // x = conv_ffn(LN(x_in), proj)  [half-batch E buffers]
    ln_kernel<<<576, blk, 0, stream>>>(x_in, ln_proj_w, ln_proj_b, LNY);
    for (int h=0; h<2; ++h) {
        conv1x1_mfma_kernel<unsigned short,true,false,true><<<dim3(288,2,2), blk, 0, stream>>>(
            LNY + (size_t)h*2*N1b, qPW1, proj_b1, nullptr, E1, 128);
        dw3x3_bf_kernel<<<18432, blk, 0, stream>>>(E1, proj_dw, proj_dwb, E2);
        conv1x1_mfma_kernel<unsigned short,false,false,false><<<dim3(288,1,2), blk, 0, stream>>>(
            E2, qPW2, proj_b2, nullptr, RB + (size_t)h*2*N1b, 256);
    }

    // x = x + window_attention(LN(x))
    ln_kernel<<<576, blk, 0, stream>>>(RB, ln_attn_w, ln_attn_b, LNY);
    for (int h=0; h<2; ++h) {
        conv1x1_mfma_kernel<unsigned short,false,false,true><<<dim3(288,3,2), blk, 0, stream>>>(
            LNY + (size_t)h*2*N1b, qQKV, qkv_b, nullptr, QKV, 128);
        attn_kernel<<<dim3(144,4,2), blk, 0, stream>>>(QKV, rpe, LNY + (size_t)h*2*N1b);
    }
    conv1x1_mfma_kernel<unsigned short,false,true,false><<<dim3(288,1,BB), blk, 0, stream>>>(
        LNY, qAT, attn_ob, RB, RB, 128);

    // x lives in RB across the loop; y lives in LNY (bf16)
    for (int i=0;i<2;++i) {
        const float* fb1 = ffn_b1 + (size_t)i*256;
        const float* fdw = ffn_dw + (size_t)i*256*9;
        const float* fdb = ffn_dwb + (size_t)i*256;
        const float* fb2 = ffn_b2 + (size_t)i*128;
        const float* w1i = pk_w1 + (size_t)i*16*32;
        const float* b1i = pk_b1 + (size_t)i*16;
        const float* w2i = pk_w2 + (size_t)i*288*16;
        const float* b2i = pk_b2 + (size_t)i*288;
        const float* abi = aggr_b + (size_t)i*128;

        for (int h=0; h<2; ++h) {
            conv1x1_mfma_kernel<float,true,false,true><<<dim3(288,2,2), blk, 0, stream>>>(
                RB + (size_t)h*2*N1b, qF1 + (size_t)i*32768, fb1, nullptr, E1, 128);
            dw3x3_bf_kernel<<<18432, blk, 0, stream>>>(E1, fdw, fdb, E2);
            conv1x1_mfma_kernel<unsigned short,false,false,true><<<dim3(288,1,2), blk, 0, stream>>>(
                E2, qF2 + (size_t)i*32768, fb2, nullptr, LNY + (size_t)h*2*N1b, 256);
        }
        meanpool_kernel<<<BB*32, blk, 0, stream>>>(LNY, VB);
        mlp_kernel<<<1, blk, 0, stream>>>(VB, w1i, b1i, w2i, b2i, DK);
        conv13_mfma_kernel<<<dim3(3,48,BB), blk, 0, stream>>>(LNY, qW13, DK, C13);
        copyslice_kernel<<<(BB*32*(PIX/8))/256, blk, 0, stream>>>(C13, LNY);
        conv1x1_mfma_kernel<unsigned short,false,true,false><<<dim3(288,1,BB), blk, 0, stream>>>(
            LNY, qAG + (size_t)i*16384, abi, RB, RB, 128);
    }

    // out = conv3x3(LN(x)) + bias + skip
    ln_kernel<<<576, blk, 0, stream>>>(RB, ln_out_w, ln_out_b, LNY);
    conv3x3_mfma_kernel<<<dim3(3,96,BB), blk, 0, stream>>>(LNY, qW3, co_b, x_in, out);
}

// Round 8
// 1815.810 us; speedup vs baseline: 3.2535x; 1.1738x over previous
//
#include <hip/hip_runtime.h>
#include <cmath>

#define HWD 192
#define PIX (HWD*HWD)      // 36864
#define BB  4
#define CCH 128

using short8 = __attribute__((ext_vector_type(8))) short;
using f32x4  = __attribute__((ext_vector_type(4))) float;

__device__ __forceinline__ float gelu_f(float x) {
    return 0.5f * x * (1.0f + erff(x * 0.70710678118654752f));
}
__device__ __forceinline__ unsigned short f2bf(float f) {
    unsigned int u = __float_as_uint(f);
    u += 0x7fff + ((u >> 16) & 1);          // round-to-nearest-even
    return (unsigned short)(u >> 16);
}
__device__ __forceinline__ float bf2f(unsigned short s) {
    return __uint_as_float((unsigned int)s << 16);
}
__device__ __forceinline__ unsigned short to_bf(float v) { return f2bf(v); }
__device__ __forceinline__ unsigned short to_bf(unsigned short v) { return v; }
__device__ __forceinline__ unsigned pack2bf(float a, float b) {
    return (unsigned)f2bf(a) | ((unsigned)f2bf(b) << 16);
}

// ---------------- LayerNorm: fp32 in, bf16 out; 1 px/thread --------------------
__global__ __launch_bounds__(256) void ln_kernel(const float* __restrict__ in,
        const float* __restrict__ w, const float* __restrict__ b,
        unsigned short* __restrict__ out)
{
    int t = blockIdx.x * 256 + threadIdx.x;       // BB*PIX threads
    int bi = t / PIX;
    int p  = t - bi*PIX;
    const float* base = in + (size_t)bi * CCH * PIX + p;
    float v[CCH];
    float s = 0.f;
    #pragma unroll
    for (int c=0;c<CCH;++c) { v[c] = base[(size_t)c*PIX]; s += v[c]; }
    float m = s * (1.f/128.f);
    float q = 0.f;
    #pragma unroll
    for (int c=0;c<CCH;++c) { float d = v[c]-m; q += d*d; }
    float iv = rsqrtf(q*(1.f/128.f) + 1e-6f);
    unsigned short* ob = out + (size_t)bi * CCH * PIX + p;
    #pragma unroll
    for (int c=0;c<CCH;++c)
        ob[(size_t)c*PIX] = f2bf((v[c]-m)*iv*w[c] + b[c]);
}

// ---------------- 1x1 conv via bf16 MFMA ---------------------------------------
template<typename TIN, bool DOGELU, bool DORES, bool OBF>
__global__ __launch_bounds__(256) void conv1x1_mfma_kernel(
    const TIN* __restrict__ in,              // (z, Cin, PIX)
    const unsigned short* __restrict__ wq,   // (Cout, Cin) bf16
    const float* __restrict__ bias,
    const float* __restrict__ res,           // (z, Cout, PIX) fp32 or null
    void* __restrict__ outv,                 // (z, Cout, PIX)
    int Cin)
{
    constexpr int CIP = 72;
    __shared__ unsigned short XL[128*CIP];
    const int Cout = gridDim.y * 128;
    const int px0 = blockIdx.x * 128;
    const int co0 = blockIdx.y * 128;
    const size_t bi = blockIdx.z;
    in  += bi * (size_t)Cin * PIX;
    if (DORES) res += bi * (size_t)Cout * PIX;
    float* outf = (float*)outv + bi * (size_t)Cout * PIX;
    unsigned short* outb = (unsigned short*)outv + bi * (size_t)Cout * PIX;
    const int tid = threadIdx.x;
    const int lane = tid & 63, wid = tid >> 6;
    const int wco = (wid >> 1) * 64;
    const int wpx = (wid & 1) * 64;
    const int l15 = lane & 15, l4 = lane >> 4;

    f32x4 acc[4][4];
    #pragma unroll
    for (int i=0;i<4;++i)
        #pragma unroll
        for (int j=0;j<4;++j) acc[i][j] = (f32x4){0.f,0.f,0.f,0.f};

    for (int k0 = 0; k0 < Cin; k0 += 64) {
        __syncthreads();
        #pragma unroll
        for (int it = 0; it < 8; ++it) {
            int f = tid + it*256;            // 0..2047
            int px = f & 127;
            int ci = (f >> 7) * 4;           // 0..60
            const TIN* gp = in + (size_t)(k0+ci)*PIX + px0 + px;
            unsigned short b0 = to_bf(gp[0]);
            unsigned short b1 = to_bf(gp[PIX]);
            unsigned short b2 = to_bf(gp[2*PIX]);
            unsigned short b3 = to_bf(gp[3*PIX]);
            uint2 pk;
            pk.x = (unsigned)b0 | ((unsigned)b1 << 16);
            pk.y = (unsigned)b2 | ((unsigned)b3 << 16);
            *(uint2*)&XL[px*CIP + ci] = pk;
        }
        __syncthreads();
        #pragma unroll
        for (int ks = 0; ks < 2; ++ks) {
            short8 a[4];
            #pragma unroll
            for (int mt=0; mt<4; ++mt) {
                int co = co0 + wco + mt*16 + l15;
                a[mt] = *(const short8*)(wq + (size_t)co*Cin + k0 + ks*32 + l4*8);
            }
            #pragma unroll
            for (int nt=0; nt<4; ++nt) {
                const short8 b = *(const short8*)&XL[(wpx + nt*16 + l15)*CIP + ks*32 + l4*8];
                #pragma unroll
                for (int mt=0; mt<4; ++mt)
                    acc[mt][nt] = __builtin_amdgcn_mfma_f32_16x16x32_bf16(a[mt], b, acc[mt][nt], 0, 0, 0);
            }
        }
    }
    #pragma unroll
    for (int mt=0; mt<4; ++mt) {
        #pragma unroll
        for (int r=0; r<4; ++r) {
            int co = co0 + wco + mt*16 + l4*4 + r;
            float bs = bias[co];
            #pragma unroll
            for (int nt=0; nt<4; ++nt) {
                int px = px0 + wpx + nt*16 + l15;
                float v = acc[mt][nt][r] + bs;
                if (DOGELU) v = gelu_f(v);
                size_t o = (size_t)co*PIX + px;
                if (DORES) v += res[o];
                if (OBF) outb[o] = f2bf(v);
                else     outf[o] = v;
            }
        }
    }
}

// ---------------- 3x3 dense conv 128->128 via bf16 MFMA + bias + skip ----------
__global__ __launch_bounds__(256) void conv3x3_mfma_kernel(
    const unsigned short* __restrict__ in,   // (B,128,PIX) bf16
    const unsigned short* __restrict__ wq,   // (128,9,128) bf16 [co][tap][ci]
    const float* __restrict__ bias, const float* __restrict__ skip,
    float* __restrict__ out)
{
    constexpr int CIP = 40;
    __shared__ unsigned short XL[4*66*CIP];
    const int x0 = blockIdx.x * 64;          // 0..2
    const int y0 = blockIdx.y * 2;           // 0..95
    const int bi = blockIdx.z;
    const int tid = threadIdx.x;
    const int lane = tid & 63, wid = tid >> 6;
    const int wco = (wid >> 1) * 64;
    const int wrow = wid & 1;
    const int l15 = lane & 15, l4 = lane >> 4;
    const unsigned short* inb = in + (size_t)bi * CCH * PIX;

    f32x4 acc[4][4];
    #pragma unroll
    for (int i=0;i<4;++i)
        #pragma unroll
        for (int j=0;j<4;++j) acc[i][j] = (f32x4){0.f,0.f,0.f,0.f};

    for (int ci0 = 0; ci0 < 128; ci0 += 32) {
        __syncthreads();
        for (int it = 0; it < 33; ++it) {
            int idx = tid + it*256;          // 0..8447
            int ci = idx / 264;
            int rem = idx - ci*264;
            int row = rem / 66;
            int x = rem - row*66;
            int gy = y0 - 1 + row, gx = x0 - 1 + x;
            unsigned short v = ((unsigned)gy < (unsigned)HWD && (unsigned)gx < (unsigned)HWD)
                      ? inb[(size_t)(ci0+ci)*PIX + (size_t)gy*HWD + gx] : (unsigned short)0;
            XL[(row*66 + x)*CIP + ci] = v;
        }
        __syncthreads();
        #pragma unroll
        for (int dy=0; dy<3; ++dy) {
            #pragma unroll
            for (int dx=0; dx<3; ++dx) {
                short8 a[4];
                #pragma unroll
                for (int mt=0; mt<4; ++mt) {
                    int co = wco + mt*16 + l15;
                    a[mt] = *(const short8*)(wq + ((size_t)co*9 + dy*3+dx)*128 + ci0 + l4*8);
                }
                const int rl = wrow + dy;    // 0..3
                #pragma unroll
                for (int nt=0; nt<4; ++nt) {
                    const int xl = nt*16 + l15 + dx;   // 0..65
                    const short8 b = *(const short8*)&XL[(rl*66 + xl)*CIP + l4*8];
                    #pragma unroll
                    for (int mt=0; mt<4; ++mt)
                        acc[mt][nt] = __builtin_amdgcn_mfma_f32_16x16x32_bf16(a[mt], b, acc[mt][nt], 0, 0, 0);
                }
            }
        }
    }
    const int gy = y0 + wrow;
    #pragma unroll
    for (int mt=0; mt<4; ++mt) {
        #pragma unroll
        for (int r=0; r<4; ++r) {
            int co = wco + mt*16 + l4*4 + r;
            float bs = bias[co];
            #pragma unroll
            for (int nt=0; nt<4; ++nt) {
                int gx = x0 + nt*16 + l15;
                size_t o = ((size_t)bi*CCH + co)*PIX + (size_t)gy*HWD + gx;
                out[o] = acc[mt][nt][r] + bs + skip[o];
            }
        }
    }
}

// ---------------- 13x13 dense conv 32->32 pad6 via bf16 MFMA + fused dyn dw3x3 -
__global__ __launch_bounds__(256) void conv13_mfma_kernel(
    const unsigned short* __restrict__ Y,    // (B,128,PIX) bf16, reads ch 0..31
    const unsigned short* __restrict__ wq,   // [169][32co][32ci] bf16
    const float* __restrict__ dk,            // [B*32][9]
    unsigned short* __restrict__ outC)       // (B,32,PIX) bf16
{
    __shared__ unsigned short XL[16*76*32];  // 77824 B, swizzled
    const int x0 = blockIdx.x * 64;          // 0..2
    const int y0 = blockIdx.y * 4;           // 0..47
    const int bi = blockIdx.z;
    const int tid = threadIdx.x;
    const int lane = tid & 63, wr = tid >> 6;
    const int l15 = lane & 15, l4 = lane >> 4;
    const unsigned short* inb = Y + (size_t)bi * CCH * PIX;

    #pragma unroll 1
    for (int it = 0; it < 152; ++it) {
        int idx = tid + it*256;              // 0..38911
        int ci = idx / 1216;
        int rem = idx - ci*1216;
        int row = rem / 76;
        int x   = rem - row*76;
        int gy = y0 - 6 + row, gx = x0 - 6 + x;
        unsigned short v = ((unsigned)gy < (unsigned)HWD && (unsigned)gx < (unsigned)HWD)
                  ? inb[(size_t)ci*PIX + (size_t)gy*HWD + gx] : (unsigned short)0;
        int P = row*76 + x;
        XL[P*32 + (ci ^ ((P&3)<<3))] = v;
    }
    __syncthreads();

    f32x4 acc[2][4];
    #pragma unroll
    for (int i=0;i<2;++i)
        #pragma unroll
        for (int j=0;j<4;++j) acc[i][j] = (f32x4){0.f,0.f,0.f,0.f};

    #pragma unroll 1
    for (int dy=0; dy<13; ++dy) {
        const unsigned short* wrow = wq + (size_t)dy*13*1024;
        #pragma unroll
        for (int dx=0; dx<13; ++dx) {
            const short8 a0 = *(const short8*)(wrow + dx*1024 + l15*32 + l4*8);
            const short8 a1 = *(const short8*)(wrow + dx*1024 + (16+l15)*32 + l4*8);
            #pragma unroll
            for (int nt=0; nt<4; ++nt) {
                const int P = (wr + dy)*76 + nt*16 + l15 + dx;
                const short8 b = *(const short8*)&XL[P*32 + ((l4*8) ^ ((P&3)<<3))];
                acc[0][nt] = __builtin_amdgcn_mfma_f32_16x16x32_bf16(a0, b, acc[0][nt], 0, 0, 0);
                acc[1][nt] = __builtin_amdgcn_mfma_f32_16x16x32_bf16(a1, b, acc[1][nt], 0, 0, 0);
            }
        }
    }
    const int gy = y0 + wr;
    #pragma unroll
    for (int mt=0; mt<2; ++mt) {
        #pragma unroll
        for (int r=0; r<4; ++r) {
            const int co = mt*16 + l4*4 + r;
            const float* dkk = dk + (bi*32 + co)*9;
            float k0=dkk[0],k1=dkk[1],k2=dkk[2],k3=dkk[3],k4=dkk[4],
                  k5=dkk[5],k6=dkk[6],k7=dkk[7],k8=dkk[8];
            #pragma unroll
            for (int nt=0; nt<4; ++nt) {
                const int px = nt*16 + l15;
                float dsum = 0.f;
                #pragma unroll
                for (int e=0; e<9; ++e) {
                    int ey = e/3, ex = e - ey*3;
                    int P = (wr+5+ey)*76 + px+5+ex;
                    float pv = bf2f(XL[P*32 + (co ^ ((P&3)<<3))]);
                    float kk = (e==0?k0:e==1?k1:e==2?k2:e==3?k3:e==4?k4:e==5?k5:e==6?k6:e==7?k7:k8);
                    dsum += pv * kk;
                }
                float v = acc[mt][nt][r] + dsum;
                outC[((size_t)bi*32 + co)*PIX + (size_t)gy*HWD + x0 + px] = f2bf(v);
            }
        }
    }
}

// ---------------- depthwise 3x3 pad1 + bias, bf16 in/out (gelu(conv)+in) -------
__global__ __launch_bounds__(256) void dw3x3_bf_kernel(const unsigned short* __restrict__ in,
    const float* __restrict__ w, const float* __restrict__ b,
    unsigned short* __restrict__ out)
{
    int t = blockIdx.x*256 + threadIdx.x;     // nb*256*PIX/4 threads
    int pc = t / (PIX/4);
    int p4 = (t - pc*(PIX/4)) * 4;
    int c = pc & 255;
    int y = p4 / HWD, x0 = p4 - y*HWD;
    const unsigned short* ib = in + (size_t)pc * PIX;
    float wk[9];
    #pragma unroll
    for (int e=0;e<9;++e) wk[e] = w[c*9+e];
    float bc = b[c];
    float a0=bc,a1=bc,a2=bc,a3=bc;
    #pragma unroll
    for (int ky=0;ky<3;++ky) {
        int yy = y + ky - 1;
        if ((unsigned)yy < (unsigned)HWD) {
            const unsigned short* row = ib + (size_t)yy*HWD;
            float v[6];
            #pragma unroll
            for (int d=0;d<6;++d) {
                int xx = x0 + d - 1;
                v[d] = ((unsigned)xx < (unsigned)HWD) ? bf2f(row[xx]) : 0.f;
            }
            a0 += v[0]*wk[ky*3+0] + v[1]*wk[ky*3+1] + v[2]*wk[ky*3+2];
            a1 += v[1]*wk[ky*3+0] + v[2]*wk[ky*3+1] + v[3]*wk[ky*3+2];
            a2 += v[2]*wk[ky*3+0] + v[3]*wk[ky*3+1] + v[4]*wk[ky*3+2];
            a3 += v[3]*wk[ky*3+0] + v[4]*wk[ky*3+1] + v[5]*wk[ky*3+2];
        }
    }
    const unsigned short* cen = ib + (size_t)y*HWD + x0;
    unsigned short r0 = f2bf(gelu_f(a0) + bf2f(cen[0]));
    unsigned short r1 = f2bf(gelu_f(a1) + bf2f(cen[1]));
    unsigned short r2 = f2bf(gelu_f(a2) + bf2f(cen[2]));
    unsigned short r3 = f2bf(gelu_f(a3) + bf2f(cen[3]));
    uint2 pk;
    pk.x = (unsigned)r0 | ((unsigned)r1 << 16);
    pk.y = (unsigned)r2 | ((unsigned)r3 << 16);
    *(uint2*)(out + (size_t)pc*PIX + p4) = pk;
}

// ---------------- window attention via bf16 MFMA -------------------------------
// grid (144 win, 4 head, 8 = 2 z-halves x 4 q-chunks); block = 4 waves x 16 q.
__global__ __launch_bounds__(256) void attn_mfma_kernel(
    const unsigned short* __restrict__ qkv,  // (2, 384, PIX) bf16
    const float* __restrict__ table,         // (4, 961) f32
    unsigned short* __restrict__ o)          // (2, 128, PIX) bf16
{
    __shared__ unsigned short KL[256*40];    // [k][c] pad40
    __shared__ unsigned short VL[32*264];    // [d][k] pad264
    __shared__ unsigned short PL[4*16*264];  // per-wave P [q][k] pad264
    __shared__ float BT[961];
    __shared__ unsigned short OL[64*33];     // [q][d] pad33
    const int win = blockIdx.x, head = blockIdx.y;
    const int bi2 = blockIdx.z >> 2, qc = blockIdx.z & 3;
    const int wy = win/12, wx = win - wy*12;
    qkv += (size_t)bi2 * 384 * PIX;
    o   += (size_t)bi2 * CCH * PIX;
    const unsigned short* qb = qkv + (size_t)(head*32) * PIX;
    const unsigned short* kb = qkv + (size_t)(128 + head*32) * PIX;
    const unsigned short* vb = qkv + (size_t)(256 + head*32) * PIX;
    const int tid = threadIdx.x;

    // stage K [k][c] and V [d][k]
    for (int i = tid; i < 8192; i += 256) {
        int c = i >> 8, k = i & 255;
        int sp = ((wy<<4) + (k>>4))*HWD + (wx<<4) + (k&15);
        unsigned short kv = kb[(size_t)c*PIX + sp];
        unsigned short vv = vb[(size_t)c*PIX + sp];
        KL[k*40 + c] = kv;
        VL[c*264 + k] = vv;
    }
    for (int i = tid; i < 961; i += 256) BT[i] = table[head*961 + i];
    __syncthreads();

    const int lane = tid & 63, w = tid >> 6;
    const int l15 = lane & 15, l4 = lane >> 4;
    const int qi = qc*64 + w*16 + l15;       // this lane's q row (softmax owner)
    const int iy = qi >> 4, ix = qi & 15;
    const int spq = ((wy<<4) + iy)*HWD + (wx<<4) + ix;

    short8 qf;
    #pragma unroll
    for (int j=0;j<8;++j) qf[j] = (short)qb[(size_t)(l4*8+j)*PIX + spq];

    // S^T tiles: s[nt] holds S[k=nt*16+l4*4+r][q=l15]
    f32x4 s[16];
    #pragma unroll
    for (int nt=0; nt<16; ++nt) {
        const short8 a = *(const short8*)&KL[(nt*16 + l15)*40 + l4*8];
        s[nt] = __builtin_amdgcn_mfma_f32_16x16x32_bf16(a, qf, (f32x4){0.f,0.f,0.f,0.f}, 0, 0, 0);
    }

    const float scale = 0.17677669529663687f;   // 32^-0.5
    float m = -1e30f;
    #pragma unroll
    for (int nt=0; nt<16; ++nt) {
        #pragma unroll
        for (int r=0; r<4; ++r) {
            int k = nt*16 + l4*4 + r;
            float bv = BT[((k>>4) - iy + 15)*31 + ((k&15) - ix + 15)];
            float v = s[nt][r]*scale + bv;
            s[nt][r] = v;
            m = fmaxf(m, v);
        }
    }
    m = fmaxf(m, __shfl_xor(m, 16, 64));
    m = fmaxf(m, __shfl_xor(m, 32, 64));
    float l = 0.f;
    #pragma unroll
    for (int nt=0; nt<16; ++nt) {
        #pragma unroll
        for (int r=0; r<4; ++r) {
            float p = __expf(s[nt][r] - m);
            s[nt][r] = p;
            l += p;
        }
    }
    l += __shfl_xor(l, 16, 64);
    l += __shfl_xor(l, 32, 64);

    // pack P to per-wave LDS [q=l15][k]
    unsigned short* PLw = &PL[w*16*264];
    #pragma unroll
    for (int nt=0; nt<16; ++nt) {
        *(unsigned*)&PLw[l15*264 + nt*16 + l4*4]     = pack2bf(s[nt][0], s[nt][1]);
        *(unsigned*)&PLw[l15*264 + nt*16 + l4*4 + 2] = pack2bf(s[nt][2], s[nt][3]);
    }

    // PV: O[q][d] (16x32)
    f32x4 o0 = (f32x4){0.f,0.f,0.f,0.f}, o1 = (f32x4){0.f,0.f,0.f,0.f};
    #pragma unroll
    for (int kt=0; kt<8; ++kt) {
        const short8 pa = *(const short8*)&PLw[l15*264 + kt*32 + l4*8];
        const short8 v0 = *(const short8*)&VL[l15*264 + kt*32 + l4*8];
        const short8 v1 = *(const short8*)&VL[(16+l15)*264 + kt*32 + l4*8];
        o0 = __builtin_amdgcn_mfma_f32_16x16x32_bf16(pa, v0, o0, 0, 0, 0);
        o1 = __builtin_amdgcn_mfma_f32_16x16x32_bf16(pa, v1, o1, 0, 0, 0);
    }

    // normalize (1/l fetched from the lane owning that q-row) and stage to OL
    #pragma unroll
    for (int r=0; r<4; ++r) {
        float lr = __shfl(l, l4*4 + r, 64);
        float inv = 1.f / lr;
        OL[(w*16 + l4*4 + r)*33 + l15]      = f2bf(o0[r]*inv);
        OL[(w*16 + l4*4 + r)*33 + 16 + l15] = f2bf(o1[r]*inv);
    }
    __syncthreads();

    // coalesced store: thread = (d, 8-px segment)
    const int d = tid >> 3, seg = tid & 7;
    const int q0l = seg*8;
    const int qi0 = qc*64 + q0l;
    const int sp0 = ((wy<<4) + (qi0>>4))*HWD + (wx<<4) + (qi0 & 15);
    unsigned short tmp[8];
    #pragma unroll
    for (int j=0;j<8;++j) tmp[j] = OL[(q0l+j)*33 + d];
    *(uint4*)&o[(size_t)(head*32 + d)*PIX + sp0] = *(uint4*)tmp;
}

// ---------------- mean over spatial for channels 0..31 (bf16 in) ---------------
__global__ __launch_bounds__(256) void meanpool_kernel(const unsigned short* __restrict__ in,
    float* __restrict__ v)
{
    int bc = blockIdx.x;               // BB*32
    int bi = bc >> 5, c = bc & 31;
    const unsigned short* base = in + ((size_t)bi*CCH + c) * PIX;
    float s = 0.f;
    for (int i = threadIdx.x; i < PIX/4; i += 256) {
        const uint2 t4 = ((const uint2*)base)[i];
        s += bf2f((unsigned short)(t4.x & 0xffff)) + bf2f((unsigned short)(t4.x >> 16))
           + bf2f((unsigned short)(t4.y & 0xffff)) + bf2f((unsigned short)(t4.y >> 16));
    }
    #pragma unroll
    for (int off=32; off>0; off>>=1) s += __shfl_down(s, off, 64);
    __shared__ float red[4];
    if ((threadIdx.x & 63) == 0) red[threadIdx.x >> 6] = s;
    __syncthreads();
    if (threadIdx.x == 0) v[bc] = (red[0]+red[1]+red[2]+red[3]) * (1.f/PIX);
}

// ---------------- tiny MLP producing dynamic 3x3 kernels -----------------------
__global__ __launch_bounds__(256) void mlp_kernel(const float* __restrict__ v,
    const float* __restrict__ pw1, const float* __restrict__ pb1,
    const float* __restrict__ pw2, const float* __restrict__ pb2,
    float* __restrict__ dk)
{
    __shared__ float h[64];
    int tid = threadIdx.x;
    if (tid < 64) {
        int bi = tid >> 4, m = tid & 15;
        float s = pb1[m];
        for (int c=0;c<32;++c) s += v[bi*32+c]*pw1[m*32+c];
        h[tid] = gelu_f(s);
    }
    __syncthreads();
    for (int idx = tid; idx < BB*288; idx += 256) {
        int bi = idx / 288, j = idx - bi*288;
        float s = pb2[j];
        for (int m=0;m<16;++m) s += h[bi*16+m]*pw2[j*16+m];
        dk[idx] = s;
    }
}

// ---------------- fp32 -> bf16 cast (same layout) ------------------------------
__global__ __launch_bounds__(256) void wcast_kernel(const float* __restrict__ w,
    unsigned short* __restrict__ wq, int n)
{
    int idx = blockIdx.x*256 + threadIdx.x;
    if (idx < n) wq[idx] = f2bf(w[idx]);
}

// ---------------- co_w (128,128,3,3) -> bf16 [co][tap][ci] ---------------------
__global__ __launch_bounds__(256) void w3cast_kernel(const float* __restrict__ w,
    unsigned short* __restrict__ wq)
{
    int idx = blockIdx.x*256 + threadIdx.x;     // 128*128*9
    if (idx >= 128*128*9) return;
    int co = idx / (128*9);
    int rem = idx - co*128*9;
    int ci = rem / 9;
    int tap = rem - ci*9;
    wq[((size_t)co*9 + tap)*128 + ci] = f2bf(w[idx]);
}

// ---------------- plk (32,32,13,13) -> bf16 [tap][co][ci] ----------------------
__global__ __launch_bounds__(256) void w13cast_kernel(const float* __restrict__ w,
    unsigned short* __restrict__ wq)
{
    int idx = blockIdx.x*256 + threadIdx.x;     // 32*32*169
    if (idx >= 32*32*169) return;
    int co = idx / (32*169);
    int rem = idx - co*32*169;
    int ci = rem / 169;
    int tap = rem - ci*169;
    wq[((size_t)tap*32 + co)*32 + ci] = f2bf(w[idx]);
}

// ---------------- copy (B,32,PIX) bf16 into ch 0..31 of (B,128,PIX) bf16 -------
__global__ __launch_bounds__(256) void copyslice_kernel(const unsigned short* __restrict__ src,
    unsigned short* __restrict__ dst)
{
    int idx = blockIdx.x*256 + threadIdx.x;      // BB*32*PIX/8
    int bc = idx / (PIX/8);
    int p8 = (idx - bc*(PIX/8)) * 8;
    int bi = bc >> 5, c = bc & 31;
    *(uint4*)(dst + ((size_t)bi*CCH + c)*PIX + p8) =
        *(const uint4*)(src + (size_t)bc*PIX + p8);
}

extern "C" void kernel_launch(void* const* d_in, const int* in_sizes, int n_in,
                              void* d_out, int out_size, void* d_ws, size_t ws_size,
                              hipStream_t stream) {
    (void)in_sizes; (void)n_in; (void)out_size;
    const float* x_in      = (const float*)d_in[0];
    const float* plk       = (const float*)d_in[1];
    const float* ln_proj_w = (const float*)d_in[2];
    const float* ln_proj_b = (const float*)d_in[3];
    const float* proj_w1   = (const float*)d_in[4];
    const float* proj_b1   = (const float*)d_in[5];
    const float* proj_dw   = (const float*)d_in[6];
    const float* proj_dwb  = (const float*)d_in[7];
    const float* proj_w2   = (const float*)d_in[8];
    const float* proj_b2   = (const float*)d_in[9];
    const float* ln_attn_w = (const float*)d_in[10];
    const float* ln_attn_b = (const float*)d_in[11];
    const float* qkv_w     = (const float*)d_in[12];
    const float* qkv_b     = (const float*)d_in[13];
    const float* attn_ow   = (const float*)d_in[14];
    const float* attn_ob   = (const float*)d_in[15];
    const float* rpe       = (const float*)d_in[16];
    const float* ffn_w1    = (const float*)d_in[17];
    const float* ffn_b1    = (const float*)d_in[18];
    const float* ffn_dw    = (const float*)d_in[19];
    const float* ffn_dwb   = (const float*)d_in[20];
    const float* ffn_w2    = (const float*)d_in[21];
    const float* ffn_b2    = (const float*)d_in[22];
    const float* pk_w1     = (const float*)d_in[23];
    const float* pk_b1     = (const float*)d_in[24];
    const float* pk_w2     = (const float*)d_in[25];
    const float* pk_b2     = (const float*)d_in[26];
    const float* aggr_w    = (const float*)d_in[27];
    const float* aggr_b    = (const float*)d_in[28];
    const float* ln_out_w  = (const float*)d_in[29];
    const float* ln_out_b  = (const float*)d_in[30];
    const float* co_w      = (const float*)d_in[31];
    const float* co_b      = (const float*)d_in[32];
    float* out = (float*)d_out;

    const size_t N1b = (size_t)CCH * PIX;          // 4,718,592 elems (one batch)
    const size_t RBsz = (size_t)BB * N1b;          // 18,874,368 fl
    const size_t LNYw = RBsz / 2;                  // bf16 buffer in float-words
    const size_t POOLw = RBsz;                     // 37.7M ushorts in float-words
    const size_t need_floats = RBsz + LNYw + POOLw + 1408 + 307712 + 64;
    if (ws_size < need_floats * sizeof(float)) return;   // diagnostic guard

    float* ws  = (float*)d_ws;
    float* RB  = ws;                               // fp32 residual x
    unsigned short* LNY  = (unsigned short*)(RB + RBsz);   // bf16 (B,128,PIX)
    unsigned short* POOL = (unsigned short*)(RB + RBsz + LNYw);
    float* VB  = (float*)(RB + RBsz + LNYw + POOLw);   // 256
    float* DK  = VB + 256;                             // 1152
    unsigned short* Q0  = (unsigned short*)(DK + 1152);
    unsigned short* qPW1 = Q0;                 // 256*128
    unsigned short* qPW2 = qPW1 + 32768;       // 128*256
    unsigned short* qQKV = qPW2 + 32768;       // 384*128
    unsigned short* qAT  = qQKV + 49152;       // 128*128
    unsigned short* qF1  = qAT  + 16384;       // 2*256*128
    unsigned short* qF2  = qF1  + 65536;       // 2*128*256
    unsigned short* qAG  = qF2  + 65536;       // 2*128*128
    unsigned short* qW3  = qAG  + 32768;       // 128*9*128
    unsigned short* qW13 = qW3  + 147456;      // 169*32*32

    unsigned short* E1 = POOL;                 // 2 batches * 256 * PIX
    unsigned short* E2 = POOL + (size_t)2*256*PIX;
    unsigned short* QKV = POOL;                // 2 batches * 384 * PIX
    unsigned short* C13 = POOL;                // 4 batches * 32 * PIX

    dim3 blk(256);

    // ---- weight prep ----
    wcast_kernel<<<128, blk, 0, stream>>>(proj_w1, qPW1, 32768);
    wcast_kernel<<<128, blk, 0, stream>>>(proj_w2, qPW2, 32768);
    wcast_kernel<<<192, blk, 0, stream>>>(qkv_w, qQKV, 49152);
    wcast_kernel<<<64,  blk, 0, stream>>>(attn_ow, qAT, 16384);
    wcast_kernel<<<256, blk, 0, stream>>>(ffn_w1, qF1, 65536);
    wcast_kernel<<<256, blk, 0, stream>>>(ffn_w2, qF2, 65536);
    wcast_kernel<<<128, blk, 0, stream>>>(aggr_w, qAG, 32768);
    w3cast_kernel<<<576, blk, 0, stream>>>(co_w, qW3);
    w13cast_kernel<<<676, blk, 0, stream>>>(plk, qW13);

    // x = conv_ffn(LN(x_in), proj)
    ln_kernel<<<576, blk, 0, stream>>>(x_in, ln_proj_w, ln_proj_b, LNY);
    for (int h=0; h<2; ++h) {
        conv1x1_mfma_kernel<unsigned short,true,false,true><<<dim3(288,2,2), blk, 0, stream>>>(
            LNY + (size_t)h*2*N1b, qPW1, proj_b1, nullptr, E1, 128);
        dw3x3_bf_kernel<<<18432, blk, 0, stream>>>(E1, proj_dw, proj_dwb, E2);
        conv1x1_mfma_kernel<unsigned short,false,false,false><<<dim3(288,1,2), blk, 0, stream>>>(
            E2, qPW2, proj_b2, nullptr, RB + (size_t)h*2*N1b, 256);
    }

    // x = x + window_attention(LN(x))
    ln_kernel<<<576, blk, 0, stream>>>(RB, ln_attn_w, ln_attn_b, LNY);
    for (int h=0; h<2; ++h) {
        conv1x1_mfma_kernel<unsigned short,false,false,true><<<dim3(288,3,2), blk, 0, stream>>>(
            LNY + (size_t)h*2*N1b, qQKV, qkv_b, nullptr, QKV, 128);
        attn_mfma_kernel<<<dim3(144,4,8), blk, 0, stream>>>(QKV, rpe, LNY + (size_t)h*2*N1b);
    }
    conv1x1_mfma_kernel<unsigned short,false,true,false><<<dim3(288,1,BB), blk, 0, stream>>>(
        LNY, qAT, attn_ob, RB, RB, 128);

    // x lives in RB across the loop; y lives in LNY (bf16)
    for (int i=0;i<2;++i) {
        const float* fb1 = ffn_b1 + (size_t)i*256;
        const float* fdw = ffn_dw + (size_t)i*256*9;
        const float* fdb = ffn_dwb + (size_t)i*256;
        const float* fb2 = ffn_b2 + (size_t)i*128;
        const float* w1i = pk_w1 + (size_t)i*16*32;
        const float* b1i = pk_b1 + (size_t)i*16;
        const float* w2i = pk_w2 + (size_t)i*288*16;
        const float* b2i = pk_b2 + (size_t)i*288;
        const float* abi = aggr_b + (size_t)i*128;

        for (int h=0; h<2; ++h) {
            conv1x1_mfma_kernel<float,true,false,true><<<dim3(288,2,2), blk, 0, stream>>>(
                RB + (size_t)h*2*N1b, qF1 + (size_t)i*32768, fb1, nullptr, E1, 128);
            dw3x3_bf_kernel<<<18432, blk, 0, stream>>>(E1, fdw, fdb, E2);
            conv1x1_mfma_kernel<unsigned short,false,false,true><<<dim3(288,1,2), blk, 0, stream>>>(
                E2, qF2 + (size_t)i*32768, fb2, nullptr, LNY + (size_t)h*2*N1b, 256);
        }
        meanpool_kernel<<<BB*32, blk, 0, stream>>>(LNY, VB);
        mlp_kernel<<<1, blk, 0, stream>>>(VB, w1i, b1i, w2i, b2i, DK);
        conv13_mfma_kernel<<<dim3(3,48,BB), blk, 0, stream>>>(LNY, qW13, DK, C13);
        copyslice_kernel<<<(BB*32*(PIX/8))/256, blk, 0, stream>>>(C13, LNY);
        conv1x1_mfma_kernel<unsigned short,false,true,false><<<dim3(288,1,BB), blk, 0, stream>>>(
            LNY, qAG + (size_t)i*16384, abi, RB, RB, 128);
    }

    // out = conv3x3(LN(x)) + bias + skip
    ln_kernel<<<576, blk, 0, stream>>>(RB, ln_out_w, ln_out_b, LNY);
    conv3x3_mfma_kernel<<<dim3(3,96,BB), blk, 0, stream>>>(LNY, qW3, co_b, x_in, out);
}

// Round 9
// 1619.667 us; speedup vs baseline: 3.6475x; 1.1211x over previous
//
#include <hip/hip_runtime.h>
#include <cmath>

#define HWD 192
#define PIX (HWD*HWD)      // 36864
#define BB  4
#define CCH 128

using short8 = __attribute__((ext_vector_type(8))) short;
using f32x4  = __attribute__((ext_vector_type(4))) float;

__device__ __forceinline__ float gelu_f(float x) {
    return 0.5f * x * (1.0f + erff(x * 0.70710678118654752f));
}
__device__ __forceinline__ unsigned short f2bf(float f) {
    unsigned int u = __float_as_uint(f);
    u += 0x7fff + ((u >> 16) & 1);          // round-to-nearest-even
    return (unsigned short)(u >> 16);
}
__device__ __forceinline__ float bf2f(unsigned short s) {
    return __uint_as_float((unsigned int)s << 16);
}
__device__ __forceinline__ unsigned short to_bf(float v) { return f2bf(v); }
__device__ __forceinline__ unsigned short to_bf(unsigned short v) { return v; }
__device__ __forceinline__ unsigned pack2bf(float a, float b) {
    return (unsigned)f2bf(a) | ((unsigned)f2bf(b) << 16);
}

// ---------------- LayerNorm: fp32 in, bf16 out channel-major -------------------
__global__ __launch_bounds__(256) void ln_kernel(const float* __restrict__ in,
        const float* __restrict__ w, const float* __restrict__ b,
        unsigned short* __restrict__ out)
{
    int t = blockIdx.x * 256 + threadIdx.x;       // BB*PIX threads
    int bi = t / PIX;
    int p  = t - bi*PIX;
    const float* base = in + (size_t)bi * CCH * PIX + p;
    float v[CCH];
    float s = 0.f;
    #pragma unroll
    for (int c=0;c<CCH;++c) { v[c] = base[(size_t)c*PIX]; s += v[c]; }
    float m = s * (1.f/128.f);
    float q = 0.f;
    #pragma unroll
    for (int c=0;c<CCH;++c) { float d = v[c]-m; q += d*d; }
    float iv = rsqrtf(q*(1.f/128.f) + 1e-6f);
    unsigned short* ob = out + (size_t)bi * CCH * PIX + p;
    #pragma unroll
    for (int c=0;c<CCH;++c)
        ob[(size_t)c*PIX] = f2bf((v[c]-m)*iv*w[c] + b[c]);
}

// ---------------- LayerNorm: fp32 in, bf16 out TRANSPOSED (B,PIX,128) ----------
__global__ __launch_bounds__(256) void ln_t_kernel(const float* __restrict__ in,
        const float* __restrict__ w, const float* __restrict__ b,
        unsigned short* __restrict__ outT)
{
    int t = blockIdx.x * 256 + threadIdx.x;       // BB*PIX threads
    int bi = t / PIX;
    int p  = t - bi*PIX;
    const float* base = in + (size_t)bi * CCH * PIX + p;
    float v[CCH];
    float s = 0.f;
    #pragma unroll
    for (int c=0;c<CCH;++c) { v[c] = base[(size_t)c*PIX]; s += v[c]; }
    float m = s * (1.f/128.f);
    float q = 0.f;
    #pragma unroll
    for (int c=0;c<CCH;++c) { float d = v[c]-m; q += d*d; }
    float iv = rsqrtf(q*(1.f/128.f) + 1e-6f);
    unsigned short* ob = outT + ((size_t)bi * PIX + p) * 128;
    #pragma unroll
    for (int qq=0; qq<16; ++qq) {
        unsigned short e[8];
        #pragma unroll
        for (int j=0;j<8;++j) {
            int c = qq*8 + j;
            e[j] = f2bf((v[c]-m)*iv*w[c] + b[c]);
        }
        *(uint4*)&ob[qq*8] = *(uint4*)e;
    }
}

// ---------------- transpose y ch 0..31: (B,128,PIX) -> (B,PIX,32) --------------
__global__ __launch_bounds__(256) void t32_kernel(const unsigned short* __restrict__ in,
    unsigned short* __restrict__ outT)
{
    int t = blockIdx.x * 256 + threadIdx.x;       // BB*PIX threads
    int bi = t / PIX;
    int p  = t - bi*PIX;
    const unsigned short* base = in + (size_t)bi * CCH * PIX + p;
    unsigned short e[32];
    #pragma unroll
    for (int c=0;c<32;++c) e[c] = base[(size_t)c*PIX];
    unsigned short* ob = outT + ((size_t)bi * PIX + p) * 32;
    #pragma unroll
    for (int q=0;q<4;++q) *(uint4*)&ob[q*8] = *(uint4*)&e[q*8];
}

// ---------------- 1x1 conv via bf16 MFMA ---------------------------------------
template<typename TIN, bool DOGELU, bool DORES, bool OBF>
__global__ __launch_bounds__(256) void conv1x1_mfma_kernel(
    const TIN* __restrict__ in,              // (z, Cin, PIX)
    const unsigned short* __restrict__ wq,   // (Cout, Cin) bf16
    const float* __restrict__ bias,
    const float* __restrict__ res,           // (z, Cout, PIX) fp32 or null
    void* __restrict__ outv,                 // (z, Cout, PIX)
    int Cin)
{
    constexpr int CIP = 72;
    __shared__ unsigned short XL[128*CIP];
    const int Cout = gridDim.y * 128;
    const int px0 = blockIdx.x * 128;
    const int co0 = blockIdx.y * 128;
    const size_t bi = blockIdx.z;
    in  += bi * (size_t)Cin * PIX;
    if (DORES) res += bi * (size_t)Cout * PIX;
    float* outf = (float*)outv + bi * (size_t)Cout * PIX;
    unsigned short* outb = (unsigned short*)outv + bi * (size_t)Cout * PIX;
    const int tid = threadIdx.x;
    const int lane = tid & 63, wid = tid >> 6;
    const int wco = (wid >> 1) * 64;
    const int wpx = (wid & 1) * 64;
    const int l15 = lane & 15, l4 = lane >> 4;

    f32x4 acc[4][4];
    #pragma unroll
    for (int i=0;i<4;++i)
        #pragma unroll
        for (int j=0;j<4;++j) acc[i][j] = (f32x4){0.f,0.f,0.f,0.f};

    for (int k0 = 0; k0 < Cin; k0 += 64) {
        __syncthreads();
        #pragma unroll
        for (int it = 0; it < 8; ++it) {
            int f = tid + it*256;            // 0..2047
            int px = f & 127;
            int ci = (f >> 7) * 4;           // 0..60
            const TIN* gp = in + (size_t)(k0+ci)*PIX + px0 + px;
            unsigned short b0 = to_bf(gp[0]);
            unsigned short b1 = to_bf(gp[PIX]);
            unsigned short b2 = to_bf(gp[2*PIX]);
            unsigned short b3 = to_bf(gp[3*PIX]);
            uint2 pk;
            pk.x = (unsigned)b0 | ((unsigned)b1 << 16);
            pk.y = (unsigned)b2 | ((unsigned)b3 << 16);
            *(uint2*)&XL[px*CIP + ci] = pk;
        }
        __syncthreads();
        #pragma unroll
        for (int ks = 0; ks < 2; ++ks) {
            short8 a[4];
            #pragma unroll
            for (int mt=0; mt<4; ++mt) {
                int co = co0 + wco + mt*16 + l15;
                a[mt] = *(const short8*)(wq + (size_t)co*Cin + k0 + ks*32 + l4*8);
            }
            #pragma unroll
            for (int nt=0; nt<4; ++nt) {
                const short8 b = *(const short8*)&XL[(wpx + nt*16 + l15)*CIP + ks*32 + l4*8];
                #pragma unroll
                for (int mt=0; mt<4; ++mt)
                    acc[mt][nt] = __builtin_amdgcn_mfma_f32_16x16x32_bf16(a[mt], b, acc[mt][nt], 0, 0, 0);
            }
        }
    }
    #pragma unroll
    for (int mt=0; mt<4; ++mt) {
        #pragma unroll
        for (int r=0; r<4; ++r) {
            int co = co0 + wco + mt*16 + l4*4 + r;
            float bs = bias[co];
            #pragma unroll
            for (int nt=0; nt<4; ++nt) {
                int px = px0 + wpx + nt*16 + l15;
                float v = acc[mt][nt][r] + bs;
                if (DOGELU) v = gelu_f(v);
                size_t o = (size_t)co*PIX + px;
                if (DORES) v += res[o];
                if (OBF) outb[o] = f2bf(v);
                else     outf[o] = v;
            }
        }
    }
}

// ---------------- 3x3 dense conv 128->128 via bf16 MFMA + bias + skip ----------
// input TRANSPOSED XT (B,PIX,128) bf16 -> vectorized staging
__global__ __launch_bounds__(256) void conv3x3_mfma_kernel(
    const unsigned short* __restrict__ inT,  // (B,PIX,128) bf16
    const unsigned short* __restrict__ wq,   // (128,9,128) bf16 [co][tap][ci]
    const float* __restrict__ bias, const float* __restrict__ skip,
    float* __restrict__ out)
{
    constexpr int CIP = 40;
    __shared__ unsigned short XL[4*66*CIP];
    const int x0 = blockIdx.x * 64;          // 0..2
    const int y0 = blockIdx.y * 2;           // 0..95
    const int bi = blockIdx.z;
    const int tid = threadIdx.x;
    const int lane = tid & 63, wid = tid >> 6;
    const int wco = (wid >> 1) * 64;
    const int wrow = wid & 1;
    const int l15 = lane & 15, l4 = lane >> 4;
    const unsigned short* inb = inT + (size_t)bi * PIX * 128;

    f32x4 acc[4][4];
    #pragma unroll
    for (int i=0;i<4;++i)
        #pragma unroll
        for (int j=0;j<4;++j) acc[i][j] = (f32x4){0.f,0.f,0.f,0.f};

    for (int ci0 = 0; ci0 < 128; ci0 += 32) {
        __syncthreads();
        #pragma unroll
        for (int it = 0; it < 5; ++it) {
            int idx = tid + it*256;          // 0..1055 (4 rows x 66 x x 4 q)
            if (idx < 1056) {
                int P = idx >> 2;            // 0..263
                int q = idx & 3;
                int row = P / 66;
                int x = P - row*66;
                int gy = y0 - 1 + row, gx = x0 - 1 + x;
                uint4 v = {0u,0u,0u,0u};
                if ((unsigned)gy < (unsigned)HWD && (unsigned)gx < (unsigned)HWD)
                    v = *(const uint4*)&inb[((size_t)gy*HWD + gx)*128 + ci0 + q*8];
                *(uint4*)&XL[(row*66 + x)*CIP + q*8] = v;
            }
        }
        __syncthreads();
        #pragma unroll
        for (int dy=0; dy<3; ++dy) {
            #pragma unroll
            for (int dx=0; dx<3; ++dx) {
                short8 a[4];
                #pragma unroll
                for (int mt=0; mt<4; ++mt) {
                    int co = wco + mt*16 + l15;
                    a[mt] = *(const short8*)(wq + ((size_t)co*9 + dy*3+dx)*128 + ci0 + l4*8);
                }
                const int rl = wrow + dy;    // 0..3
                #pragma unroll
                for (int nt=0; nt<4; ++nt) {
                    const int xl = nt*16 + l15 + dx;   // 0..65
                    const short8 b = *(const short8*)&XL[(rl*66 + xl)*CIP + l4*8];
                    #pragma unroll
                    for (int mt=0; mt<4; ++mt)
                        acc[mt][nt] = __builtin_amdgcn_mfma_f32_16x16x32_bf16(a[mt], b, acc[mt][nt], 0, 0, 0);
                }
            }
        }
    }
    const int gy = y0 + wrow;
    #pragma unroll
    for (int mt=0; mt<4; ++mt) {
        #pragma unroll
        for (int r=0; r<4; ++r) {
            int co = wco + mt*16 + l4*4 + r;
            float bs = bias[co];
            #pragma unroll
            for (int nt=0; nt<4; ++nt) {
                int gx = x0 + nt*16 + l15;
                size_t o = ((size_t)bi*CCH + co)*PIX + (size_t)gy*HWD + gx;
                out[o] = acc[mt][nt][r] + bs + skip[o];
            }
        }
    }
}

// ---------------- 13x13 dense conv 32->32 pad6 via bf16 MFMA + fused dyn dw3x3 -
// input TRANSPOSED YT (B,PIX,32) bf16 -> vectorized swizzled staging
__global__ __launch_bounds__(256) void conv13_mfma_kernel(
    const unsigned short* __restrict__ YT,   // (B,PIX,32) bf16
    const unsigned short* __restrict__ wq,   // [169][32co][32ci] bf16
    const float* __restrict__ dk,            // [B*32][9]
    unsigned short* __restrict__ outC)       // (B,32,PIX) bf16
{
    __shared__ unsigned short XL[16*76*32];  // 77824 B, swizzled
    const int x0 = blockIdx.x * 64;          // 0..2
    const int y0 = blockIdx.y * 4;           // 0..47
    const int bi = blockIdx.z;
    const int tid = threadIdx.x;
    const int lane = tid & 63, wr = tid >> 6;
    const int l15 = lane & 15, l4 = lane >> 4;
    const unsigned short* inT = YT + (size_t)bi * PIX * 32;

    // stage 16 rows x 76 px x 32 ci (uint4 granularity, 8-granular swizzle)
    #pragma unroll 1
    for (int it = 0; it < 19; ++it) {
        int idx = tid + it*256;              // 0..4863 = 1216 P x 4 q
        int P = idx >> 2;
        int q = idx & 3;
        int row = P / 76;
        int x   = P - row*76;
        int gy = y0 - 6 + row, gx = x0 - 6 + x;
        uint4 v = {0u,0u,0u,0u};
        if ((unsigned)gy < (unsigned)HWD && (unsigned)gx < (unsigned)HWD)
            v = *(const uint4*)&inT[((size_t)gy*HWD + gx)*32 + q*8];
        *(uint4*)&XL[P*32 + ((q*8) ^ ((P&3)<<3))] = v;
    }
    __syncthreads();

    f32x4 acc[2][4];
    #pragma unroll
    for (int i=0;i<2;++i)
        #pragma unroll
        for (int j=0;j<4;++j) acc[i][j] = (f32x4){0.f,0.f,0.f,0.f};

    #pragma unroll 1
    for (int dy=0; dy<13; ++dy) {
        const unsigned short* wrow = wq + (size_t)dy*13*1024;
        #pragma unroll
        for (int dx=0; dx<13; ++dx) {
            const short8 a0 = *(const short8*)(wrow + dx*1024 + l15*32 + l4*8);
            const short8 a1 = *(const short8*)(wrow + dx*1024 + (16+l15)*32 + l4*8);
            #pragma unroll
            for (int nt=0; nt<4; ++nt) {
                const int P = (wr + dy)*76 + nt*16 + l15 + dx;
                const short8 b = *(const short8*)&XL[P*32 + ((l4*8) ^ ((P&3)<<3))];
                acc[0][nt] = __builtin_amdgcn_mfma_f32_16x16x32_bf16(a0, b, acc[0][nt], 0, 0, 0);
                acc[1][nt] = __builtin_amdgcn_mfma_f32_16x16x32_bf16(a1, b, acc[1][nt], 0, 0, 0);
            }
        }
    }
    const int gy = y0 + wr;
    #pragma unroll
    for (int mt=0; mt<2; ++mt) {
        #pragma unroll
        for (int r=0; r<4; ++r) {
            const int co = mt*16 + l4*4 + r;
            const float* dkk = dk + (bi*32 + co)*9;
            float k0=dkk[0],k1=dkk[1],k2=dkk[2],k3=dkk[3],k4=dkk[4],
                  k5=dkk[5],k6=dkk[6],k7=dkk[7],k8=dkk[8];
            #pragma unroll
            for (int nt=0; nt<4; ++nt) {
                const int px = nt*16 + l15;
                float dsum = 0.f;
                #pragma unroll
                for (int e=0; e<9; ++e) {
                    int ey = e/3, ex = e - ey*3;
                    int P = (wr+5+ey)*76 + px+5+ex;
                    float pv = bf2f(XL[P*32 + (co ^ ((P&3)<<3))]);
                    float kk = (e==0?k0:e==1?k1:e==2?k2:e==3?k3:e==4?k4:e==5?k5:e==6?k6:e==7?k7:k8);
                    dsum += pv * kk;
                }
                float v = acc[mt][nt][r] + dsum;
                outC[((size_t)bi*32 + co)*PIX + (size_t)gy*HWD + x0 + px] = f2bf(v);
            }
        }
    }
}

// ---------------- depthwise 3x3 pad1 + bias, bf16 in/out (gelu(conv)+in) -------
__global__ __launch_bounds__(256) void dw3x3_bf_kernel(const unsigned short* __restrict__ in,
    const float* __restrict__ w, const float* __restrict__ b,
    unsigned short* __restrict__ out)
{
    int t = blockIdx.x*256 + threadIdx.x;     // nb*256*PIX/4 threads
    int pc = t / (PIX/4);
    int p4 = (t - pc*(PIX/4)) * 4;
    int c = pc & 255;
    int y = p4 / HWD, x0 = p4 - y*HWD;
    const unsigned short* ib = in + (size_t)pc * PIX;
    float wk[9];
    #pragma unroll
    for (int e=0;e<9;++e) wk[e] = w[c*9+e];
    float bc = b[c];
    float a0=bc,a1=bc,a2=bc,a3=bc;
    #pragma unroll
    for (int ky=0;ky<3;++ky) {
        int yy = y + ky - 1;
        if ((unsigned)yy < (unsigned)HWD) {
            const unsigned short* row = ib + (size_t)yy*HWD;
            float v[6];
            #pragma unroll
            for (int d=0;d<6;++d) {
                int xx = x0 + d - 1;
                v[d] = ((unsigned)xx < (unsigned)HWD) ? bf2f(row[xx]) : 0.f;
            }
            a0 += v[0]*wk[ky*3+0] + v[1]*wk[ky*3+1] + v[2]*wk[ky*3+2];
            a1 += v[1]*wk[ky*3+0] + v[2]*wk[ky*3+1] + v[3]*wk[ky*3+2];
            a2 += v[2]*wk[ky*3+0] + v[3]*wk[ky*3+1] + v[4]*wk[ky*3+2];
            a3 += v[3]*wk[ky*3+0] + v[4]*wk[ky*3+1] + v[5]*wk[ky*3+2];
        }
    }
    const unsigned short* cen = ib + (size_t)y*HWD + x0;
    unsigned short r0 = f2bf(gelu_f(a0) + bf2f(cen[0]));
    unsigned short r1 = f2bf(gelu_f(a1) + bf2f(cen[1]));
    unsigned short r2 = f2bf(gelu_f(a2) + bf2f(cen[2]));
    unsigned short r3 = f2bf(gelu_f(a3) + bf2f(cen[3]));
    uint2 pk;
    pk.x = (unsigned)r0 | ((unsigned)r1 << 16);
    pk.y = (unsigned)r2 | ((unsigned)r3 << 16);
    *(uint2*)(out + (size_t)pc*PIX + p4) = pk;
}

// ---------------- window attention via bf16 MFMA -------------------------------
__global__ __launch_bounds__(256) void attn_mfma_kernel(
    const unsigned short* __restrict__ qkv,  // (2, 384, PIX) bf16
    const float* __restrict__ table,         // (4, 961) f32
    unsigned short* __restrict__ o)          // (2, 128, PIX) bf16
{
    __shared__ unsigned short KL[256*40];    // [k][c] pad40
    __shared__ unsigned short VL[32*264];    // [d][k] pad264
    __shared__ unsigned short PL[4*16*264];  // per-wave P [q][k] pad264
    __shared__ float BT[961];
    __shared__ unsigned short OL[64*33];     // [q][d] pad33
    const int win = blockIdx.x, head = blockIdx.y;
    const int bi2 = blockIdx.z >> 2, qc = blockIdx.z & 3;
    const int wy = win/12, wx = win - wy*12;
    qkv += (size_t)bi2 * 384 * PIX;
    o   += (size_t)bi2 * CCH * PIX;
    const unsigned short* qb = qkv + (size_t)(head*32) * PIX;
    const unsigned short* kb = qkv + (size_t)(128 + head*32) * PIX;
    const unsigned short* vb = qkv + (size_t)(256 + head*32) * PIX;
    const int tid = threadIdx.x;

    for (int i = tid; i < 8192; i += 256) {
        int c = i >> 8, k = i & 255;
        int sp = ((wy<<4) + (k>>4))*HWD + (wx<<4) + (k&15);
        unsigned short kv = kb[(size_t)c*PIX + sp];
        unsigned short vv = vb[(size_t)c*PIX + sp];
        KL[k*40 + c] = kv;
        VL[c*264 + k] = vv;
    }
    for (int i = tid; i < 961; i += 256) BT[i] = table[head*961 + i];
    __syncthreads();

    const int lane = tid & 63, w = tid >> 6;
    const int l15 = lane & 15, l4 = lane >> 4;
    const int qi = qc*64 + w*16 + l15;
    const int iy = qi >> 4, ix = qi & 15;
    const int spq = ((wy<<4) + iy)*HWD + (wx<<4) + ix;

    short8 qf;
    #pragma unroll
    for (int j=0;j<8;++j) qf[j] = (short)qb[(size_t)(l4*8+j)*PIX + spq];

    f32x4 s[16];
    #pragma unroll
    for (int nt=0; nt<16; ++nt) {
        const short8 a = *(const short8*)&KL[(nt*16 + l15)*40 + l4*8];
        s[nt] = __builtin_amdgcn_mfma_f32_16x16x32_bf16(a, qf, (f32x4){0.f,0.f,0.f,0.f}, 0, 0, 0);
    }

    const float scale = 0.17677669529663687f;   // 32^-0.5
    float m = -1e30f;
    #pragma unroll
    for (int nt=0; nt<16; ++nt) {
        #pragma unroll
        for (int r=0; r<4; ++r) {
            int k = nt*16 + l4*4 + r;
            float bv = BT[((k>>4) - iy + 15)*31 + ((k&15) - ix + 15)];
            float v = s[nt][r]*scale + bv;
            s[nt][r] = v;
            m = fmaxf(m, v);
        }
    }
    m = fmaxf(m, __shfl_xor(m, 16, 64));
    m = fmaxf(m, __shfl_xor(m, 32, 64));
    float l = 0.f;
    #pragma unroll
    for (int nt=0; nt<16; ++nt) {
        #pragma unroll
        for (int r=0; r<4; ++r) {
            float p = __expf(s[nt][r] - m);
            s[nt][r] = p;
            l += p;
        }
    }
    l += __shfl_xor(l, 16, 64);
    l += __shfl_xor(l, 32, 64);

    unsigned short* PLw = &PL[w*16*264];
    #pragma unroll
    for (int nt=0; nt<16; ++nt) {
        *(unsigned*)&PLw[l15*264 + nt*16 + l4*4]     = pack2bf(s[nt][0], s[nt][1]);
        *(unsigned*)&PLw[l15*264 + nt*16 + l4*4 + 2] = pack2bf(s[nt][2], s[nt][3]);
    }

    f32x4 o0 = (f32x4){0.f,0.f,0.f,0.f}, o1 = (f32x4){0.f,0.f,0.f,0.f};
    #pragma unroll
    for (int kt=0; kt<8; ++kt) {
        const short8 pa = *(const short8*)&PLw[l15*264 + kt*32 + l4*8];
        const short8 v0 = *(const short8*)&VL[l15*264 + kt*32 + l4*8];
        const short8 v1 = *(const short8*)&VL[(16+l15)*264 + kt*32 + l4*8];
        o0 = __builtin_amdgcn_mfma_f32_16x16x32_bf16(pa, v0, o0, 0, 0, 0);
        o1 = __builtin_amdgcn_mfma_f32_16x16x32_bf16(pa, v1, o1, 0, 0, 0);
    }

    #pragma unroll
    for (int r=0; r<4; ++r) {
        float lr = __shfl(l, l4*4 + r, 64);
        float inv = 1.f / lr;
        OL[(w*16 + l4*4 + r)*33 + l15]      = f2bf(o0[r]*inv);
        OL[(w*16 + l4*4 + r)*33 + 16 + l15] = f2bf(o1[r]*inv);
    }
    __syncthreads();

    const int d = tid >> 3, seg = tid & 7;
    const int q0l = seg*8;
    const int qi0 = qc*64 + q0l;
    const int sp0 = ((wy<<4) + (qi0>>4))*HWD + (wx<<4) + (qi0 & 15);
    unsigned short tmp[8];
    #pragma unroll
    for (int j=0;j<8;++j) tmp[j] = OL[(q0l+j)*33 + d];
    *(uint4*)&o[(size_t)(head*32 + d)*PIX + sp0] = *(uint4*)tmp;
}

// ---------------- mean over spatial for channels 0..31 (bf16 in) ---------------
__global__ __launch_bounds__(256) void meanpool_kernel(const unsigned short* __restrict__ in,
    float* __restrict__ v)
{
    int bc = blockIdx.x;               // BB*32
    int bi = bc >> 5, c = bc & 31;
    const unsigned short* base = in + ((size_t)bi*CCH + c) * PIX;
    float s = 0.f;
    for (int i = threadIdx.x; i < PIX/4; i += 256) {
        const uint2 t4 = ((const uint2*)base)[i];
        s += bf2f((unsigned short)(t4.x & 0xffff)) + bf2f((unsigned short)(t4.x >> 16))
           + bf2f((unsigned short)(t4.y & 0xffff)) + bf2f((unsigned short)(t4.y >> 16));
    }
    #pragma unroll
    for (int off=32; off>0; off>>=1) s += __shfl_down(s, off, 64);
    __shared__ float red[4];
    if ((threadIdx.x & 63) == 0) red[threadIdx.x >> 6] = s;
    __syncthreads();
    if (threadIdx.x == 0) v[bc] = (red[0]+red[1]+red[2]+red[3]) * (1.f/PIX);
}

// ---------------- tiny MLP producing dynamic 3x3 kernels -----------------------
__global__ __launch_bounds__(256) void mlp_kernel(const float* __restrict__ v,
    const float* __restrict__ pw1, const float* __restrict__ pb1,
    const float* __restrict__ pw2, const float* __restrict__ pb2,
    float* __restrict__ dk)
{
    __shared__ float h[64];
    int tid = threadIdx.x;
    if (tid < 64) {
        int bi = tid >> 4, m = tid & 15;
        float s = pb1[m];
        for (int c=0;c<32;++c) s += v[bi*32+c]*pw1[m*32+c];
        h[tid] = gelu_f(s);
    }
    __syncthreads();
    for (int idx = tid; idx < BB*288; idx += 256) {
        int bi = idx / 288, j = idx - bi*288;
        float s = pb2[j];
        for (int m=0;m<16;++m) s += h[bi*16+m]*pw2[j*16+m];
        dk[idx] = s;
    }
}

// ---------------- fp32 -> bf16 cast (same layout) ------------------------------
__global__ __launch_bounds__(256) void wcast_kernel(const float* __restrict__ w,
    unsigned short* __restrict__ wq, int n)
{
    int idx = blockIdx.x*256 + threadIdx.x;
    if (idx < n) wq[idx] = f2bf(w[idx]);
}

// ---------------- co_w (128,128,3,3) -> bf16 [co][tap][ci] ---------------------
__global__ __launch_bounds__(256) void w3cast_kernel(const float* __restrict__ w,
    unsigned short* __restrict__ wq)
{
    int idx = blockIdx.x*256 + threadIdx.x;     // 128*128*9
    if (idx >= 128*128*9) return;
    int co = idx / (128*9);
    int rem = idx - co*128*9;
    int ci = rem / 9;
    int tap = rem - ci*9;
    wq[((size_t)co*9 + tap)*128 + ci] = f2bf(w[idx]);
}

// ---------------- plk (32,32,13,13) -> bf16 [tap][co][ci] ----------------------
__global__ __launch_bounds__(256) void w13cast_kernel(const float* __restrict__ w,
    unsigned short* __restrict__ wq)
{
    int idx = blockIdx.x*256 + threadIdx.x;     // 32*32*169
    if (idx >= 32*32*169) return;
    int co = idx / (32*169);
    int rem = idx - co*32*169;
    int ci = rem / 169;
    int tap = rem - ci*169;
    wq[((size_t)tap*32 + co)*32 + ci] = f2bf(w[idx]);
}

// ---------------- copy (B,32,PIX) bf16 into ch 0..31 of (B,128,PIX) bf16 -------
__global__ __launch_bounds__(256) void copyslice_kernel(const unsigned short* __restrict__ src,
    unsigned short* __restrict__ dst)
{
    int idx = blockIdx.x*256 + threadIdx.x;      // BB*32*PIX/8
    int bc = idx / (PIX/8);
    int p8 = (idx - bc*(PIX/8)) * 8;
    int bi = bc >> 5, c = bc & 31;
    *(uint4*)(dst + ((size_t)bi*CCH + c)*PIX + p8) =
        *(const uint4*)(src + (size_t)bc*PIX + p8);
}

extern "C" void kernel_launch(void* const* d_in, const int* in_sizes, int n_in,
                              void* d_out, int out_size, void* d_ws, size_t ws_size,
                              hipStream_t stream) {
    (void)in_sizes; (void)n_in; (void)out_size;
    const float* x_in      = (const float*)d_in[0];
    const float* plk       = (const float*)d_in[1];
    const float* ln_proj_w = (const float*)d_in[2];
    const float* ln_proj_b = (const float*)d_in[3];
    const float* proj_w1   = (const float*)d_in[4];
    const float* proj_b1   = (const float*)d_in[5];
    const float* proj_dw   = (const float*)d_in[6];
    const float* proj_dwb  = (const float*)d_in[7];
    const float* proj_w2   = (const float*)d_in[8];
    const float* proj_b2   = (const float*)d_in[9];
    const float* ln_attn_w = (const float*)d_in[10];
    const float* ln_attn_b = (const float*)d_in[11];
    const float* qkv_w     = (const float*)d_in[12];
    const float* qkv_b     = (const float*)d_in[13];
    const float* attn_ow   = (const float*)d_in[14];
    const float* attn_ob   = (const float*)d_in[15];
    const float* rpe       = (const float*)d_in[16];
    const float* ffn_w1    = (const float*)d_in[17];
    const float* ffn_b1    = (const float*)d_in[18];
    const float* ffn_dw    = (const float*)d_in[19];
    const float* ffn_dwb   = (const float*)d_in[20];
    const float* ffn_w2    = (const float*)d_in[21];
    const float* ffn_b2    = (const float*)d_in[22];
    const float* pk_w1     = (const float*)d_in[23];
    const float* pk_b1     = (const float*)d_in[24];
    const float* pk_w2     = (const float*)d_in[25];
    const float* pk_b2     = (const float*)d_in[26];
    const float* aggr_w    = (const float*)d_in[27];
    const float* aggr_b    = (const float*)d_in[28];
    const float* ln_out_w  = (const float*)d_in[29];
    const float* ln_out_b  = (const float*)d_in[30];
    const float* co_w      = (const float*)d_in[31];
    const float* co_b      = (const float*)d_in[32];
    float* out = (float*)d_out;

    const size_t N1b = (size_t)CCH * PIX;          // 4,718,592 elems (one batch)
    const size_t RBsz = (size_t)BB * N1b;          // 18,874,368 fl
    const size_t LNYw = RBsz / 2;                  // bf16 buffer in float-words
    const size_t POOLw = RBsz;                     // 37.7M ushorts in float-words
    const size_t need_floats = RBsz + LNYw + POOLw + 1408 + 307712 + 64;
    if (ws_size < need_floats * sizeof(float)) return;   // diagnostic guard

    float* ws  = (float*)d_ws;
    float* RB  = ws;                               // fp32 residual x
    unsigned short* LNY  = (unsigned short*)(RB + RBsz);   // bf16 (B,128,PIX)
    unsigned short* POOL = (unsigned short*)(RB + RBsz + LNYw);
    float* VB  = (float*)(RB + RBsz + LNYw + POOLw);   // 256
    float* DK  = VB + 256;                             // 1152
    unsigned short* Q0  = (unsigned short*)(DK + 1152);
    unsigned short* qPW1 = Q0;                 // 256*128
    unsigned short* qPW2 = qPW1 + 32768;       // 128*256
    unsigned short* qQKV = qPW2 + 32768;       // 384*128
    unsigned short* qAT  = qQKV + 49152;       // 128*128
    unsigned short* qF1  = qAT  + 16384;       // 2*256*128
    unsigned short* qF2  = qF1  + 65536;       // 2*128*256
    unsigned short* qAG  = qF2  + 65536;       // 2*128*128
    unsigned short* qW3  = qAG  + 32768;       // 128*9*128
    unsigned short* qW13 = qW3  + 147456;      // 169*32*32

    unsigned short* E1 = POOL;                 // 2 batches * 256 * PIX
    unsigned short* E2 = POOL + (size_t)2*256*PIX;
    unsigned short* QKV = POOL;                // 2 batches * 384 * PIX
    unsigned short* C13 = POOL;                // 4 batches * 32 * PIX
    unsigned short* YT  = POOL + (size_t)BB*32*PIX;  // (B,PIX,32), after C13 region
    unsigned short* XT  = POOL;                // (B,PIX,128) for final conv3x3

    dim3 blk(256);

    // ---- weight prep ----
    wcast_kernel<<<128, blk, 0, stream>>>(proj_w1, qPW1, 32768);
    wcast_kernel<<<128, blk, 0, stream>>>(proj_w2, qPW2, 32768);
    wcast_kernel<<<192, blk, 0, stream>>>(qkv_w, qQKV, 49152);
    wcast_kernel<<<64,  blk, 0, stream>>>(attn_ow, qAT, 16384);
    wcast_kernel<<<256, blk, 0, stream>>>(ffn_w1, qF1, 65536);
    wcast_kernel<<<256, blk, 0, stream>>>(ffn_w2, qF2, 65536);
    wcast_kernel<<<128, blk, 0, stream>>>(aggr_w, qAG, 32768);
    w3cast_kernel<<<576, blk, 0, stream>>>(co_w, qW3);
    w13cast_kernel<<<676, blk, 0, stream>>>(plk, qW13);

    // x = conv_ffn(LN(x_in), proj)
    ln_kernel<<<576, blk, 0, stream>>>(x_in, ln_proj_w, ln_proj_b, LNY);
    for (int h=0; h<2; ++h) {
        conv1x1_mfma_kernel<unsigned short,true,false,true><<<dim3(288,2,2), blk, 0, stream>>>(
            LNY + (size_t)h*2*N1b, qPW1, proj_b1, nullptr, E1, 128);
        dw3x3_bf_kernel<<<18432, blk, 0, stream>>>(E1, proj_dw, proj_dwb, E2);
        conv1x1_mfma_kernel<unsigned short,false,false,false><<<dim3(288,1,2), blk, 0, stream>>>(
            E2, qPW2, proj_b2, nullptr, RB + (size_t)h*2*N1b, 256);
    }

    // x = x + window_attention(LN(x))
    ln_kernel<<<576, blk, 0, stream>>>(RB, ln_attn_w, ln_attn_b, LNY);
    for (int h=0; h<2; ++h) {
        conv1x1_mfma_kernel<unsigned short,false,false,true><<<dim3(288,3,2), blk, 0, stream>>>(
            LNY + (size_t)h*2*N1b, qQKV, qkv_b, nullptr, QKV, 128);
        attn_mfma_kernel<<<dim3(144,4,8), blk, 0, stream>>>(QKV, rpe, LNY + (size_t)h*2*N1b);
    }
    conv1x1_mfma_kernel<unsigned short,false,true,false><<<dim3(288,1,BB), blk, 0, stream>>>(
        LNY, qAT, attn_ob, RB, RB, 128);

    // x lives in RB across the loop; y lives in LNY (bf16)
    for (int i=0;i<2;++i) {
        const float* fb1 = ffn_b1 + (size_t)i*256;
        const float* fdw = ffn_dw + (size_t)i*256*9;
        const float* fdb = ffn_dwb + (size_t)i*256;
        const float* fb2 = ffn_b2 + (size_t)i*128;
        const float* w1i = pk_w1 + (size_t)i*16*32;
        const float* b1i = pk_b1 + (size_t)i*16;
        const float* w2i = pk_w2 + (size_t)i*288*16;
        const float* b2i = pk_b2 + (size_t)i*288;
        const float* abi = aggr_b + (size_t)i*128;

        for (int h=0; h<2; ++h) {
            conv1x1_mfma_kernel<float,true,false,true><<<dim3(288,2,2), blk, 0, stream>>>(
                RB + (size_t)h*2*N1b, qF1 + (size_t)i*32768, fb1, nullptr, E1, 128);
            dw3x3_bf_kernel<<<18432, blk, 0, stream>>>(E1, fdw, fdb, E2);
            conv1x1_mfma_kernel<unsigned short,false,false,true><<<dim3(288,1,2), blk, 0, stream>>>(
                E2, qF2 + (size_t)i*32768, fb2, nullptr, LNY + (size_t)h*2*N1b, 256);
        }
        t32_kernel<<<576, blk, 0, stream>>>(LNY, YT);
        meanpool_kernel<<<BB*32, blk, 0, stream>>>(LNY, VB);
        mlp_kernel<<<1, blk, 0, stream>>>(VB, w1i, b1i, w2i, b2i, DK);
        conv13_mfma_kernel<<<dim3(3,48,BB), blk, 0, stream>>>(YT, qW13, DK, C13);
        copyslice_kernel<<<(BB*32*(PIX/8))/256, blk, 0, stream>>>(C13, LNY);
        conv1x1_mfma_kernel<unsigned short,false,true,false><<<dim3(288,1,BB), blk, 0, stream>>>(
            LNY, qAG + (size_t)i*16384, abi, RB, RB, 128);
    }

    // out = conv3x3(LN(x)) + bias + skip  [transposed LN output]
    ln_t_kernel<<<576, blk, 0, stream>>>(RB, ln_out_w, ln_out_b, XT);
    conv3x3_mfma_kernel<<<dim3(3,96,BB), blk, 0, stream>>>(XT, qW3, co_b, x_in, out);
}